// Round 2
// baseline (7589.203 us; speedup 1.0000x reference)
//
#include <hip/hip_runtime.h>
#include <math.h>

#define Bsz 8
#define Cdim 512
#define Tdim 4096
#define NHq 8
#define CD 96
#define NB 8
#define NE 1024
#define NCHq 256
#define Mtok (Bsz*Tdim)     // 32768
#define M2tok (Bsz*NCHq)    // 2048

// ---------------- pe + constant query rows ----------------
__global__ __launch_bounds__(256) void pe_qc_kernel(float* pe_tab, float* qc_ln,
        const float* __restrict__ lnq_g, const float* __restrict__ lnq_b){
  int t = blockIdx.x;           // 0..15
  int tid = threadIdx.x;
  __shared__ float red[256];
  double f = -log(10000.0) / (double)Cdim;
  float v[2];
  #pragma unroll
  for (int u = 0; u < 2; ++u){
    int c = tid + u*256;
    int ce = c & ~1;
    double ang = (double)t * exp(f * (double)ce);
    v[u] = (float)((c & 1) ? cos(ang) : sin(ang));
    pe_tab[t*Cdim + c] = v[u];
  }
  red[tid] = v[0] + v[1]; __syncthreads();
  for (int s = 128; s > 0; s >>= 1){ if (tid < s) red[tid] += red[tid+s]; __syncthreads(); }
  float mean = red[0] * (1.f/512.f); __syncthreads();
  float d0 = v[0]-mean, d1 = v[1]-mean;
  red[tid] = d0*d0 + d1*d1; __syncthreads();
  for (int s = 128; s > 0; s >>= 1){ if (tid < s) red[tid] += red[tid+s]; __syncthreads(); }
  float rstd = 1.0f/sqrtf(red[0]*(1.f/512.f) + 1e-5f);
  qc_ln[t*Cdim + tid]       = d0*rstd*lnq_g[tid]     + lnq_b[tid];
  qc_ln[t*Cdim + tid + 256] = d1*rstd*lnq_g[tid+256] + lnq_b[tid+256];
}

// ---------------- generic row LayerNorm (rows of 512) ----------------
// mode 0: dst = norm*g+b ; mode 1: dst = tanh(norm*g+b)*clip(scale)
__global__ __launch_bounds__(256) void ln_rows_kernel(const float* __restrict__ src, float* __restrict__ dst,
        const float* __restrict__ g, const float* __restrict__ bia, int mode, const float* __restrict__ scale_ptr){
  int row = blockIdx.x; int tid = threadIdx.x;
  const float* sr = src + (size_t)row*Cdim;
  float v0 = sr[tid], v1 = sr[tid+256];
  __shared__ float red[256];
  red[tid] = v0+v1; __syncthreads();
  for (int s = 128; s > 0; s >>= 1){ if (tid < s) red[tid] += red[tid+s]; __syncthreads(); }
  float mean = red[0]*(1.f/512.f); __syncthreads();
  float d0 = v0-mean, d1 = v1-mean;
  red[tid] = d0*d0 + d1*d1; __syncthreads();
  for (int s = 128; s > 0; s >>= 1){ if (tid < s) red[tid] += red[tid+s]; __syncthreads(); }
  float rstd = 1.0f/sqrtf(red[0]*(1.f/512.f) + 1e-5f);
  float h0 = d0*rstd*g[tid]     + bia[tid];
  float h1 = d1*rstd*g[tid+256] + bia[tid+256];
  if (mode == 1){
    float sc = *scale_ptr; sc = fminf(fmaxf(sc, 0.005f), 0.5f);
    h0 = tanhf(h0)*sc; h1 = tanhf(h1)*sc;
  }
  float* dr = dst + (size_t)row*Cdim;
  dr[tid] = h0; dr[tid+256] = h1;
}

// ---------------- transposes [B,C,T] <-> token rows [B*T, C] ----------------
__global__ void tin_kernel(const float* __restrict__ qa, const float* __restrict__ pe_tab, float* __restrict__ rows){
  __shared__ float tile[32][33];
  int b = blockIdx.z, c0 = blockIdx.y*32, t0 = blockIdx.x*32;
  int tx = threadIdx.x, ty = threadIdx.y;
  int t = t0 + tx;
  #pragma unroll
  for (int j = 0; j < 4; j++){
    int c = c0 + ty + j*8;
    tile[ty+j*8][tx] = qa[((size_t)(b*Cdim + c))*Tdim + t] + pe_tab[(t & 15)*Cdim + c];
  }
  __syncthreads();
  #pragma unroll
  for (int j = 0; j < 4; j++){
    int tt = t0 + ty + j*8;
    rows[((size_t)(b*Tdim + tt))*Cdim + c0 + tx] = tile[tx][ty+j*8];
  }
}

__global__ void resid_kernel(const float* __restrict__ zt, const float* __restrict__ zp_rows, float* __restrict__ rows){
  __shared__ float tile[32][33];
  int b = blockIdx.z, c0 = blockIdx.y*32, t0 = blockIdx.x*32;
  int tx = threadIdx.x, ty = threadIdx.y;
  int t = t0 + tx;
  #pragma unroll
  for (int j = 0; j < 4; j++){
    int c = c0 + ty + j*8;
    tile[ty+j*8][tx] = zt[((size_t)(b*Cdim + c))*Tdim + t];
  }
  __syncthreads();
  #pragma unroll
  for (int j = 0; j < 4; j++){
    int tt = t0 + ty + j*8;
    size_t o = ((size_t)(b*Tdim + tt))*Cdim + c0 + tx;
    rows[o] = tile[tx][ty+j*8] - zp_rows[o];
  }
}

__global__ void tout_kernel(const float* __restrict__ rows, float* __restrict__ out){
  __shared__ float tile[32][33];
  int b = blockIdx.z, c0 = blockIdx.y*32, t0 = blockIdx.x*32;
  int tx = threadIdx.x, ty = threadIdx.y;
  #pragma unroll
  for (int j = 0; j < 4; j++){
    int tt = t0 + ty + j*8;
    tile[ty+j*8][tx] = rows[((size_t)(b*Tdim + tt))*Cdim + c0 + tx];
  }
  __syncthreads();
  #pragma unroll
  for (int j = 0; j < 4; j++){
    int c = c0 + ty + j*8;
    out[((size_t)(b*Cdim + c))*Tdim + t0 + tx] = tile[tx][ty+j*8];
  }
}

// ---------------- weight transposes ----------------
__global__ void twd_kernel(const float* __restrict__ Wd, float* __restrict__ WdT){ // Wd[96][512] -> WdT[512][96]
  int i = blockIdx.x*256 + threadIdx.x; if (i >= 96*512) return;
  int kq = i / 96, n = i % 96;
  WdT[i] = Wd[(size_t)n*512 + kq];
}
__global__ void twu_kernel(const float* __restrict__ Wu, float* __restrict__ WuT){ // Wu[512][96] -> WuT[96][512]
  int i = blockIdx.x*256 + threadIdx.x; if (i >= 96*512) return;
  int d = i / 512, c = i % 512;
  WuT[i] = Wu[(size_t)c*96 + d];
}

// ---------------- 0.5*||e||^2 per codebook entry ----------------
__global__ void hb_kernel(const float* __restrict__ books, float* __restrict__ hb){
  int j = blockIdx.x*256 + threadIdx.x;
  if (j >= NB*NE) return;
  const float* e = books + (size_t)j*CD;
  float s = 0.f;
  #pragma unroll
  for (int d = 0; d < CD; d++) s = fmaf(e[d], e[d], s);
  hb[j] = 0.5f*s;
}

// ---------------- generic tiled fp32 GEMM (64x64 tile): odd shapes only ----------------
// addmode: 0 none, 1 addbuf[(m&15)*N+n], 2 addbuf[m*N+n]
__global__ __launch_bounds__(256) void gemm_kernel(const float* __restrict__ A, const float* __restrict__ Bm,
        float* __restrict__ Cm, int M, int N, int K,
        const float* __restrict__ bias, const float* __restrict__ addbuf, int addmode, int act){
  __shared__ float As[16][65];
  __shared__ float Bs[16][64];
  int l = threadIdx.x;
  int tx = l & 15, ty = l >> 4;
  int m0 = blockIdx.y*64, n0 = blockIdx.x*64;
  int ai = l >> 2, ak = (l & 3)*4;
  int bk = l >> 4, bj = (l & 15)*4;
  float acc[4][4] = {{0.f}};
  bool nfull = (n0 + 64 <= N);
  for (int k0 = 0; k0 < K; k0 += 16){
    float4 av = make_float4(0.f, 0.f, 0.f, 0.f);
    if (m0 + ai < M) av = *(const float4*)(A + (size_t)(m0+ai)*K + k0 + ak);
    As[ak][ai] = av.x; As[ak+1][ai] = av.y; As[ak+2][ai] = av.z; As[ak+3][ai] = av.w;
    if (nfull){
      *(float4*)(&Bs[bk][bj]) = *(const float4*)(Bm + (size_t)(k0+bk)*N + n0 + bj);
    } else {
      #pragma unroll
      for (int u = 0; u < 4; u++){
        int n = n0 + bj + u;
        Bs[bk][bj+u] = (n < N) ? Bm[(size_t)(k0+bk)*N + n] : 0.f;
      }
    }
    __syncthreads();
    #pragma unroll
    for (int kk = 0; kk < 16; kk++){
      float a0 = As[kk][ty*4], a1 = As[kk][ty*4+1], a2 = As[kk][ty*4+2], a3 = As[kk][ty*4+3];
      float b0 = Bs[kk][tx*4], b1 = Bs[kk][tx*4+1], b2 = Bs[kk][tx*4+2], b3 = Bs[kk][tx*4+3];
      acc[0][0] = fmaf(a0,b0,acc[0][0]); acc[0][1] = fmaf(a0,b1,acc[0][1]);
      acc[0][2] = fmaf(a0,b2,acc[0][2]); acc[0][3] = fmaf(a0,b3,acc[0][3]);
      acc[1][0] = fmaf(a1,b0,acc[1][0]); acc[1][1] = fmaf(a1,b1,acc[1][1]);
      acc[1][2] = fmaf(a1,b2,acc[1][2]); acc[1][3] = fmaf(a1,b3,acc[1][3]);
      acc[2][0] = fmaf(a2,b0,acc[2][0]); acc[2][1] = fmaf(a2,b1,acc[2][1]);
      acc[2][2] = fmaf(a2,b2,acc[2][2]); acc[2][3] = fmaf(a2,b3,acc[2][3]);
      acc[3][0] = fmaf(a3,b0,acc[3][0]); acc[3][1] = fmaf(a3,b1,acc[3][1]);
      acc[3][2] = fmaf(a3,b2,acc[3][2]); acc[3][3] = fmaf(a3,b3,acc[3][3]);
    }
    __syncthreads();
  }
  #pragma unroll
  for (int r = 0; r < 4; r++){
    int m = m0 + ty*4 + r; if (m >= M) continue;
    #pragma unroll
    for (int c = 0; c < 4; c++){
      int n = n0 + tx*4 + c; if (n >= N) continue;
      float v = acc[r][c];
      if (bias) v += bias[n];
      if (act == 1) v = 0.5f*v*(1.0f + erff(v*0.7071067811865475f));
      if (addmode == 1) v += addbuf[(size_t)(m & 15)*N + n];
      else if (addmode == 2) v += addbuf[(size_t)m*N + n];
      Cm[(size_t)m*N + n] = v;
    }
  }
}

// ---------------- fast fp32 GEMM: 128x128 tile, 8x8 acc/thread ----------------
// requires M%128==0, N%128==0, K%16==0
__global__ __launch_bounds__(256) void fgemm_kernel(const float* __restrict__ A, const float* __restrict__ Bm,
        float* __restrict__ Cm, int M, int N, int K,
        const float* __restrict__ bias, const float* __restrict__ addbuf, int addmode, int act){
  __shared__ float As[16][128];
  __shared__ float Bs[16][128];
  int l = threadIdx.x;
  int tx = l & 15, ty = l >> 4;          // 16x16 thread grid
  int m0 = blockIdx.y*128, n0 = blockIdx.x*128;
  int ar = l >> 1, ac = (l & 1) * 8;     // A staging: 128 rows x 16 cols, 2 thr/row
  int br = l >> 4, bc = (l & 15) * 8;    // B staging: 16 rows x 128 cols
  float acc[8][8] = {{0.f}};
  const float* Aptr = A + (size_t)(m0 + ar)*K + ac;
  const float* Bptr = Bm + (size_t)br*N + n0 + bc;
  for (int k0 = 0; k0 < K; k0 += 16){
    float4 a0 = *(const float4*)(Aptr + k0);
    float4 a1 = *(const float4*)(Aptr + k0 + 4);
    float4 bv0 = *(const float4*)(Bptr + (size_t)k0*N);
    float4 bv1 = *(const float4*)(Bptr + (size_t)k0*N + 4);
    As[ac+0][ar]=a0.x; As[ac+1][ar]=a0.y; As[ac+2][ar]=a0.z; As[ac+3][ar]=a0.w;
    As[ac+4][ar]=a1.x; As[ac+5][ar]=a1.y; As[ac+6][ar]=a1.z; As[ac+7][ar]=a1.w;
    *(float4*)(&Bs[br][bc])   = bv0;
    *(float4*)(&Bs[br][bc+4]) = bv1;
    __syncthreads();
    #pragma unroll
    for (int kk = 0; kk < 16; kk++){
      float av[8], bw[8];
      *(float4*)(av)   = *(const float4*)(&As[kk][ty*4]);
      *(float4*)(av+4) = *(const float4*)(&As[kk][64 + ty*4]);
      *(float4*)(bw)   = *(const float4*)(&Bs[kk][tx*4]);
      *(float4*)(bw+4) = *(const float4*)(&Bs[kk][64 + tx*4]);
      #pragma unroll
      for (int i = 0; i < 8; i++)
        #pragma unroll
        for (int j = 0; j < 8; j++)
          acc[i][j] = fmaf(av[i], bw[j], acc[i][j]);
    }
    __syncthreads();
  }
  #pragma unroll
  for (int i = 0; i < 8; i++){
    int m = m0 + ((i < 4) ? (ty*4 + i) : (64 + ty*4 + i - 4));
    #pragma unroll
    for (int jh = 0; jh < 2; jh++){
      int nb = n0 + jh*64 + tx*4;
      float v[4];
      #pragma unroll
      for (int j = 0; j < 4; j++){
        float u = acc[i][jh*4 + j];
        int n = nb + j;
        if (bias) u += bias[n];
        if (act == 1) u = 0.5f*u*(1.0f + erff(u*0.7071067811865475f));
        if (addmode == 1) u += addbuf[(size_t)(m & 15)*N + n];
        else if (addmode == 2) u += addbuf[(size_t)m*N + n];
        v[j] = u;
      }
      *(float4*)(Cm + (size_t)m*N + nb) = *(float4*)v;
    }
  }
}

// ---------------- attention, phase 1: 16 const queries x 16 keys per (b,chunk) ----------------
__global__ __launch_bounds__(128) void attn1_kernel(const float* __restrict__ Kb, const float* __restrict__ Vb,
        const float* __restrict__ Qp, float* __restrict__ ctxb){
  int idx = blockIdx.x;                 // b*256 + ch
  int b = idx >> 8, ch = idx & 255;
  size_t m0 = (size_t)b*Tdim + ch*16;
  int t = threadIdx.x >> 3, h = threadIdx.x & 7;
  const float* q = Qp + t*Cdim + h*64;
  float qr[64];
  #pragma unroll
  for (int d = 0; d < 64; d += 4){ float4 f = *(const float4*)(q+d); qr[d]=f.x; qr[d+1]=f.y; qr[d+2]=f.z; qr[d+3]=f.w; }
  float s[16];
  #pragma unroll
  for (int k = 0; k < 16; k++){
    const float* kr = Kb + (m0+k)*Cdim + h*64;
    float acc = 0.f;
    #pragma unroll
    for (int d = 0; d < 64; d += 4){
      float4 f = *(const float4*)(kr+d);
      acc = fmaf(qr[d],f.x,acc); acc = fmaf(qr[d+1],f.y,acc);
      acc = fmaf(qr[d+2],f.z,acc); acc = fmaf(qr[d+3],f.w,acc);
    }
    s[k] = acc * 0.125f;
  }
  float mx = s[0];
  #pragma unroll
  for (int k = 1; k < 16; k++) mx = fmaxf(mx, s[k]);
  float sum = 0.f;
  #pragma unroll
  for (int k = 0; k < 16; k++){ s[k] = expf(s[k]-mx); sum += s[k]; }
  float inv = 1.0f/sum;
  float ctx[64];
  #pragma unroll
  for (int d = 0; d < 64; d++) ctx[d] = 0.f;
  #pragma unroll
  for (int k = 0; k < 16; k++){
    float p = s[k]*inv;
    const float* vr = Vb + (m0+k)*Cdim + h*64;
    #pragma unroll
    for (int d = 0; d < 64; d += 4){
      float4 f = *(const float4*)(vr+d);
      ctx[d]=fmaf(p,f.x,ctx[d]); ctx[d+1]=fmaf(p,f.y,ctx[d+1]);
      ctx[d+2]=fmaf(p,f.z,ctx[d+2]); ctx[d+3]=fmaf(p,f.w,ctx[d+3]);
    }
  }
  float* o = ctxb + (m0+t)*Cdim + h*64;
  #pragma unroll
  for (int d = 0; d < 64; d += 4){
    float4 f; f.x=ctx[d]; f.y=ctx[d+1]; f.z=ctx[d+2]; f.w=ctx[d+3];
    *(float4*)(o+d) = f;
  }
}

// ---------------- attention, phase 2: 1 query (token 0) per (b,chunk) ----------------
__global__ __launch_bounds__(64) void attn2_kernel(const float* __restrict__ Kb, const float* __restrict__ Vb,
        const float* __restrict__ Qp, float* __restrict__ ctxb){
  int m2 = blockIdx.x;                 // b*256 + ch
  int b = m2 >> 8, ch = m2 & 255;
  size_t m0 = (size_t)b*Tdim + ch*16;
  int h = threadIdx.x;
  if (h >= 8) return;
  const float* q = Qp + (size_t)m2*Cdim + h*64;
  float qr[64];
  #pragma unroll
  for (int d = 0; d < 64; d += 4){ float4 f = *(const float4*)(q+d); qr[d]=f.x; qr[d+1]=f.y; qr[d+2]=f.z; qr[d+3]=f.w; }
  float s[16];
  #pragma unroll
  for (int k = 0; k < 16; k++){
    const float* kr = Kb + (m0+k)*Cdim + h*64;
    float acc = 0.f;
    #pragma unroll
    for (int d = 0; d < 64; d += 4){
      float4 f = *(const float4*)(kr+d);
      acc = fmaf(qr[d],f.x,acc); acc = fmaf(qr[d+1],f.y,acc);
      acc = fmaf(qr[d+2],f.z,acc); acc = fmaf(qr[d+3],f.w,acc);
    }
    s[k] = acc * 0.125f;
  }
  float mx = s[0];
  #pragma unroll
  for (int k = 1; k < 16; k++) mx = fmaxf(mx, s[k]);
  float sum = 0.f;
  #pragma unroll
  for (int k = 0; k < 16; k++){ s[k] = expf(s[k]-mx); sum += s[k]; }
  float inv = 1.0f/sum;
  float ctx[64];
  #pragma unroll
  for (int d = 0; d < 64; d++) ctx[d] = 0.f;
  #pragma unroll
  for (int k = 0; k < 16; k++){
    float p = s[k]*inv;
    const float* vr = Vb + (m0+k)*Cdim + h*64;
    #pragma unroll
    for (int d = 0; d < 64; d += 4){
      float4 f = *(const float4*)(vr+d);
      ctx[d]=fmaf(p,f.x,ctx[d]); ctx[d+1]=fmaf(p,f.y,ctx[d+1]);
      ctx[d+2]=fmaf(p,f.z,ctx[d+2]); ctx[d+3]=fmaf(p,f.w,ctx[d+3]);
    }
  }
  float* o = ctxb + (size_t)m2*Cdim + h*64;
  #pragma unroll
  for (int d = 0; d < 64; d += 4){
    float4 f; f.x=ctx[d]; f.y=ctx[d+1]; f.z=ctx[d+2]; f.w=ctx[d+3];
    *(float4*)(o+d) = f;
  }
}

// ---------------- phase 2: build token-0 query rows (carry + pe[:,0], LN) ----------------
__global__ __launch_bounds__(256) void q2_kernel(const float* __restrict__ dout, float* __restrict__ p2q,
        const float* __restrict__ g, const float* __restrict__ bia){
  int m2 = blockIdx.x; int tid = threadIdx.x;
  int b = m2 >> 8, ch = m2 & 255;
  int tprev = ch*16 - 1;
  float v0, v1;
  {
    int c = tid;
    float carry = (ch == 0) ? 0.f : dout[((size_t)(b*Cdim + c))*Tdim + tprev];
    v0 = carry + ((c & 1) ? 1.f : 0.f);     // pe[c,0] = c even ? sin(0)=0 : cos(0)=1
  }
  {
    int c = tid + 256;
    float carry = (ch == 0) ? 0.f : dout[((size_t)(b*Cdim + c))*Tdim + tprev];
    v1 = carry + ((c & 1) ? 1.f : 0.f);
  }
  __shared__ float red[256];
  red[tid] = v0+v1; __syncthreads();
  for (int s = 128; s > 0; s >>= 1){ if (tid < s) red[tid] += red[tid+s]; __syncthreads(); }
  float mean = red[0]*(1.f/512.f); __syncthreads();
  float d0 = v0-mean, d1 = v1-mean;
  red[tid] = d0*d0 + d1*d1; __syncthreads();
  for (int s = 128; s > 0; s >>= 1){ if (tid < s) red[tid] += red[tid+s]; __syncthreads(); }
  float rstd = 1.0f/sqrtf(red[0]*(1.f/512.f) + 1e-5f);
  p2q[(size_t)m2*Cdim + tid]       = d0*rstd*g[tid]     + bia[tid];
  p2q[(size_t)m2*Cdim + tid + 256] = d1*rstd*g[tid+256] + bia[tid+256];
}

// ---------------- phase 2: r = zt[:, :, t0] - z_pred0 ----------------
__global__ __launch_bounds__(256) void r2_kernel(const float* __restrict__ zt, const float* __restrict__ zp,
        float* __restrict__ out){
  int m2 = blockIdx.x; int tid = threadIdx.x;
  int b = m2 >> 8, ch = m2 & 255; int t0 = ch*16;
  #pragma unroll
  for (int u = 0; u < 2; u++){
    int c = tid + u*256;
    out[(size_t)m2*Cdim + c] = zt[((size_t)(b*Cdim + c))*Tdim + t0] - zp[(size_t)m2*Cdim + c];
  }
}

// ---------------- phase 2: scatter z_hat token-0 columns into d_out ----------------
__global__ __launch_bounds__(256) void scatter2_kernel(const float* __restrict__ z, float* __restrict__ dout){
  int m2 = blockIdx.x; int tid = threadIdx.x;
  int b = m2 >> 8, ch = m2 & 255; int t0 = ch*16;
  #pragma unroll
  for (int u = 0; u < 2; u++){
    int c = tid + u*256;
    dout[((size_t)(b*Cdim + c))*Tdim + t0] = z[(size_t)m2*Cdim + c];
  }
}

// ---------------- residual VQ, vector-path layout ----------------
// Old layout routed the codebook through the SCALAR path (wave-uniform addresses ->
// s_load chains, in-order lgkmcnt drains, 6.3 TB through sL1): VALUBusy 36%, 5.8x FLOP floor.
// New layout: lane = tok*4 + chunk. 16 tokens/wave, each token's 96 dims split over
// 4 lanes (res[24]/lane -> no AGPR shuffling). Codebook rows flow through the VECTOR
// path (per-lane float4 loads, pipelined under vmcnt, L2-resident). Per-candidate dot
// finished with a 2-op DPP quad butterfly (no LDS/DS). NWAVES waves scan disjoint
// ascending candidate ranges; argmax merged once per book via tiny parity-buffered LDS
// (1 barrier/book; ascending scan + strict '>' preserves jnp.argmax first-max rule).
__device__ __forceinline__ float quad_sum(float v){
  int t = __builtin_amdgcn_update_dpp(0, __float_as_int(v), 0xB1, 0xF, 0xF, false); // quad_perm [1,0,3,2]
  v += __int_as_float(t);
  t = __builtin_amdgcn_update_dpp(0, __float_as_int(v), 0x4E, 0xF, 0xF, false);     // quad_perm [2,3,0,1]
  v += __int_as_float(t);
  return v;
}

template<int NWAVES>
__global__ __launch_bounds__(64*NWAVES) void vq_kernel(float* __restrict__ x, const float* __restrict__ books,
        const float* __restrict__ hb){
  const int RNG = NE / NWAVES;           // candidates per wave
  int lane = threadIdx.x & 63;
  int wv   = __builtin_amdgcn_readfirstlane(threadIdx.x >> 6);
  int tok  = lane >> 2;                  // 0..15
  int cch  = lane & 3;                   // dim chunk (24 floats)
  size_t tok0 = (size_t)blockIdx.x * 16;
  float* xw = x + (tok0 + tok)*CD + cch*24;
  float res[24];
  #pragma unroll
  for (int j = 0; j < 24; j += 4){
    float4 f = *(const float4*)(xw + j);
    res[j]=f.x; res[j+1]=f.y; res[j+2]=f.z; res[j+3]=f.w;
  }
  __shared__ float s_best[2][NWAVES][16];
  __shared__ int   s_idx [2][NWAVES][16];
  for (int k = 0; k < NB; k++){
    const float* bk = books + (size_t)k*NE*CD;
    const float* hk = hb + k*NE;
    int cbase = wv * RNG;
    float best = -3.0e38f; int bidx = 0;
    for (int cc = 0; cc < RNG; cc += 2){
      int c0 = cbase + cc;
      const float* e0 = bk + (size_t)c0*CD + cch*24;
      float4 q0[6], q1[6];
      #pragma unroll
      for (int j = 0; j < 6; j++) q0[j] = *(const float4*)(e0 + 4*j);
      #pragma unroll
      for (int j = 0; j < 6; j++) q1[j] = *(const float4*)(e0 + CD + 4*j);
      float a0 = 0.f, a1 = 0.f;
      #pragma unroll
      for (int j = 0; j < 6; j++){
        a0 = fmaf(res[4*j],  q0[j].x, a0);
        a1 = fmaf(res[4*j],  q1[j].x, a1);
        a0 = fmaf(res[4*j+1],q0[j].y, a0);
        a1 = fmaf(res[4*j+1],q1[j].y, a1);
        a0 = fmaf(res[4*j+2],q0[j].z, a0);
        a1 = fmaf(res[4*j+2],q1[j].z, a1);
        a0 = fmaf(res[4*j+3],q0[j].w, a0);
        a1 = fmaf(res[4*j+3],q1[j].w, a1);
      }
      a0 = quad_sum(a0);                 // all 4 lanes of the token get full dot
      a1 = quad_sum(a1);
      float s0 = a0 - hk[c0];
      float s1 = a1 - hk[c0+1];
      if (s0 > best){ best = s0; bidx = c0; }
      if (s1 > best){ best = s1; bidx = c0 + 1; }
    }
    int par = k & 1;
    if (cch == 0){ s_best[par][wv][tok] = best; s_idx[par][wv][tok] = bidx; }
    __syncthreads();
    float bb = s_best[par][0][tok]; int bi = s_idx[par][0][tok];
    #pragma unroll
    for (int w = 1; w < NWAVES; w++){
      float b2 = s_best[par][w][tok];
      int   i2 = s_idx [par][w][tok];
      if (b2 > bb){ bb = b2; bi = i2; }  // ascending wave ranges -> first-max tie rule
    }
    const float* ev = bk + (size_t)bi*CD + cch*24;
    #pragma unroll
    for (int j = 0; j < 24; j += 4){
      float4 f = *(const float4*)(ev + j);
      res[j]-=f.x; res[j+1]-=f.y; res[j+2]-=f.z; res[j+3]-=f.w;
    }
    // parity double-buffer: next book writes the other LDS slot, no second barrier
  }
  if (wv == 0){
    #pragma unroll
    for (int j = 0; j < 24; j += 4){
      float4 xo = *(const float4*)(xw + j);
      float4 q;
      q.x = xo.x - res[j]; q.y = xo.y - res[j+1]; q.z = xo.z - res[j+2]; q.w = xo.w - res[j+3];
      *(float4*)(xw + j) = q;
    }
  }
}

// ---------------- host ----------------
extern "C" void kernel_launch(void* const* d_in, const int* in_sizes, int n_in,
                              void* d_out, int out_size, void* d_ws, size_t ws_size,
                              hipStream_t stream) {
  const float* qa    = (const float*)d_in[0];
  const float* zt    = (const float*)d_in[1];
  const float* lnq_g = (const float*)d_in[2];
  const float* lnq_b = (const float*)d_in[3];
  const float* lnkv_g= (const float*)d_in[4];
  const float* lnkv_b= (const float*)d_in[5];
  const float* Wq    = (const float*)d_in[6];
  const float* Wk    = (const float*)d_in[7];
  const float* Wv    = (const float*)d_in[8];
  const float* Wo    = (const float*)d_in[9];
  const float* ffn_g = (const float*)d_in[10];
  const float* ffn_b = (const float*)d_in[11];
  const float* W1    = (const float*)d_in[12];
  const float* b1    = (const float*)d_in[13];
  const float* W2    = (const float*)d_in[14];
  const float* b2    = (const float*)d_in[15];
  const float* tn_g  = (const float*)d_in[16];
  const float* tn_b  = (const float*)d_in[17];
  const float* scale = (const float*)d_in[18];
  const float* Wd    = (const float*)d_in[19];
  const float* bd    = (const float*)d_in[20];
  const float* Wu    = (const float*)d_in[21];
  const float* bu    = (const float*)d_in[22];
  const float* books = (const float*)d_in[23];
  float* out = (float*)d_out;

  // ---- workspace layout (total ~208.5 MiB) ----
  float* ws = (float*)d_ws;
  size_t off = 0;
  float* pe_tab  = ws + off; off += 16*512;
  float* qc_ln   = ws + off; off += 16*512;
  float* qc_proj = ws + off; off += 16*512;
  float* WdT     = ws + off; off += 512*96;
  float* WuT     = ws + off; off += 96*512;
  float* hbuf    = ws + off; off += 8*1024;
  float* bA      = ws + off; off += (size_t)Mtok*512;   // kv rows -> ctx -> lny -> rn -> zhat rows -> phase2 scratch
  float* bK      = ws + off; off += (size_t)Mtok*512;
  float* bV      = ws + off; off += (size_t)Mtok*512;
  float* bH      = ws + off; off += (size_t)4096*1024;  // FFN hidden tile; also hosts bX
  float* bX      = bH;                                  // Mtok*96 = 12.6MB <= 16.8MB, used after FFN done
  // y / z_pred rows [Mtok,512] live in d_out (same element count); dead before tout overwrites d_out
  float* bY      = out;

  // phase-2 scratch carved inside bA (only used after tout consumes bA)
  float* p2q   = bA;
  float* p2Qp  = bA + 1048576;
  float* p2ctx = bA + 2*1048576;
  float* p2y   = bA + 3*1048576;
  float* p2lny = bA + 4*1048576;
  float* p2h   = bA + 5*1048576;          // 2048*1024
  float* p2r   = bA + 7*1048576;
  float* p2x   = bA + 8*1048576;          // 2048*96
  float* p2z   = bA + 8*1048576 + 196608;

  dim3 tpb32(32, 8);
  dim3 tgrid(Tdim/32, Cdim/32, Bsz);

  // ---- prep ----
  hipLaunchKernelGGL(pe_qc_kernel, dim3(16), dim3(256), 0, stream, pe_tab, qc_ln, lnq_g, lnq_b);
  hipLaunchKernelGGL(twd_kernel, dim3((96*512+255)/256), dim3(256), 0, stream, Wd, WdT);
  hipLaunchKernelGGL(twu_kernel, dim3((96*512+255)/256), dim3(256), 0, stream, Wu, WuT);
  hipLaunchKernelGGL(hb_kernel, dim3((NB*NE+255)/256), dim3(256), 0, stream, books, hbuf);

  // ---- phase 1: kv path ----
  hipLaunchKernelGGL(tin_kernel, tgrid, tpb32, 0, stream, qa, pe_tab, bA);
  hipLaunchKernelGGL(ln_rows_kernel, dim3(Mtok), dim3(256), 0, stream, bA, bA, lnkv_g, lnkv_b, 0, scale);
  hipLaunchKernelGGL(fgemm_kernel, dim3(4, Mtok/128), dim3(256), 0, stream, bA, Wk, bK, Mtok, 512, 512,
                     (const float*)nullptr, (const float*)nullptr, 0, 0);
  hipLaunchKernelGGL(fgemm_kernel, dim3(4, Mtok/128), dim3(256), 0, stream, bA, Wv, bV, Mtok, 512, 512,
                     (const float*)nullptr, (const float*)nullptr, 0, 0);
  hipLaunchKernelGGL(gemm_kernel, dim3(8, 1), dim3(256), 0, stream, qc_ln, Wq, qc_proj, 16, 512, 512,
                     (const float*)nullptr, (const float*)nullptr, 0, 0);

  // ---- phase 1: attention + Wo + FFN ----
  hipLaunchKernelGGL(attn1_kernel, dim3(M2tok), dim3(128), 0, stream, bK, bV, qc_proj, bA);
  hipLaunchKernelGGL(fgemm_kernel, dim3(4, Mtok/128), dim3(256), 0, stream, bA, Wo, bY, Mtok, 512, 512,
                     (const float*)nullptr, qc_ln, 1, 0);
  hipLaunchKernelGGL(ln_rows_kernel, dim3(Mtok), dim3(256), 0, stream, bY, bA, ffn_g, ffn_b, 0, scale);
  for (int p = 0; p < 8; p++){
    size_t mo = (size_t)p*4096;
    hipLaunchKernelGGL(fgemm_kernel, dim3(8, 4096/128), dim3(256), 0, stream, bA + mo*512, W1, bH, 4096, 1024, 512,
                       b1, (const float*)nullptr, 0, 1);
    hipLaunchKernelGGL(fgemm_kernel, dim3(4, 4096/128), dim3(256), 0, stream, bH, W2, bY + mo*512, 4096, 512, 1024,
                       b2, bY + mo*512, 2, 0);
  }

  // ---- phase 1: residual -> tanh LN -> Wd -> VQ -> Wu -> z_hat ----
  hipLaunchKernelGGL(resid_kernel, tgrid, tpb32, 0, stream, zt, bY, bA);
  hipLaunchKernelGGL(ln_rows_kernel, dim3(Mtok), dim3(256), 0, stream, bA, bA, tn_g, tn_b, 1, scale);
  hipLaunchKernelGGL(gemm_kernel, dim3(2, Mtok/64), dim3(256), 0, stream, bA, WdT, bX, Mtok, 96, 512,
                     bd, (const float*)nullptr, 0, 0);
  hipLaunchKernelGGL(vq_kernel<4>, dim3(Mtok/16), dim3(256), 0, stream, bX, books, hbuf);
  hipLaunchKernelGGL(fgemm_kernel, dim3(4, Mtok/128), dim3(256), 0, stream, bX, WuT, bA, Mtok, 512, 96,
                     bu, bY, 2, 0);
  hipLaunchKernelGGL(tout_kernel, tgrid, tpb32, 0, stream, bA, out);

  // ---- phase 2: token 0 of each chunk with true carries ----
  hipLaunchKernelGGL(q2_kernel, dim3(M2tok), dim3(256), 0, stream, out, p2q, lnq_g, lnq_b);
  hipLaunchKernelGGL(fgemm_kernel, dim3(4, M2tok/128), dim3(256), 0, stream, p2q, Wq, p2Qp, M2tok, 512, 512,
                     (const float*)nullptr, (const float*)nullptr, 0, 0);
  hipLaunchKernelGGL(attn2_kernel, dim3(M2tok), dim3(64), 0, stream, bK, bV, p2Qp, p2ctx);
  hipLaunchKernelGGL(fgemm_kernel, dim3(4, M2tok/128), dim3(256), 0, stream, p2ctx, Wo, p2y, M2tok, 512, 512,
                     (const float*)nullptr, p2q, 2, 0);
  hipLaunchKernelGGL(ln_rows_kernel, dim3(M2tok), dim3(256), 0, stream, p2y, p2lny, ffn_g, ffn_b, 0, scale);
  hipLaunchKernelGGL(fgemm_kernel, dim3(8, M2tok/128), dim3(256), 0, stream, p2lny, W1, p2h, M2tok, 1024, 512,
                     b1, (const float*)nullptr, 0, 1);
  hipLaunchKernelGGL(fgemm_kernel, dim3(4, M2tok/128), dim3(256), 0, stream, p2h, W2, p2y, M2tok, 512, 1024,
                     b2, p2y, 2, 0);
  hipLaunchKernelGGL(r2_kernel, dim3(M2tok), dim3(256), 0, stream, zt, p2y, p2r);
  hipLaunchKernelGGL(ln_rows_kernel, dim3(M2tok), dim3(256), 0, stream, p2r, p2r, tn_g, tn_b, 1, scale);
  hipLaunchKernelGGL(gemm_kernel, dim3(2, M2tok/64), dim3(256), 0, stream, p2r, WdT, p2x, M2tok, 96, 512,
                     bd, (const float*)nullptr, 0, 0);
  hipLaunchKernelGGL(vq_kernel<8>, dim3(M2tok/16), dim3(512), 0, stream, p2x, books, hbuf);
  hipLaunchKernelGGL(fgemm_kernel, dim3(4, M2tok/128), dim3(256), 0, stream, p2x, WuT, p2z, M2tok, 512, 96,
                     bu, p2y, 2, 0);
  hipLaunchKernelGGL(scatter2_kernel, dim3(M2tok), dim3(256), 0, stream, p2z, out);

  (void)in_sizes; (void)n_in; (void)out_size; (void)ws_size;
}

// Round 3
// 4993.423 us; speedup vs baseline: 1.5198x; 1.5198x over previous
//
#include <hip/hip_runtime.h>
#include <math.h>

#define Bsz 8
#define Cdim 512
#define Tdim 4096
#define NHq 8
#define CD 96
#define NB 8
#define NE 1024
#define NCHq 256
#define Mtok (Bsz*Tdim)     // 32768
#define M2tok (Bsz*NCHq)    // 2048

// ---------------- pe + constant query rows ----------------
__global__ __launch_bounds__(256) void pe_qc_kernel(float* pe_tab, float* qc_ln,
        const float* __restrict__ lnq_g, const float* __restrict__ lnq_b){
  int t = blockIdx.x;           // 0..15
  int tid = threadIdx.x;
  __shared__ float red[256];
  double f = -log(10000.0) / (double)Cdim;
  float v[2];
  #pragma unroll
  for (int u = 0; u < 2; ++u){
    int c = tid + u*256;
    int ce = c & ~1;
    double ang = (double)t * exp(f * (double)ce);
    v[u] = (float)((c & 1) ? cos(ang) : sin(ang));
    pe_tab[t*Cdim + c] = v[u];
  }
  red[tid] = v[0] + v[1]; __syncthreads();
  for (int s = 128; s > 0; s >>= 1){ if (tid < s) red[tid] += red[tid+s]; __syncthreads(); }
  float mean = red[0] * (1.f/512.f); __syncthreads();
  float d0 = v[0]-mean, d1 = v[1]-mean;
  red[tid] = d0*d0 + d1*d1; __syncthreads();
  for (int s = 128; s > 0; s >>= 1){ if (tid < s) red[tid] += red[tid+s]; __syncthreads(); }
  float rstd = 1.0f/sqrtf(red[0]*(1.f/512.f) + 1e-5f);
  qc_ln[t*Cdim + tid]       = d0*rstd*lnq_g[tid]     + lnq_b[tid];
  qc_ln[t*Cdim + tid + 256] = d1*rstd*lnq_g[tid+256] + lnq_b[tid+256];
}

// ---------------- generic row LayerNorm (rows of 512) ----------------
// mode 0: dst = norm*g+b ; mode 1: dst = tanh(norm*g+b)*clip(scale)
__global__ __launch_bounds__(256) void ln_rows_kernel(const float* __restrict__ src, float* __restrict__ dst,
        const float* __restrict__ g, const float* __restrict__ bia, int mode, const float* __restrict__ scale_ptr){
  int row = blockIdx.x; int tid = threadIdx.x;
  const float* sr = src + (size_t)row*Cdim;
  float v0 = sr[tid], v1 = sr[tid+256];
  __shared__ float red[256];
  red[tid] = v0+v1; __syncthreads();
  for (int s = 128; s > 0; s >>= 1){ if (tid < s) red[tid] += red[tid+s]; __syncthreads(); }
  float mean = red[0]*(1.f/512.f); __syncthreads();
  float d0 = v0-mean, d1 = v1-mean;
  red[tid] = d0*d0 + d1*d1; __syncthreads();
  for (int s = 128; s > 0; s >>= 1){ if (tid < s) red[tid] += red[tid+s]; __syncthreads(); }
  float rstd = 1.0f/sqrtf(red[0]*(1.f/512.f) + 1e-5f);
  float h0 = d0*rstd*g[tid]     + bia[tid];
  float h1 = d1*rstd*g[tid+256] + bia[tid+256];
  if (mode == 1){
    float sc = *scale_ptr; sc = fminf(fmaxf(sc, 0.005f), 0.5f);
    h0 = tanhf(h0)*sc; h1 = tanhf(h1)*sc;
  }
  float* dr = dst + (size_t)row*Cdim;
  dr[tid] = h0; dr[tid+256] = h1;
}

// ---------------- transposes [B,C,T] <-> token rows [B*T, C] ----------------
__global__ void tin_kernel(const float* __restrict__ qa, const float* __restrict__ pe_tab, float* __restrict__ rows){
  __shared__ float tile[32][33];
  int b = blockIdx.z, c0 = blockIdx.y*32, t0 = blockIdx.x*32;
  int tx = threadIdx.x, ty = threadIdx.y;
  int t = t0 + tx;
  #pragma unroll
  for (int j = 0; j < 4; j++){
    int c = c0 + ty + j*8;
    tile[ty+j*8][tx] = qa[((size_t)(b*Cdim + c))*Tdim + t] + pe_tab[(t & 15)*Cdim + c];
  }
  __syncthreads();
  #pragma unroll
  for (int j = 0; j < 4; j++){
    int tt = t0 + ty + j*8;
    rows[((size_t)(b*Tdim + tt))*Cdim + c0 + tx] = tile[tx][ty+j*8];
  }
}

__global__ void resid_kernel(const float* __restrict__ zt, const float* __restrict__ zp_rows, float* __restrict__ rows){
  __shared__ float tile[32][33];
  int b = blockIdx.z, c0 = blockIdx.y*32, t0 = blockIdx.x*32;
  int tx = threadIdx.x, ty = threadIdx.y;
  int t = t0 + tx;
  #pragma unroll
  for (int j = 0; j < 4; j++){
    int c = c0 + ty + j*8;
    tile[ty+j*8][tx] = zt[((size_t)(b*Cdim + c))*Tdim + t];
  }
  __syncthreads();
  #pragma unroll
  for (int j = 0; j < 4; j++){
    int tt = t0 + ty + j*8;
    size_t o = ((size_t)(b*Tdim + tt))*Cdim + c0 + tx;
    rows[o] = tile[tx][ty+j*8] - zp_rows[o];
  }
}

__global__ void tout_kernel(const float* __restrict__ rows, float* __restrict__ out){
  __shared__ float tile[32][33];
  int b = blockIdx.z, c0 = blockIdx.y*32, t0 = blockIdx.x*32;
  int tx = threadIdx.x, ty = threadIdx.y;
  #pragma unroll
  for (int j = 0; j < 4; j++){
    int tt = t0 + ty + j*8;
    tile[ty+j*8][tx] = rows[((size_t)(b*Tdim + tt))*Cdim + c0 + tx];
  }
  __syncthreads();
  #pragma unroll
  for (int j = 0; j < 4; j++){
    int c = c0 + ty + j*8;
    out[((size_t)(b*Cdim + c))*Tdim + t0 + tx] = tile[tx][ty+j*8];
  }
}

// ---------------- weight transposes ----------------
__global__ void twd_kernel(const float* __restrict__ Wd, float* __restrict__ WdT){ // Wd[96][512] -> WdT[512][96]
  int i = blockIdx.x*256 + threadIdx.x; if (i >= 96*512) return;
  int kq = i / 96, n = i % 96;
  WdT[i] = Wd[(size_t)n*512 + kq];
}
__global__ void twu_kernel(const float* __restrict__ Wu, float* __restrict__ WuT){ // Wu[512][96] -> WuT[96][512]
  int i = blockIdx.x*256 + threadIdx.x; if (i >= 96*512) return;
  int d = i / 512, c = i % 512;
  WuT[i] = Wu[(size_t)c*96 + d];
}

// ---------------- books[k][c][d] -> booksT[k][d][c] (tiled transpose) ----------------
__global__ void tbt_kernel(const float* __restrict__ books, float* __restrict__ booksT){
  __shared__ float tile[32][33];
  int k = blockIdx.z, d0 = blockIdx.y*32, c0 = blockIdx.x*32;
  int tx = threadIdx.x, ty = threadIdx.y;
  #pragma unroll
  for (int j = 0; j < 4; j++){
    int c = c0 + ty + j*8;
    tile[ty+j*8][tx] = books[((size_t)k*NE + c)*CD + d0 + tx];
  }
  __syncthreads();
  #pragma unroll
  for (int j = 0; j < 4; j++){
    int d = d0 + ty + j*8;
    booksT[(size_t)k*CD*NE + (size_t)d*NE + c0 + tx] = tile[tx][ty+j*8];
  }
}

// ---------------- 0.5*||e||^2 per codebook entry ----------------
__global__ void hb_kernel(const float* __restrict__ books, float* __restrict__ hb){
  int j = blockIdx.x*256 + threadIdx.x;
  if (j >= NB*NE) return;
  const float* e = books + (size_t)j*CD;
  float s = 0.f;
  #pragma unroll
  for (int d = 0; d < CD; d++) s = fmaf(e[d], e[d], s);
  hb[j] = 0.5f*s;
}

// ---------------- generic tiled fp32 GEMM (64x64 tile): odd shapes only ----------------
// addmode: 0 none, 1 addbuf[(m&15)*N+n], 2 addbuf[m*N+n]
__global__ __launch_bounds__(256) void gemm_kernel(const float* __restrict__ A, const float* __restrict__ Bm,
        float* __restrict__ Cm, int M, int N, int K,
        const float* __restrict__ bias, const float* __restrict__ addbuf, int addmode, int act){
  __shared__ float As[16][65];
  __shared__ float Bs[16][64];
  int l = threadIdx.x;
  int tx = l & 15, ty = l >> 4;
  int m0 = blockIdx.y*64, n0 = blockIdx.x*64;
  int ai = l >> 2, ak = (l & 3)*4;
  int bk = l >> 4, bj = (l & 15)*4;
  float acc[4][4] = {{0.f}};
  bool nfull = (n0 + 64 <= N);
  for (int k0 = 0; k0 < K; k0 += 16){
    float4 av = make_float4(0.f, 0.f, 0.f, 0.f);
    if (m0 + ai < M) av = *(const float4*)(A + (size_t)(m0+ai)*K + k0 + ak);
    As[ak][ai] = av.x; As[ak+1][ai] = av.y; As[ak+2][ai] = av.z; As[ak+3][ai] = av.w;
    if (nfull){
      *(float4*)(&Bs[bk][bj]) = *(const float4*)(Bm + (size_t)(k0+bk)*N + n0 + bj);
    } else {
      #pragma unroll
      for (int u = 0; u < 4; u++){
        int n = n0 + bj + u;
        Bs[bk][bj+u] = (n < N) ? Bm[(size_t)(k0+bk)*N + n] : 0.f;
      }
    }
    __syncthreads();
    #pragma unroll
    for (int kk = 0; kk < 16; kk++){
      float a0 = As[kk][ty*4], a1 = As[kk][ty*4+1], a2 = As[kk][ty*4+2], a3 = As[kk][ty*4+3];
      float b0 = Bs[kk][tx*4], b1 = Bs[kk][tx*4+1], b2 = Bs[kk][tx*4+2], b3 = Bs[kk][tx*4+3];
      acc[0][0] = fmaf(a0,b0,acc[0][0]); acc[0][1] = fmaf(a0,b1,acc[0][1]);
      acc[0][2] = fmaf(a0,b2,acc[0][2]); acc[0][3] = fmaf(a0,b3,acc[0][3]);
      acc[1][0] = fmaf(a1,b0,acc[1][0]); acc[1][1] = fmaf(a1,b1,acc[1][1]);
      acc[1][2] = fmaf(a1,b2,acc[1][2]); acc[1][3] = fmaf(a1,b3,acc[1][3]);
      acc[2][0] = fmaf(a2,b0,acc[2][0]); acc[2][1] = fmaf(a2,b1,acc[2][1]);
      acc[2][2] = fmaf(a2,b2,acc[2][2]); acc[2][3] = fmaf(a2,b3,acc[2][3]);
      acc[3][0] = fmaf(a3,b0,acc[3][0]); acc[3][1] = fmaf(a3,b1,acc[3][1]);
      acc[3][2] = fmaf(a3,b2,acc[3][2]); acc[3][3] = fmaf(a3,b3,acc[3][3]);
    }
    __syncthreads();
  }
  #pragma unroll
  for (int r = 0; r < 4; r++){
    int m = m0 + ty*4 + r; if (m >= M) continue;
    #pragma unroll
    for (int c = 0; c < 4; c++){
      int n = n0 + tx*4 + c; if (n >= N) continue;
      float v = acc[r][c];
      if (bias) v += bias[n];
      if (act == 1) v = 0.5f*v*(1.0f + erff(v*0.7071067811865475f));
      if (addmode == 1) v += addbuf[(size_t)(m & 15)*N + n];
      else if (addmode == 2) v += addbuf[(size_t)m*N + n];
      Cm[(size_t)m*N + n] = v;
    }
  }
}

// ---------------- fast fp32 GEMM: 128x128 tile, 8x8 acc/thread ----------------
// requires M%128==0, N%128==0, K%16==0
__global__ __launch_bounds__(256) void fgemm_kernel(const float* __restrict__ A, const float* __restrict__ Bm,
        float* __restrict__ Cm, int M, int N, int K,
        const float* __restrict__ bias, const float* __restrict__ addbuf, int addmode, int act){
  __shared__ float As[16][128];
  __shared__ float Bs[16][128];
  int l = threadIdx.x;
  int tx = l & 15, ty = l >> 4;          // 16x16 thread grid
  int m0 = blockIdx.y*128, n0 = blockIdx.x*128;
  int ar = l >> 1, ac = (l & 1) * 8;     // A staging: 128 rows x 16 cols, 2 thr/row
  int br = l >> 4, bc = (l & 15) * 8;    // B staging: 16 rows x 128 cols
  float acc[8][8] = {{0.f}};
  const float* Aptr = A + (size_t)(m0 + ar)*K + ac;
  const float* Bptr = Bm + (size_t)br*N + n0 + bc;
  for (int k0 = 0; k0 < K; k0 += 16){
    float4 a0 = *(const float4*)(Aptr + k0);
    float4 a1 = *(const float4*)(Aptr + k0 + 4);
    float4 bv0 = *(const float4*)(Bptr + (size_t)k0*N);
    float4 bv1 = *(const float4*)(Bptr + (size_t)k0*N + 4);
    As[ac+0][ar]=a0.x; As[ac+1][ar]=a0.y; As[ac+2][ar]=a0.z; As[ac+3][ar]=a0.w;
    As[ac+4][ar]=a1.x; As[ac+5][ar]=a1.y; As[ac+6][ar]=a1.z; As[ac+7][ar]=a1.w;
    *(float4*)(&Bs[br][bc])   = bv0;
    *(float4*)(&Bs[br][bc+4]) = bv1;
    __syncthreads();
    #pragma unroll
    for (int kk = 0; kk < 16; kk++){
      float av[8], bw[8];
      *(float4*)(av)   = *(const float4*)(&As[kk][ty*4]);
      *(float4*)(av+4) = *(const float4*)(&As[kk][64 + ty*4]);
      *(float4*)(bw)   = *(const float4*)(&Bs[kk][tx*4]);
      *(float4*)(bw+4) = *(const float4*)(&Bs[kk][64 + tx*4]);
      #pragma unroll
      for (int i = 0; i < 8; i++)
        #pragma unroll
        for (int j = 0; j < 8; j++)
          acc[i][j] = fmaf(av[i], bw[j], acc[i][j]);
    }
    __syncthreads();
  }
  #pragma unroll
  for (int i = 0; i < 8; i++){
    int m = m0 + ((i < 4) ? (ty*4 + i) : (64 + ty*4 + i - 4));
    #pragma unroll
    for (int jh = 0; jh < 2; jh++){
      int nb = n0 + jh*64 + tx*4;
      float v[4];
      #pragma unroll
      for (int j = 0; j < 4; j++){
        float u = acc[i][jh*4 + j];
        int n = nb + j;
        if (bias) u += bias[n];
        if (act == 1) u = 0.5f*u*(1.0f + erff(u*0.7071067811865475f));
        if (addmode == 1) u += addbuf[(size_t)(m & 15)*N + n];
        else if (addmode == 2) u += addbuf[(size_t)m*N + n];
        v[j] = u;
      }
      *(float4*)(Cm + (size_t)m*N + nb) = *(float4*)v;
    }
  }
}

// ---------------- attention, phase 1: 16 const queries x 16 keys per (b,chunk) ----------------
__global__ __launch_bounds__(128) void attn1_kernel(const float* __restrict__ Kb, const float* __restrict__ Vb,
        const float* __restrict__ Qp, float* __restrict__ ctxb){
  int idx = blockIdx.x;                 // b*256 + ch
  int b = idx >> 8, ch = idx & 255;
  size_t m0 = (size_t)b*Tdim + ch*16;
  int t = threadIdx.x >> 3, h = threadIdx.x & 7;
  const float* q = Qp + t*Cdim + h*64;
  float qr[64];
  #pragma unroll
  for (int d = 0; d < 64; d += 4){ float4 f = *(const float4*)(q+d); qr[d]=f.x; qr[d+1]=f.y; qr[d+2]=f.z; qr[d+3]=f.w; }
  float s[16];
  #pragma unroll
  for (int k = 0; k < 16; k++){
    const float* kr = Kb + (m0+k)*Cdim + h*64;
    float acc = 0.f;
    #pragma unroll
    for (int d = 0; d < 64; d += 4){
      float4 f = *(const float4*)(kr+d);
      acc = fmaf(qr[d],f.x,acc); acc = fmaf(qr[d+1],f.y,acc);
      acc = fmaf(qr[d+2],f.z,acc); acc = fmaf(qr[d+3],f.w,acc);
    }
    s[k] = acc * 0.125f;
  }
  float mx = s[0];
  #pragma unroll
  for (int k = 1; k < 16; k++) mx = fmaxf(mx, s[k]);
  float sum = 0.f;
  #pragma unroll
  for (int k = 0; k < 16; k++){ s[k] = expf(s[k]-mx); sum += s[k]; }
  float inv = 1.0f/sum;
  float ctx[64];
  #pragma unroll
  for (int d = 0; d < 64; d++) ctx[d] = 0.f;
  #pragma unroll
  for (int k = 0; k < 16; k++){
    float p = s[k]*inv;
    const float* vr = Vb + (m0+k)*Cdim + h*64;
    #pragma unroll
    for (int d = 0; d < 64; d += 4){
      float4 f = *(const float4*)(vr+d);
      ctx[d]=fmaf(p,f.x,ctx[d]); ctx[d+1]=fmaf(p,f.y,ctx[d+1]);
      ctx[d+2]=fmaf(p,f.z,ctx[d+2]); ctx[d+3]=fmaf(p,f.w,ctx[d+3]);
    }
  }
  float* o = ctxb + (m0+t)*Cdim + h*64;
  #pragma unroll
  for (int d = 0; d < 64; d += 4){
    float4 f; f.x=ctx[d]; f.y=ctx[d+1]; f.z=ctx[d+2]; f.w=ctx[d+3];
    *(float4*)(o+d) = f;
  }
}

// ---------------- attention, phase 2: 1 query (token 0) per (b,chunk) ----------------
__global__ __launch_bounds__(64) void attn2_kernel(const float* __restrict__ Kb, const float* __restrict__ Vb,
        const float* __restrict__ Qp, float* __restrict__ ctxb){
  int m2 = blockIdx.x;                 // b*256 + ch
  int b = m2 >> 8, ch = m2 & 255;
  size_t m0 = (size_t)b*Tdim + ch*16;
  int h = threadIdx.x;
  if (h >= 8) return;
  const float* q = Qp + (size_t)m2*Cdim + h*64;
  float qr[64];
  #pragma unroll
  for (int d = 0; d < 64; d += 4){ float4 f = *(const float4*)(q+d); qr[d]=f.x; qr[d+1]=f.y; qr[d+2]=f.z; qr[d+3]=f.w; }
  float s[16];
  #pragma unroll
  for (int k = 0; k < 16; k++){
    const float* kr = Kb + (m0+k)*Cdim + h*64;
    float acc = 0.f;
    #pragma unroll
    for (int d = 0; d < 64; d += 4){
      float4 f = *(const float4*)(kr+d);
      acc = fmaf(qr[d],f.x,acc); acc = fmaf(qr[d+1],f.y,acc);
      acc = fmaf(qr[d+2],f.z,acc); acc = fmaf(qr[d+3],f.w,acc);
    }
    s[k] = acc * 0.125f;
  }
  float mx = s[0];
  #pragma unroll
  for (int k = 1; k < 16; k++) mx = fmaxf(mx, s[k]);
  float sum = 0.f;
  #pragma unroll
  for (int k = 0; k < 16; k++){ s[k] = expf(s[k]-mx); sum += s[k]; }
  float inv = 1.0f/sum;
  float ctx[64];
  #pragma unroll
  for (int d = 0; d < 64; d++) ctx[d] = 0.f;
  #pragma unroll
  for (int k = 0; k < 16; k++){
    float p = s[k]*inv;
    const float* vr = Vb + (m0+k)*Cdim + h*64;
    #pragma unroll
    for (int d = 0; d < 64; d += 4){
      float4 f = *(const float4*)(vr+d);
      ctx[d]=fmaf(p,f.x,ctx[d]); ctx[d+1]=fmaf(p,f.y,ctx[d+1]);
      ctx[d+2]=fmaf(p,f.z,ctx[d+2]); ctx[d+3]=fmaf(p,f.w,ctx[d+3]);
    }
  }
  float* o = ctxb + (size_t)m2*Cdim + h*64;
  #pragma unroll
  for (int d = 0; d < 64; d += 4){
    float4 f; f.x=ctx[d]; f.y=ctx[d+1]; f.z=ctx[d+2]; f.w=ctx[d+3];
    *(float4*)(o+d) = f;
  }
}

// ---------------- phase 2: build token-0 query rows (carry + pe[:,0], LN) ----------------
__global__ __launch_bounds__(256) void q2_kernel(const float* __restrict__ dout, float* __restrict__ p2q,
        const float* __restrict__ g, const float* __restrict__ bia){
  int m2 = blockIdx.x; int tid = threadIdx.x;
  int b = m2 >> 8, ch = m2 & 255;
  int tprev = ch*16 - 1;
  float v0, v1;
  {
    int c = tid;
    float carry = (ch == 0) ? 0.f : dout[((size_t)(b*Cdim + c))*Tdim + tprev];
    v0 = carry + ((c & 1) ? 1.f : 0.f);     // pe[c,0] = c even ? sin(0)=0 : cos(0)=1
  }
  {
    int c = tid + 256;
    float carry = (ch == 0) ? 0.f : dout[((size_t)(b*Cdim + c))*Tdim + tprev];
    v1 = carry + ((c & 1) ? 1.f : 0.f);
  }
  __shared__ float red[256];
  red[tid] = v0+v1; __syncthreads();
  for (int s = 128; s > 0; s >>= 1){ if (tid < s) red[tid] += red[tid+s]; __syncthreads(); }
  float mean = red[0]*(1.f/512.f); __syncthreads();
  float d0 = v0-mean, d1 = v1-mean;
  red[tid] = d0*d0 + d1*d1; __syncthreads();
  for (int s = 128; s > 0; s >>= 1){ if (tid < s) red[tid] += red[tid+s]; __syncthreads(); }
  float rstd = 1.0f/sqrtf(red[0]*(1.f/512.f) + 1e-5f);
  p2q[(size_t)m2*Cdim + tid]       = d0*rstd*g[tid]     + bia[tid];
  p2q[(size_t)m2*Cdim + tid + 256] = d1*rstd*g[tid+256] + bia[tid+256];
}

// ---------------- phase 2: r = zt[:, :, t0] - z_pred0 ----------------
__global__ __launch_bounds__(256) void r2_kernel(const float* __restrict__ zt, const float* __restrict__ zp,
        float* __restrict__ out){
  int m2 = blockIdx.x; int tid = threadIdx.x;
  int b = m2 >> 8, ch = m2 & 255; int t0 = ch*16;
  #pragma unroll
  for (int u = 0; u < 2; u++){
    int c = tid + u*256;
    out[(size_t)m2*Cdim + c] = zt[((size_t)(b*Cdim + c))*Tdim + t0] - zp[(size_t)m2*Cdim + c];
  }
}

// ---------------- phase 2: scatter z_hat token-0 columns into d_out ----------------
__global__ __launch_bounds__(256) void scatter2_kernel(const float* __restrict__ z, float* __restrict__ dout){
  int m2 = blockIdx.x; int tid = threadIdx.x;
  int b = m2 >> 8, ch = m2 & 255; int t0 = ch*16;
  #pragma unroll
  for (int u = 0; u < 2; u++){
    int c = tid + u*256;
    dout[((size_t)(b*Cdim + c))*Tdim + t0] = z[(size_t)m2*Cdim + c];
  }
}

// ---------------- residual VQ as LDS-staged GEMM (fgemm geometry) ----------------
// Per book: scores = res[MT,96] @ E^T[96,1024] done in 128-candidate tiles with
// 8x8 (or 4x8) register blocking -> each LDS byte feeds 64 FMAs (prev layouts fed <=2).
// res lives in LDS As[96][MT] (transposed), updated in place per book.
// E^T tile staged coalesced from precomputed booksT. Argmax: per-thread running best
// (strict > over ascending own candidates) then cross-thread merge (score>, idx< on tie)
// == exact jnp.argmax first-max rule. 256 threads; MT=128 (phase1) / 64 (phase2).
template<int MT>
__global__ __launch_bounds__(256, 1) void vqg_kernel(float* __restrict__ x,
        const float* __restrict__ books, const float* __restrict__ booksT,
        const float* __restrict__ hb){
  constexpr int MI  = MT/16;    // acc rows per thread (8 or 4)
  constexpr int TPT = 256/MT;   // threads per token (2 or 4)
  constexpr int F4  = 24/TPT;   // float4 slices of a token per thread (12 or 6)
  int l = threadIdx.x;
  int tx = l & 15, ty = l >> 4;
  int tok = l / TPT, part = l % TPT;
  size_t tok0 = (size_t)blockIdx.x * MT;
  __shared__ float As[96][MT];    // res^T
  __shared__ float Es[96][128];   // E^T candidate tile
  __shared__ float hs[128];
  __shared__ float sb[MT][16];
  __shared__ int   si[MT][16];
  __shared__ int   sel[MT];
  float* xp = x + (tok0 + tok)*CD;
  // stage res^T = x^T
  #pragma unroll
  for (int j = 0; j < F4; j++){
    int d4 = part*F4 + j;
    float4 v = *(const float4*)(xp + d4*4);
    As[d4*4+0][tok]=v.x; As[d4*4+1][tok]=v.y; As[d4*4+2][tok]=v.z; As[d4*4+3][tok]=v.w;
  }
  for (int k = 0; k < NB; k++){
    const float* bT = booksT + (size_t)k*CD*NE;
    float best[MI]; int bidx[MI];
    #pragma unroll
    for (int i = 0; i < MI; i++){ best[i] = -3.0e38f; bidx[i] = 0; }
    for (int t = 0; t < 8; t++){
      int n0 = t*128;
      __syncthreads();                 // also orders As writes (init/update) before reads
      #pragma unroll
      for (int j = 0; j < 12; j++){    // stage 96x128 E^T tile, coalesced
        int f4 = j*256 + l;
        int d = f4 >> 5, c4 = f4 & 31;
        float4 v = *(const float4*)(bT + (size_t)d*NE + n0 + c4*4);
        *(float4*)(&Es[d][c4*4]) = v;
      }
      if (l < 32){
        float4 hv = *(const float4*)(hb + k*NE + n0 + l*4);
        *(float4*)(&hs[l*4]) = hv;
      }
      __syncthreads();
      float acc[MI][8];
      #pragma unroll
      for (int i = 0; i < MI; i++)
        #pragma unroll
        for (int j = 0; j < 8; j++) acc[i][j] = 0.f;
      #pragma unroll 2
      for (int kk = 0; kk < 96; kk++){
        float av[MI], bw[8];
        #pragma unroll
        for (int g = 0; g < MI/4; g++)
          *(float4*)(av + g*4) = *(const float4*)(&As[kk][g*64 + ty*4]);
        *(float4*)(bw)   = *(const float4*)(&Es[kk][tx*4]);
        *(float4*)(bw+4) = *(const float4*)(&Es[kk][64 + tx*4]);
        #pragma unroll
        for (int i = 0; i < MI; i++)
          #pragma unroll
          for (int j = 0; j < 8; j++)
            acc[i][j] = fmaf(av[i], bw[j], acc[i][j]);
      }
      #pragma unroll
      for (int i = 0; i < MI; i++){
        #pragma unroll
        for (int j = 0; j < 8; j++){
          int cl = (j>>2)*64 + tx*4 + (j&3);     // ascending within thread
          float s = acc[i][j] - hs[cl];
          if (s > best[i]){ best[i] = s; bidx[i] = n0 + cl; }
        }
      }
    }
    // cross-thread argmax merge (16 tx partials per token row)
    #pragma unroll
    for (int i = 0; i < MI; i++){
      int row = (i>>2)*64 + ty*4 + (i&3);
      sb[row][tx] = best[i]; si[row][tx] = bidx[i];
    }
    __syncthreads();
    if (l < MT){
      float bb = sb[l][0]; int bi = si[l][0];
      #pragma unroll
      for (int t2 = 1; t2 < 16; t2++){
        float b2 = sb[l][t2]; int i2 = si[l][t2];
        if (b2 > bb || (b2 == bb && i2 < bi)){ bb = b2; bi = i2; }
      }
      sel[l] = bi;
    }
    __syncthreads();
    // res -= E[k][sel]
    int s = sel[tok];
    const float* e = books + ((size_t)k*NE + s)*CD;
    #pragma unroll
    for (int j = 0; j < F4; j++){
      int d4 = part*F4 + j;
      float4 v = *(const float4*)(e + d4*4);
      As[d4*4+0][tok] -= v.x; As[d4*4+1][tok] -= v.y;
      As[d4*4+2][tok] -= v.z; As[d4*4+3][tok] -= v.w;
    }
  }
  // q_sum = x - res_final (thread reads exactly the cells it wrote -> no barrier)
  #pragma unroll
  for (int j = 0; j < F4; j++){
    int d4 = part*F4 + j;
    float4 xo = *(const float4*)(xp + d4*4);
    float4 q;
    q.x = xo.x - As[d4*4+0][tok];
    q.y = xo.y - As[d4*4+1][tok];
    q.z = xo.z - As[d4*4+2][tok];
    q.w = xo.w - As[d4*4+3][tok];
    *(float4*)(xp + d4*4) = q;
  }
}

// ---------------- host ----------------
extern "C" void kernel_launch(void* const* d_in, const int* in_sizes, int n_in,
                              void* d_out, int out_size, void* d_ws, size_t ws_size,
                              hipStream_t stream) {
  const float* qa    = (const float*)d_in[0];
  const float* zt    = (const float*)d_in[1];
  const float* lnq_g = (const float*)d_in[2];
  const float* lnq_b = (const float*)d_in[3];
  const float* lnkv_g= (const float*)d_in[4];
  const float* lnkv_b= (const float*)d_in[5];
  const float* Wq    = (const float*)d_in[6];
  const float* Wk    = (const float*)d_in[7];
  const float* Wv    = (const float*)d_in[8];
  const float* Wo    = (const float*)d_in[9];
  const float* ffn_g = (const float*)d_in[10];
  const float* ffn_b = (const float*)d_in[11];
  const float* W1    = (const float*)d_in[12];
  const float* b1    = (const float*)d_in[13];
  const float* W2    = (const float*)d_in[14];
  const float* b2    = (const float*)d_in[15];
  const float* tn_g  = (const float*)d_in[16];
  const float* tn_b  = (const float*)d_in[17];
  const float* scale = (const float*)d_in[18];
  const float* Wd    = (const float*)d_in[19];
  const float* bd    = (const float*)d_in[20];
  const float* Wu    = (const float*)d_in[21];
  const float* bu    = (const float*)d_in[22];
  const float* books = (const float*)d_in[23];
  float* out = (float*)d_out;

  // ---- workspace layout (total ~208.5 MiB) ----
  float* ws = (float*)d_ws;
  size_t off = 0;
  float* pe_tab  = ws + off; off += 16*512;
  float* qc_ln   = ws + off; off += 16*512;
  float* qc_proj = ws + off; off += 16*512;
  float* WdT     = ws + off; off += 512*96;
  float* WuT     = ws + off; off += 96*512;
  float* hbuf    = ws + off; off += 8*1024;
  float* bA      = ws + off; off += (size_t)Mtok*512;   // kv rows -> ctx -> lny -> rn -> zhat rows -> phase2 scratch
  float* bK      = ws + off; off += (size_t)Mtok*512;
  float* bV      = ws + off; off += (size_t)Mtok*512;
  float* bH      = ws + off; off += (size_t)4096*1024;  // FFN hidden tile; also hosts bX + booksT
  float* bX      = bH;                                  // Mtok*96 = 12.6MB
  float* booksTp = bH + (size_t)Mtok*CD;                // 3MB in bH's spare tail (16.8 - 12.6 = 4.2MB)
  // y / z_pred rows [Mtok,512] live in d_out (same element count); dead before tout overwrites d_out
  float* bY      = out;

  // phase-2 scratch carved inside bA (only used after tout consumes bA)
  float* p2q   = bA;
  float* p2Qp  = bA + 1048576;
  float* p2ctx = bA + 2*1048576;
  float* p2y   = bA + 3*1048576;
  float* p2lny = bA + 4*1048576;
  float* p2h   = bA + 5*1048576;          // 2048*1024
  float* p2r   = bA + 7*1048576;
  float* p2x   = bA + 8*1048576;          // 2048*96
  float* p2z   = bA + 8*1048576 + 196608;

  dim3 tpb32(32, 8);
  dim3 tgrid(Tdim/32, Cdim/32, Bsz);

  // ---- prep ----
  hipLaunchKernelGGL(pe_qc_kernel, dim3(16), dim3(256), 0, stream, pe_tab, qc_ln, lnq_g, lnq_b);
  hipLaunchKernelGGL(twd_kernel, dim3((96*512+255)/256), dim3(256), 0, stream, Wd, WdT);
  hipLaunchKernelGGL(twu_kernel, dim3((96*512+255)/256), dim3(256), 0, stream, Wu, WuT);
  hipLaunchKernelGGL(hb_kernel, dim3((NB*NE+255)/256), dim3(256), 0, stream, books, hbuf);

  // ---- phase 1: kv path ----
  hipLaunchKernelGGL(tin_kernel, tgrid, tpb32, 0, stream, qa, pe_tab, bA);
  hipLaunchKernelGGL(ln_rows_kernel, dim3(Mtok), dim3(256), 0, stream, bA, bA, lnkv_g, lnkv_b, 0, scale);
  hipLaunchKernelGGL(fgemm_kernel, dim3(4, Mtok/128), dim3(256), 0, stream, bA, Wk, bK, Mtok, 512, 512,
                     (const float*)nullptr, (const float*)nullptr, 0, 0);
  hipLaunchKernelGGL(fgemm_kernel, dim3(4, Mtok/128), dim3(256), 0, stream, bA, Wv, bV, Mtok, 512, 512,
                     (const float*)nullptr, (const float*)nullptr, 0, 0);
  hipLaunchKernelGGL(gemm_kernel, dim3(8, 1), dim3(256), 0, stream, qc_ln, Wq, qc_proj, 16, 512, 512,
                     (const float*)nullptr, (const float*)nullptr, 0, 0);

  // ---- phase 1: attention + Wo + FFN ----
  hipLaunchKernelGGL(attn1_kernel, dim3(M2tok), dim3(128), 0, stream, bK, bV, qc_proj, bA);
  hipLaunchKernelGGL(fgemm_kernel, dim3(4, Mtok/128), dim3(256), 0, stream, bA, Wo, bY, Mtok, 512, 512,
                     (const float*)nullptr, qc_ln, 1, 0);
  hipLaunchKernelGGL(ln_rows_kernel, dim3(Mtok), dim3(256), 0, stream, bY, bA, ffn_g, ffn_b, 0, scale);
  for (int p = 0; p < 8; p++){
    size_t mo = (size_t)p*4096;
    hipLaunchKernelGGL(fgemm_kernel, dim3(8, 4096/128), dim3(256), 0, stream, bA + mo*512, W1, bH, 4096, 1024, 512,
                       b1, (const float*)nullptr, 0, 1);
    hipLaunchKernelGGL(fgemm_kernel, dim3(4, 4096/128), dim3(256), 0, stream, bH, W2, bY + mo*512, 4096, 512, 1024,
                       b2, bY + mo*512, 2, 0);
  }

  // ---- phase 1: residual -> tanh LN -> Wd -> VQ -> Wu -> z_hat ----
  hipLaunchKernelGGL(resid_kernel, tgrid, tpb32, 0, stream, zt, bY, bA);
  hipLaunchKernelGGL(ln_rows_kernel, dim3(Mtok), dim3(256), 0, stream, bA, bA, tn_g, tn_b, 1, scale);
  hipLaunchKernelGGL(gemm_kernel, dim3(2, Mtok/64), dim3(256), 0, stream, bA, WdT, bX, Mtok, 96, 512,
                     bd, (const float*)nullptr, 0, 0);
  hipLaunchKernelGGL(tbt_kernel, dim3(NE/32, CD/32, NB), tpb32, 0, stream, books, booksTp);
  hipLaunchKernelGGL(vqg_kernel<128>, dim3(Mtok/128), dim3(256), 0, stream, bX, books, booksTp, hbuf);
  hipLaunchKernelGGL(fgemm_kernel, dim3(4, Mtok/128), dim3(256), 0, stream, bX, WuT, bA, Mtok, 512, 96,
                     bu, bY, 2, 0);
  hipLaunchKernelGGL(tout_kernel, tgrid, tpb32, 0, stream, bA, out);

  // ---- phase 2: token 0 of each chunk with true carries ----
  hipLaunchKernelGGL(q2_kernel, dim3(M2tok), dim3(256), 0, stream, out, p2q, lnq_g, lnq_b);
  hipLaunchKernelGGL(fgemm_kernel, dim3(4, M2tok/128), dim3(256), 0, stream, p2q, Wq, p2Qp, M2tok, 512, 512,
                     (const float*)nullptr, (const float*)nullptr, 0, 0);
  hipLaunchKernelGGL(attn2_kernel, dim3(M2tok), dim3(64), 0, stream, bK, bV, p2Qp, p2ctx);
  hipLaunchKernelGGL(fgemm_kernel, dim3(4, M2tok/128), dim3(256), 0, stream, p2ctx, Wo, p2y, M2tok, 512, 512,
                     (const float*)nullptr, p2q, 2, 0);
  hipLaunchKernelGGL(ln_rows_kernel, dim3(M2tok), dim3(256), 0, stream, p2y, p2lny, ffn_g, ffn_b, 0, scale);
  hipLaunchKernelGGL(fgemm_kernel, dim3(8, M2tok/128), dim3(256), 0, stream, p2lny, W1, p2h, M2tok, 1024, 512,
                     b1, (const float*)nullptr, 0, 1);
  hipLaunchKernelGGL(fgemm_kernel, dim3(4, M2tok/128), dim3(256), 0, stream, p2h, W2, p2y, M2tok, 512, 1024,
                     b2, p2y, 2, 0);
  hipLaunchKernelGGL(r2_kernel, dim3(M2tok), dim3(256), 0, stream, zt, p2y, p2r);
  hipLaunchKernelGGL(ln_rows_kernel, dim3(M2tok), dim3(256), 0, stream, p2r, p2r, tn_g, tn_b, 1, scale);
  hipLaunchKernelGGL(gemm_kernel, dim3(2, M2tok/64), dim3(256), 0, stream, p2r, WdT, p2x, M2tok, 96, 512,
                     bd, (const float*)nullptr, 0, 0);
  hipLaunchKernelGGL(vqg_kernel<64>, dim3(M2tok/64), dim3(256), 0, stream, p2x, books, booksTp, hbuf);
  hipLaunchKernelGGL(fgemm_kernel, dim3(4, M2tok/128), dim3(256), 0, stream, p2x, WuT, p2z, M2tok, 512, 96,
                     bu, p2y, 2, 0);
  hipLaunchKernelGGL(scatter2_kernel, dim3(M2tok), dim3(256), 0, stream, p2z, out);

  (void)in_sizes; (void)n_in; (void)out_size; (void)ws_size;
}

// Round 4
// 3733.249 us; speedup vs baseline: 2.0329x; 1.3376x over previous
//
#include <hip/hip_runtime.h>
#include <math.h>

#define Bsz 8
#define Cdim 512
#define Tdim 4096
#define NHq 8
#define CD 96
#define NB 8
#define NE 1024
#define NCHq 256
#define Mtok (Bsz*Tdim)     // 32768
#define M2tok (Bsz*NCHq)    // 2048

typedef __attribute__((ext_vector_type(8))) short bf16x8;
typedef __attribute__((ext_vector_type(4))) float f32x4;
typedef unsigned int uint;
typedef unsigned short ushort;

// ---------------- pe + constant query rows ----------------
__global__ __launch_bounds__(256) void pe_qc_kernel(float* pe_tab, float* qc_ln,
        const float* __restrict__ lnq_g, const float* __restrict__ lnq_b){
  int t = blockIdx.x;           // 0..15
  int tid = threadIdx.x;
  __shared__ float red[256];
  double f = -log(10000.0) / (double)Cdim;
  float v[2];
  #pragma unroll
  for (int u = 0; u < 2; ++u){
    int c = tid + u*256;
    int ce = c & ~1;
    double ang = (double)t * exp(f * (double)ce);
    v[u] = (float)((c & 1) ? cos(ang) : sin(ang));
    pe_tab[t*Cdim + c] = v[u];
  }
  red[tid] = v[0] + v[1]; __syncthreads();
  for (int s = 128; s > 0; s >>= 1){ if (tid < s) red[tid] += red[tid+s]; __syncthreads(); }
  float mean = red[0] * (1.f/512.f); __syncthreads();
  float d0 = v[0]-mean, d1 = v[1]-mean;
  red[tid] = d0*d0 + d1*d1; __syncthreads();
  for (int s = 128; s > 0; s >>= 1){ if (tid < s) red[tid] += red[tid+s]; __syncthreads(); }
  float rstd = 1.0f/sqrtf(red[0]*(1.f/512.f) + 1e-5f);
  qc_ln[t*Cdim + tid]       = d0*rstd*lnq_g[tid]     + lnq_b[tid];
  qc_ln[t*Cdim + tid + 256] = d1*rstd*lnq_g[tid+256] + lnq_b[tid+256];
}

// ---------------- generic row LayerNorm (rows of 512) ----------------
// mode 0: dst = norm*g+b ; mode 1: dst = tanh(norm*g+b)*clip(scale)
__global__ __launch_bounds__(256) void ln_rows_kernel(const float* __restrict__ src, float* __restrict__ dst,
        const float* __restrict__ g, const float* __restrict__ bia, int mode, const float* __restrict__ scale_ptr){
  int row = blockIdx.x; int tid = threadIdx.x;
  const float* sr = src + (size_t)row*Cdim;
  float v0 = sr[tid], v1 = sr[tid+256];
  __shared__ float red[256];
  red[tid] = v0+v1; __syncthreads();
  for (int s = 128; s > 0; s >>= 1){ if (tid < s) red[tid] += red[tid+s]; __syncthreads(); }
  float mean = red[0]*(1.f/512.f); __syncthreads();
  float d0 = v0-mean, d1 = v1-mean;
  red[tid] = d0*d0 + d1*d1; __syncthreads();
  for (int s = 128; s > 0; s >>= 1){ if (tid < s) red[tid] += red[tid+s]; __syncthreads(); }
  float rstd = 1.0f/sqrtf(red[0]*(1.f/512.f) + 1e-5f);
  float h0 = d0*rstd*g[tid]     + bia[tid];
  float h1 = d1*rstd*g[tid+256] + bia[tid+256];
  if (mode == 1){
    float sc = *scale_ptr; sc = fminf(fmaxf(sc, 0.005f), 0.5f);
    h0 = tanhf(h0)*sc; h1 = tanhf(h1)*sc;
  }
  float* dr = dst + (size_t)row*Cdim;
  dr[tid] = h0; dr[tid+256] = h1;
}

// ---------------- transposes [B,C,T] <-> token rows [B*T, C] ----------------
__global__ void tin_kernel(const float* __restrict__ qa, const float* __restrict__ pe_tab, float* __restrict__ rows){
  __shared__ float tile[32][33];
  int b = blockIdx.z, c0 = blockIdx.y*32, t0 = blockIdx.x*32;
  int tx = threadIdx.x, ty = threadIdx.y;
  int t = t0 + tx;
  #pragma unroll
  for (int j = 0; j < 4; j++){
    int c = c0 + ty + j*8;
    tile[ty+j*8][tx] = qa[((size_t)(b*Cdim + c))*Tdim + t] + pe_tab[(t & 15)*Cdim + c];
  }
  __syncthreads();
  #pragma unroll
  for (int j = 0; j < 4; j++){
    int tt = t0 + ty + j*8;
    rows[((size_t)(b*Tdim + tt))*Cdim + c0 + tx] = tile[tx][ty+j*8];
  }
}

__global__ void resid_kernel(const float* __restrict__ zt, const float* __restrict__ zp_rows, float* __restrict__ rows){
  __shared__ float tile[32][33];
  int b = blockIdx.z, c0 = blockIdx.y*32, t0 = blockIdx.x*32;
  int tx = threadIdx.x, ty = threadIdx.y;
  int t = t0 + tx;
  #pragma unroll
  for (int j = 0; j < 4; j++){
    int c = c0 + ty + j*8;
    tile[ty+j*8][tx] = zt[((size_t)(b*Cdim + c))*Tdim + t];
  }
  __syncthreads();
  #pragma unroll
  for (int j = 0; j < 4; j++){
    int tt = t0 + ty + j*8;
    size_t o = ((size_t)(b*Tdim + tt))*Cdim + c0 + tx;
    rows[o] = tile[tx][ty+j*8] - zp_rows[o];
  }
}

__global__ void tout_kernel(const float* __restrict__ rows, float* __restrict__ out){
  __shared__ float tile[32][33];
  int b = blockIdx.z, c0 = blockIdx.y*32, t0 = blockIdx.x*32;
  int tx = threadIdx.x, ty = threadIdx.y;
  #pragma unroll
  for (int j = 0; j < 4; j++){
    int tt = t0 + ty + j*8;
    tile[ty+j*8][tx] = rows[((size_t)(b*Tdim + tt))*Cdim + c0 + tx];
  }
  __syncthreads();
  #pragma unroll
  for (int j = 0; j < 4; j++){
    int c = c0 + ty + j*8;
    out[((size_t)(b*Cdim + c))*Tdim + t0 + tx] = tile[tx][ty+j*8];
  }
}

// ---------------- weight transposes ----------------
__global__ void twd_kernel(const float* __restrict__ Wd, float* __restrict__ WdT){ // Wd[96][512] -> WdT[512][96]
  int i = blockIdx.x*256 + threadIdx.x; if (i >= 96*512) return;
  int kq = i / 96, n = i % 96;
  WdT[i] = Wd[(size_t)n*512 + kq];
}

// ---------------- books[k][c][d] -> booksT[k][d][c] (tiled transpose) ----------------
__global__ void tbt_kernel(const float* __restrict__ books, float* __restrict__ booksT){
  __shared__ float tile[32][33];
  int k = blockIdx.z, d0 = blockIdx.y*32, c0 = blockIdx.x*32;
  int tx = threadIdx.x, ty = threadIdx.y;
  #pragma unroll
  for (int j = 0; j < 4; j++){
    int c = c0 + ty + j*8;
    tile[ty+j*8][tx] = books[((size_t)k*NE + c)*CD + d0 + tx];
  }
  __syncthreads();
  #pragma unroll
  for (int j = 0; j < 4; j++){
    int d = d0 + ty + j*8;
    booksT[(size_t)k*CD*NE + (size_t)d*NE + c0 + tx] = tile[tx][ty+j*8];
  }
}

// ---------------- 0.5*||e||^2 per codebook entry ----------------
__global__ void hb_kernel(const float* __restrict__ books, float* __restrict__ hb){
  int j = blockIdx.x*256 + threadIdx.x;
  if (j >= NB*NE) return;
  const float* e = books + (size_t)j*CD;
  float s = 0.f;
  #pragma unroll
  for (int d = 0; d < CD; d++) s = fmaf(e[d], e[d], s);
  hb[j] = 0.5f*s;
}

// ---------------- split-bf16 helpers (hi = truncate, lo = exact residual as bf16) ----------------
__device__ __forceinline__ uint pack_hi(float a, float b){
  uint ua = __float_as_uint(a), ub = __float_as_uint(b);
  return (ua >> 16) | (ub & 0xFFFF0000u);
}
__device__ __forceinline__ uint pack_lo(float a, float b){
  float ha = __uint_as_float(__float_as_uint(a) & 0xFFFF0000u);
  float hb = __uint_as_float(__float_as_uint(b) & 0xFFFF0000u);
  return pack_hi(a - ha, b - hb);
}

// ---------------- weight fp32 [K][N] -> transposed planar bf16 pair [N][K] ----------------
__global__ void cvtT_kernel(const float* __restrict__ W, ushort* __restrict__ hT, ushort* __restrict__ lT,
        int K, int N){
  __shared__ float tile[32][33];
  int k0 = blockIdx.y*32, n0 = blockIdx.x*32;
  int tx = threadIdx.x, ty = threadIdx.y;
  #pragma unroll
  for (int j = 0; j < 4; j++)
    tile[ty+j*8][tx] = W[(size_t)(k0+ty+j*8)*N + n0+tx];
  __syncthreads();
  #pragma unroll
  for (int j = 0; j < 4; j++){
    int n = n0 + ty + j*8;
    float f = tile[tx][ty+j*8];     // = W[k0+tx][n]
    uint u = __float_as_uint(f);
    float hf = __uint_as_float(u & 0xFFFF0000u);
    hT[(size_t)n*K + k0 + tx] = (ushort)(u >> 16);
    lT[(size_t)n*K + k0 + tx] = (ushort)(__float_as_uint(f - hf) >> 16);
  }
}

// ---------------- Wu fp32 [N=512][K=96] -> planar bf16 pair (already BT layout) ----------------
__global__ void cvtP_kernel(const float* __restrict__ X, ushort* __restrict__ h, ushort* __restrict__ lo, int n){
  int i = blockIdx.x*256 + threadIdx.x; if (i >= n) return;
  float f = X[i];
  uint u = __float_as_uint(f);
  float hf = __uint_as_float(u & 0xFFFF0000u);
  h[i]  = (ushort)(u >> 16);
  lo[i] = (ushort)(__float_as_uint(f - hf) >> 16);
}

// ---------------- generic tiled fp32 GEMM (64x64 tile): odd shapes only ----------------
// addmode: 0 none, 1 addbuf[(m&15)*N+n], 2 addbuf[m*N+n]
__global__ __launch_bounds__(256) void gemm_kernel(const float* __restrict__ A, const float* __restrict__ Bm,
        float* __restrict__ Cm, int M, int N, int K,
        const float* __restrict__ bias, const float* __restrict__ addbuf, int addmode, int act){
  __shared__ float As[16][65];
  __shared__ float Bs[16][64];
  int l = threadIdx.x;
  int tx = l & 15, ty = l >> 4;
  int m0 = blockIdx.y*64, n0 = blockIdx.x*64;
  int ai = l >> 2, ak = (l & 3)*4;
  int bk = l >> 4, bj = (l & 15)*4;
  float acc[4][4] = {{0.f}};
  bool nfull = (n0 + 64 <= N);
  for (int k0 = 0; k0 < K; k0 += 16){
    float4 av = make_float4(0.f, 0.f, 0.f, 0.f);
    if (m0 + ai < M) av = *(const float4*)(A + (size_t)(m0+ai)*K + k0 + ak);
    As[ak][ai] = av.x; As[ak+1][ai] = av.y; As[ak+2][ai] = av.z; As[ak+3][ai] = av.w;
    if (nfull){
      *(float4*)(&Bs[bk][bj]) = *(const float4*)(Bm + (size_t)(k0+bk)*N + n0 + bj);
    } else {
      #pragma unroll
      for (int u = 0; u < 4; u++){
        int n = n0 + bj + u;
        Bs[bk][bj+u] = (n < N) ? Bm[(size_t)(k0+bk)*N + n] : 0.f;
      }
    }
    __syncthreads();
    #pragma unroll
    for (int kk = 0; kk < 16; kk++){
      float a0 = As[kk][ty*4], a1 = As[kk][ty*4+1], a2 = As[kk][ty*4+2], a3 = As[kk][ty*4+3];
      float b0 = Bs[kk][tx*4], b1 = Bs[kk][tx*4+1], b2 = Bs[kk][tx*4+2], b3 = Bs[kk][tx*4+3];
      acc[0][0] = fmaf(a0,b0,acc[0][0]); acc[0][1] = fmaf(a0,b1,acc[0][1]);
      acc[0][2] = fmaf(a0,b2,acc[0][2]); acc[0][3] = fmaf(a0,b3,acc[0][3]);
      acc[1][0] = fmaf(a1,b0,acc[1][0]); acc[1][1] = fmaf(a1,b1,acc[1][1]);
      acc[1][2] = fmaf(a1,b2,acc[1][2]); acc[1][3] = fmaf(a1,b3,acc[1][3]);
      acc[2][0] = fmaf(a2,b0,acc[2][0]); acc[2][1] = fmaf(a2,b1,acc[2][1]);
      acc[2][2] = fmaf(a2,b2,acc[2][2]); acc[2][3] = fmaf(a2,b3,acc[2][3]);
      acc[3][0] = fmaf(a3,b0,acc[3][0]); acc[3][1] = fmaf(a3,b1,acc[3][1]);
      acc[3][2] = fmaf(a3,b2,acc[3][2]); acc[3][3] = fmaf(a3,b3,acc[3][3]);
    }
    __syncthreads();
  }
  #pragma unroll
  for (int r = 0; r < 4; r++){
    int m = m0 + ty*4 + r; if (m >= M) continue;
    #pragma unroll
    for (int c = 0; c < 4; c++){
      int n = n0 + tx*4 + c; if (n >= N) continue;
      float v = acc[r][c];
      if (bias) v += bias[n];
      if (act == 1) v = 0.5f*v*(1.0f + erff(v*0.7071067811865475f));
      if (addmode == 1) v += addbuf[(size_t)(m & 15)*N + n];
      else if (addmode == 2) v += addbuf[(size_t)m*N + n];
      Cm[(size_t)m*N + n] = v;
    }
  }
}

// ---------------- MFMA split-bf16 GEMM: C = A(fp32) x B (pre-split bf16-pair, transposed) ----------------
// A [M][K] fp32 (hi/lo split in-kernel during staging); BhT/BlT [N][K] bf16 planar.
// acc = Ah*Bh + Ah*Bl + Al*Bh in fp32 AGPRs: ~fp32 precision (err ~2^-16 rel per product).
// 128x128 tile, 4 waves 2x2, each wave 64x64 = 4x4 frags of mfma_f32_16x16x32_bf16.
// Frag layouts (HW-verified): A lane: row=il&15, k=(il>>4)*8+j ; D: col=il&15, row=(il>>4)*4+r.
// requires M%128==0, N%128==0, K%32==0
__global__ __launch_bounds__(256, 1) void mgemm_kernel(const float* __restrict__ A,
        const ushort* __restrict__ BhT, const ushort* __restrict__ BlT,
        float* __restrict__ Cm, int M, int N, int K,
        const float* __restrict__ bias, const float* __restrict__ addbuf, int addmode, int act){
  __shared__ __align__(16) ushort Ah[128][32];
  __shared__ __align__(16) ushort Al[128][32];
  __shared__ __align__(16) ushort Bh[128][32];
  __shared__ __align__(16) ushort Bl[128][32];
  int l = threadIdx.x;
  int il = l & 63, wv = l >> 6;
  int wr = wv >> 1, wc = wv & 1;
  int fr = il & 15, fg = il >> 4;
  int m0 = blockIdx.y*128, n0 = blockIdx.x*128;
  int srow = l >> 1, shalf = (l & 1) * 16;       // stage: row srow, 16 elems at shalf
  const float*  Ap  = A   + (size_t)(m0 + srow)*K + shalf;
  const ushort* Bhp = BhT + (size_t)(n0 + srow)*K + shalf;
  const ushort* Blp = BlT + (size_t)(n0 + srow)*K + shalf;
  f32x4 acc[4][4];
  #pragma unroll
  for (int i = 0; i < 4; i++)
    #pragma unroll
    for (int j = 0; j < 4; j++)
      acc[i][j] = (f32x4){0.f, 0.f, 0.f, 0.f};
  for (int k0 = 0; k0 < K; k0 += 32){
    float4 a0 = *(const float4*)(Ap + k0);
    float4 a1 = *(const float4*)(Ap + k0 + 4);
    float4 a2 = *(const float4*)(Ap + k0 + 8);
    float4 a3 = *(const float4*)(Ap + k0 + 12);
    uint4 bh0 = *(const uint4*)(Bhp + k0);
    uint4 bh1 = *(const uint4*)(Bhp + k0 + 8);
    uint4 bl0 = *(const uint4*)(Blp + k0);
    uint4 bl1 = *(const uint4*)(Blp + k0 + 8);
    __syncthreads();                        // previous iteration's frag reads done
    uint4 h0, h1, l0v, l1v;
    h0.x = pack_hi(a0.x,a0.y); h0.y = pack_hi(a0.z,a0.w);
    h0.z = pack_hi(a1.x,a1.y); h0.w = pack_hi(a1.z,a1.w);
    h1.x = pack_hi(a2.x,a2.y); h1.y = pack_hi(a2.z,a2.w);
    h1.z = pack_hi(a3.x,a3.y); h1.w = pack_hi(a3.z,a3.w);
    l0v.x = pack_lo(a0.x,a0.y); l0v.y = pack_lo(a0.z,a0.w);
    l0v.z = pack_lo(a1.x,a1.y); l0v.w = pack_lo(a1.z,a1.w);
    l1v.x = pack_lo(a2.x,a2.y); l1v.y = pack_lo(a2.z,a2.w);
    l1v.z = pack_lo(a3.x,a3.y); l1v.w = pack_lo(a3.z,a3.w);
    *(uint4*)&Ah[srow][shalf]   = h0;  *(uint4*)&Ah[srow][shalf+8] = h1;
    *(uint4*)&Al[srow][shalf]   = l0v; *(uint4*)&Al[srow][shalf+8] = l1v;
    *(uint4*)&Bh[srow][shalf]   = bh0; *(uint4*)&Bh[srow][shalf+8] = bh1;
    *(uint4*)&Bl[srow][shalf]   = bl0; *(uint4*)&Bl[srow][shalf+8] = bl1;
    __syncthreads();
    bf16x8 afh[4], afl[4], bfh[4], bfl[4];
    #pragma unroll
    for (int q = 0; q < 4; q++){
      afh[q] = *(const bf16x8*)&Ah[wr*64 + q*16 + fr][fg*8];
      afl[q] = *(const bf16x8*)&Al[wr*64 + q*16 + fr][fg*8];
      bfh[q] = *(const bf16x8*)&Bh[wc*64 + q*16 + fr][fg*8];
      bfl[q] = *(const bf16x8*)&Bl[wc*64 + q*16 + fr][fg*8];
    }
    #pragma unroll
    for (int i = 0; i < 4; i++)
      #pragma unroll
      for (int j = 0; j < 4; j++)
        acc[i][j] = __builtin_amdgcn_mfma_f32_16x16x32_bf16(afh[i], bfh[j], acc[i][j], 0, 0, 0);
    #pragma unroll
    for (int i = 0; i < 4; i++)
      #pragma unroll
      for (int j = 0; j < 4; j++)
        acc[i][j] = __builtin_amdgcn_mfma_f32_16x16x32_bf16(afh[i], bfl[j], acc[i][j], 0, 0, 0);
    #pragma unroll
    for (int i = 0; i < 4; i++)
      #pragma unroll
      for (int j = 0; j < 4; j++)
        acc[i][j] = __builtin_amdgcn_mfma_f32_16x16x32_bf16(afl[i], bfh[j], acc[i][j], 0, 0, 0);
  }
  #pragma unroll
  for (int i = 0; i < 4; i++){
    #pragma unroll
    for (int j = 0; j < 4; j++){
      #pragma unroll
      for (int r = 0; r < 4; r++){
        int m = m0 + wr*64 + i*16 + fg*4 + r;
        int n = n0 + wc*64 + j*16 + fr;
        float v = acc[i][j][r];
        if (bias) v += bias[n];
        if (act == 1) v = 0.5f*v*(1.0f + erff(v*0.7071067811865475f));
        if (addmode == 1) v += addbuf[(size_t)(m & 15)*N + n];
        else if (addmode == 2) v += addbuf[(size_t)m*N + n];
        Cm[(size_t)m*N + n] = v;
      }
    }
  }
}

// ---------------- attention, phase 1: 16 const queries x 16 keys per (b,chunk) ----------------
__global__ __launch_bounds__(128) void attn1_kernel(const float* __restrict__ Kb, const float* __restrict__ Vb,
        const float* __restrict__ Qp, float* __restrict__ ctxb){
  int idx = blockIdx.x;                 // b*256 + ch
  int b = idx >> 8, ch = idx & 255;
  size_t m0 = (size_t)b*Tdim + ch*16;
  int t = threadIdx.x >> 3, h = threadIdx.x & 7;
  const float* q = Qp + t*Cdim + h*64;
  float qr[64];
  #pragma unroll
  for (int d = 0; d < 64; d += 4){ float4 f = *(const float4*)(q+d); qr[d]=f.x; qr[d+1]=f.y; qr[d+2]=f.z; qr[d+3]=f.w; }
  float s[16];
  #pragma unroll
  for (int k = 0; k < 16; k++){
    const float* kr = Kb + (m0+k)*Cdim + h*64;
    float acc = 0.f;
    #pragma unroll
    for (int d = 0; d < 64; d += 4){
      float4 f = *(const float4*)(kr+d);
      acc = fmaf(qr[d],f.x,acc); acc = fmaf(qr[d+1],f.y,acc);
      acc = fmaf(qr[d+2],f.z,acc); acc = fmaf(qr[d+3],f.w,acc);
    }
    s[k] = acc * 0.125f;
  }
  float mx = s[0];
  #pragma unroll
  for (int k = 1; k < 16; k++) mx = fmaxf(mx, s[k]);
  float sum = 0.f;
  #pragma unroll
  for (int k = 0; k < 16; k++){ s[k] = expf(s[k]-mx); sum += s[k]; }
  float inv = 1.0f/sum;
  float ctx[64];
  #pragma unroll
  for (int d = 0; d < 64; d++) ctx[d] = 0.f;
  #pragma unroll
  for (int k = 0; k < 16; k++){
    float p = s[k]*inv;
    const float* vr = Vb + (m0+k)*Cdim + h*64;
    #pragma unroll
    for (int d = 0; d < 64; d += 4){
      float4 f = *(const float4*)(vr+d);
      ctx[d]=fmaf(p,f.x,ctx[d]); ctx[d+1]=fmaf(p,f.y,ctx[d+1]);
      ctx[d+2]=fmaf(p,f.z,ctx[d+2]); ctx[d+3]=fmaf(p,f.w,ctx[d+3]);
    }
  }
  float* o = ctxb + (m0+t)*Cdim + h*64;
  #pragma unroll
  for (int d = 0; d < 64; d += 4){
    float4 f; f.x=ctx[d]; f.y=ctx[d+1]; f.z=ctx[d+2]; f.w=ctx[d+3];
    *(float4*)(o+d) = f;
  }
}

// ---------------- attention, phase 2: 1 query (token 0) per (b,chunk) ----------------
__global__ __launch_bounds__(64) void attn2_kernel(const float* __restrict__ Kb, const float* __restrict__ Vb,
        const float* __restrict__ Qp, float* __restrict__ ctxb){
  int m2 = blockIdx.x;                 // b*256 + ch
  int b = m2 >> 8, ch = m2 & 255;
  size_t m0 = (size_t)b*Tdim + ch*16;
  int h = threadIdx.x;
  if (h >= 8) return;
  const float* q = Qp + (size_t)m2*Cdim + h*64;
  float qr[64];
  #pragma unroll
  for (int d = 0; d < 64; d += 4){ float4 f = *(const float4*)(q+d); qr[d]=f.x; qr[d+1]=f.y; qr[d+2]=f.z; qr[d+3]=f.w; }
  float s[16];
  #pragma unroll
  for (int k = 0; k < 16; k++){
    const float* kr = Kb + (m0+k)*Cdim + h*64;
    float acc = 0.f;
    #pragma unroll
    for (int d = 0; d < 64; d += 4){
      float4 f = *(const float4*)(kr+d);
      acc = fmaf(qr[d],f.x,acc); acc = fmaf(qr[d+1],f.y,acc);
      acc = fmaf(qr[d+2],f.z,acc); acc = fmaf(qr[d+3],f.w,acc);
    }
    s[k] = acc * 0.125f;
  }
  float mx = s[0];
  #pragma unroll
  for (int k = 1; k < 16; k++) mx = fmaxf(mx, s[k]);
  float sum = 0.f;
  #pragma unroll
  for (int k = 0; k < 16; k++){ s[k] = expf(s[k]-mx); sum += s[k]; }
  float inv = 1.0f/sum;
  float ctx[64];
  #pragma unroll
  for (int d = 0; d < 64; d++) ctx[d] = 0.f;
  #pragma unroll
  for (int k = 0; k < 16; k++){
    float p = s[k]*inv;
    const float* vr = Vb + (m0+k)*Cdim + h*64;
    #pragma unroll
    for (int d = 0; d < 64; d += 4){
      float4 f = *(const float4*)(vr+d);
      ctx[d]=fmaf(p,f.x,ctx[d]); ctx[d+1]=fmaf(p,f.y,ctx[d+1]);
      ctx[d+2]=fmaf(p,f.z,ctx[d+2]); ctx[d+3]=fmaf(p,f.w,ctx[d+3]);
    }
  }
  float* o = ctxb + (size_t)m2*Cdim + h*64;
  #pragma unroll
  for (int d = 0; d < 64; d += 4){
    float4 f; f.x=ctx[d]; f.y=ctx[d+1]; f.z=ctx[d+2]; f.w=ctx[d+3];
    *(float4*)(o+d) = f;
  }
}

// ---------------- phase 2: build token-0 query rows (carry + pe[:,0], LN) ----------------
__global__ __launch_bounds__(256) void q2_kernel(const float* __restrict__ dout, float* __restrict__ p2q,
        const float* __restrict__ g, const float* __restrict__ bia){
  int m2 = blockIdx.x; int tid = threadIdx.x;
  int b = m2 >> 8, ch = m2 & 255;
  int tprev = ch*16 - 1;
  float v0, v1;
  {
    int c = tid;
    float carry = (ch == 0) ? 0.f : dout[((size_t)(b*Cdim + c))*Tdim + tprev];
    v0 = carry + ((c & 1) ? 1.f : 0.f);     // pe[c,0] = c even ? sin(0)=0 : cos(0)=1
  }
  {
    int c = tid + 256;
    float carry = (ch == 0) ? 0.f : dout[((size_t)(b*Cdim + c))*Tdim + tprev];
    v1 = carry + ((c & 1) ? 1.f : 0.f);
  }
  __shared__ float red[256];
  red[tid] = v0+v1; __syncthreads();
  for (int s = 128; s > 0; s >>= 1){ if (tid < s) red[tid] += red[tid+s]; __syncthreads(); }
  float mean = red[0]*(1.f/512.f); __syncthreads();
  float d0 = v0-mean, d1 = v1-mean;
  red[tid] = d0*d0 + d1*d1; __syncthreads();
  for (int s = 128; s > 0; s >>= 1){ if (tid < s) red[tid] += red[tid+s]; __syncthreads(); }
  float rstd = 1.0f/sqrtf(red[0]*(1.f/512.f) + 1e-5f);
  p2q[(size_t)m2*Cdim + tid]       = d0*rstd*g[tid]     + bia[tid];
  p2q[(size_t)m2*Cdim + tid + 256] = d1*rstd*g[tid+256] + bia[tid+256];
}

// ---------------- phase 2: r = zt[:, :, t0] - z_pred0 ----------------
__global__ __launch_bounds__(256) void r2_kernel(const float* __restrict__ zt, const float* __restrict__ zp,
        float* __restrict__ out){
  int m2 = blockIdx.x; int tid = threadIdx.x;
  int b = m2 >> 8, ch = m2 & 255; int t0 = ch*16;
  #pragma unroll
  for (int u = 0; u < 2; u++){
    int c = tid + u*256;
    out[(size_t)m2*Cdim + c] = zt[((size_t)(b*Cdim + c))*Tdim + t0] - zp[(size_t)m2*Cdim + c];
  }
}

// ---------------- phase 2: scatter z_hat token-0 columns into d_out ----------------
__global__ __launch_bounds__(256) void scatter2_kernel(const float* __restrict__ z, float* __restrict__ dout){
  int m2 = blockIdx.x; int tid = threadIdx.x;
  int b = m2 >> 8, ch = m2 & 255; int t0 = ch*16;
  #pragma unroll
  for (int u = 0; u < 2; u++){
    int c = tid + u*256;
    dout[((size_t)(b*Cdim + c))*Tdim + t0] = z[(size_t)m2*Cdim + c];
  }
}

// ---------------- residual VQ as LDS-staged GEMM (fgemm geometry) ----------------
template<int MT>
__global__ __launch_bounds__(256, 1) void vqg_kernel(float* __restrict__ x,
        const float* __restrict__ books, const float* __restrict__ booksT,
        const float* __restrict__ hb){
  constexpr int MI  = MT/16;    // acc rows per thread (8 or 4)
  constexpr int TPT = 256/MT;   // threads per token (2 or 4)
  constexpr int F4  = 24/TPT;   // float4 slices of a token per thread (12 or 6)
  int l = threadIdx.x;
  int tx = l & 15, ty = l >> 4;
  int tok = l / TPT, part = l % TPT;
  size_t tok0 = (size_t)blockIdx.x * MT;
  __shared__ float As[96][MT];    // res^T
  __shared__ float Es[96][128];   // E^T candidate tile
  __shared__ float hs[128];
  __shared__ float sb[MT][16];
  __shared__ int   si[MT][16];
  __shared__ int   sel[MT];
  float* xp = x + (tok0 + tok)*CD;
  // stage res^T = x^T
  #pragma unroll
  for (int j = 0; j < F4; j++){
    int d4 = part*F4 + j;
    float4 v = *(const float4*)(xp + d4*4);
    As[d4*4+0][tok]=v.x; As[d4*4+1][tok]=v.y; As[d4*4+2][tok]=v.z; As[d4*4+3][tok]=v.w;
  }
  for (int k = 0; k < NB; k++){
    const float* bT = booksT + (size_t)k*CD*NE;
    float best[MI]; int bidx[MI];
    #pragma unroll
    for (int i = 0; i < MI; i++){ best[i] = -3.0e38f; bidx[i] = 0; }
    for (int t = 0; t < 8; t++){
      int n0 = t*128;
      __syncthreads();                 // also orders As writes (init/update) before reads
      #pragma unroll
      for (int j = 0; j < 12; j++){    // stage 96x128 E^T tile, coalesced
        int f4 = j*256 + l;
        int d = f4 >> 5, c4 = f4 & 31;
        float4 v = *(const float4*)(bT + (size_t)d*NE + n0 + c4*4);
        *(float4*)(&Es[d][c4*4]) = v;
      }
      if (l < 32){
        float4 hv = *(const float4*)(hb + k*NE + n0 + l*4);
        *(float4*)(&hs[l*4]) = hv;
      }
      __syncthreads();
      float acc[MI][8];
      #pragma unroll
      for (int i = 0; i < MI; i++)
        #pragma unroll
        for (int j = 0; j < 8; j++) acc[i][j] = 0.f;
      #pragma unroll 2
      for (int kk = 0; kk < 96; kk++){
        float av[MI], bw[8];
        #pragma unroll
        for (int g = 0; g < MI/4; g++)
          *(float4*)(av + g*4) = *(const float4*)(&As[kk][g*64 + ty*4]);
        *(float4*)(bw)   = *(const float4*)(&Es[kk][tx*4]);
        *(float4*)(bw+4) = *(const float4*)(&Es[kk][64 + tx*4]);
        #pragma unroll
        for (int i = 0; i < MI; i++)
          #pragma unroll
          for (int j = 0; j < 8; j++)
            acc[i][j] = fmaf(av[i], bw[j], acc[i][j]);
      }
      #pragma unroll
      for (int i = 0; i < MI; i++){
        #pragma unroll
        for (int j = 0; j < 8; j++){
          int cl = (j>>2)*64 + tx*4 + (j&3);     // ascending within thread
          float s = acc[i][j] - hs[cl];
          if (s > best[i]){ best[i] = s; bidx[i] = n0 + cl; }
        }
      }
    }
    // cross-thread argmax merge (16 tx partials per token row)
    #pragma unroll
    for (int i = 0; i < MI; i++){
      int row = (i>>2)*64 + ty*4 + (i&3);
      sb[row][tx] = best[i]; si[row][tx] = bidx[i];
    }
    __syncthreads();
    if (l < MT){
      float bb = sb[l][0]; int bi = si[l][0];
      #pragma unroll
      for (int t2 = 1; t2 < 16; t2++){
        float b2 = sb[l][t2]; int i2 = si[l][t2];
        if (b2 > bb || (b2 == bb && i2 < bi)){ bb = b2; bi = i2; }
      }
      sel[l] = bi;
    }
    __syncthreads();
    // res -= E[k][sel]
    int s = sel[tok];
    const float* e = books + ((size_t)k*NE + s)*CD;
    #pragma unroll
    for (int j = 0; j < F4; j++){
      int d4 = part*F4 + j;
      float4 v = *(const float4*)(e + d4*4);
      As[d4*4+0][tok] -= v.x; As[d4*4+1][tok] -= v.y;
      As[d4*4+2][tok] -= v.z; As[d4*4+3][tok] -= v.w;
    }
  }
  // q_sum = x - res_final (thread reads exactly the cells it wrote -> no barrier)
  #pragma unroll
  for (int j = 0; j < F4; j++){
    int d4 = part*F4 + j;
    float4 xo = *(const float4*)(xp + d4*4);
    float4 q;
    q.x = xo.x - As[d4*4+0][tok];
    q.y = xo.y - As[d4*4+1][tok];
    q.z = xo.z - As[d4*4+2][tok];
    q.w = xo.w - As[d4*4+3][tok];
    *(float4*)(xp + d4*4) = q;
  }
}

// ---------------- host ----------------
extern "C" void kernel_launch(void* const* d_in, const int* in_sizes, int n_in,
                              void* d_out, int out_size, void* d_ws, size_t ws_size,
                              hipStream_t stream) {
  const float* qa    = (const float*)d_in[0];
  const float* zt    = (const float*)d_in[1];
  const float* lnq_g = (const float*)d_in[2];
  const float* lnq_b = (const float*)d_in[3];
  const float* lnkv_g= (const float*)d_in[4];
  const float* lnkv_b= (const float*)d_in[5];
  const float* Wq    = (const float*)d_in[6];
  const float* Wk    = (const float*)d_in[7];
  const float* Wv    = (const float*)d_in[8];
  const float* Wo    = (const float*)d_in[9];
  const float* ffn_g = (const float*)d_in[10];
  const float* ffn_b = (const float*)d_in[11];
  const float* W1    = (const float*)d_in[12];
  const float* b1    = (const float*)d_in[13];
  const float* W2    = (const float*)d_in[14];
  const float* b2    = (const float*)d_in[15];
  const float* tn_g  = (const float*)d_in[16];
  const float* tn_b  = (const float*)d_in[17];
  const float* scale = (const float*)d_in[18];
  const float* Wd    = (const float*)d_in[19];
  const float* bd    = (const float*)d_in[20];
  const float* Wu    = (const float*)d_in[21];
  const float* bu    = (const float*)d_in[22];
  const float* books = (const float*)d_in[23];
  float* out = (float*)d_out;

  // ---- workspace layout (~217 MiB) ----
  float* ws = (float*)d_ws;
  size_t off = 0;
  float* pe_tab  = ws + off; off += 16*512;
  float* qc_ln   = ws + off; off += 16*512;
  float* qc_proj = ws + off; off += 16*512;
  float* WdT     = ws + off; off += 512*96;
  float* hbuf    = ws + off; off += 8*1024;
  // split-bf16 transposed weight pairs (ushort), 16B-aligned (off stays multiple of 4)
  ushort* wub = (ushort*)(ws + off); off += 2146304;   // 4,292,608 ushorts
  ushort* WqTh = wub;            ushort* WqTl = WqTh + 262144;
  ushort* WkTh = WqTl + 262144;  ushort* WkTl = WkTh + 262144;
  ushort* WvTh = WkTl + 262144;  ushort* WvTl = WvTh + 262144;
  ushort* WoTh = WvTl + 262144;  ushort* WoTl = WoTh + 262144;
  ushort* W1Th = WoTl + 262144;  ushort* W1Tl = W1Th + 524288;
  ushort* W2Th = W1Tl + 524288;  ushort* W2Tl = W2Th + 524288;
  ushort* WuPh = W2Tl + 524288;  ushort* WuPl = WuPh + 49152;
  float* bA      = ws + off; off += (size_t)Mtok*512;   // kv rows -> ctx -> lny -> rn -> zhat rows -> phase2 scratch
  float* bK      = ws + off; off += (size_t)Mtok*512;
  float* bV      = ws + off; off += (size_t)Mtok*512;
  float* bH      = ws + off; off += (size_t)4096*1024;  // FFN hidden tile; also hosts bX + booksT
  float* bX      = bH;                                  // Mtok*96 = 12.6MB
  float* booksTp = bH + (size_t)Mtok*CD;                // 3MB in bH's spare tail
  float* bY      = out;                                 // y / z_pred rows live in d_out

  // phase-2 scratch carved inside bA (only used after tout consumes bA)
  float* p2q   = bA;
  float* p2Qp  = bA + 1048576;
  float* p2ctx = bA + 2*1048576;
  float* p2y   = bA + 3*1048576;
  float* p2lny = bA + 4*1048576;
  float* p2h   = bA + 5*1048576;          // 2048*1024
  float* p2r   = bA + 7*1048576;
  float* p2x   = bA + 8*1048576;          // 2048*96
  float* p2z   = bA + 8*1048576 + 196608;

  dim3 tpb32(32, 8);
  dim3 tgrid(Tdim/32, Cdim/32, Bsz);

  // ---- prep ----
  hipLaunchKernelGGL(pe_qc_kernel, dim3(16), dim3(256), 0, stream, pe_tab, qc_ln, lnq_g, lnq_b);
  hipLaunchKernelGGL(twd_kernel, dim3((96*512+255)/256), dim3(256), 0, stream, Wd, WdT);
  hipLaunchKernelGGL(hb_kernel, dim3((NB*NE+255)/256), dim3(256), 0, stream, books, hbuf);
  hipLaunchKernelGGL(cvtT_kernel, dim3(16, 16), tpb32, 0, stream, Wq, WqTh, WqTl, 512, 512);
  hipLaunchKernelGGL(cvtT_kernel, dim3(16, 16), tpb32, 0, stream, Wk, WkTh, WkTl, 512, 512);
  hipLaunchKernelGGL(cvtT_kernel, dim3(16, 16), tpb32, 0, stream, Wv, WvTh, WvTl, 512, 512);
  hipLaunchKernelGGL(cvtT_kernel, dim3(16, 16), tpb32, 0, stream, Wo, WoTh, WoTl, 512, 512);
  hipLaunchKernelGGL(cvtT_kernel, dim3(32, 16), tpb32, 0, stream, W1, W1Th, W1Tl, 512, 1024);
  hipLaunchKernelGGL(cvtT_kernel, dim3(16, 32), tpb32, 0, stream, W2, W2Th, W2Tl, 1024, 512);
  hipLaunchKernelGGL(cvtP_kernel, dim3((512*96+255)/256), dim3(256), 0, stream, Wu, WuPh, WuPl, 512*96);

  // ---- phase 1: kv path ----
  hipLaunchKernelGGL(tin_kernel, tgrid, tpb32, 0, stream, qa, pe_tab, bA);
  hipLaunchKernelGGL(ln_rows_kernel, dim3(Mtok), dim3(256), 0, stream, bA, bA, lnkv_g, lnkv_b, 0, scale);
  hipLaunchKernelGGL(mgemm_kernel, dim3(4, Mtok/128), dim3(256), 0, stream, bA, WkTh, WkTl, bK, Mtok, 512, 512,
                     (const float*)nullptr, (const float*)nullptr, 0, 0);
  hipLaunchKernelGGL(mgemm_kernel, dim3(4, Mtok/128), dim3(256), 0, stream, bA, WvTh, WvTl, bV, Mtok, 512, 512,
                     (const float*)nullptr, (const float*)nullptr, 0, 0);
  hipLaunchKernelGGL(gemm_kernel, dim3(8, 1), dim3(256), 0, stream, qc_ln, Wq, qc_proj, 16, 512, 512,
                     (const float*)nullptr, (const float*)nullptr, 0, 0);

  // ---- phase 1: attention + Wo + FFN ----
  hipLaunchKernelGGL(attn1_kernel, dim3(M2tok), dim3(128), 0, stream, bK, bV, qc_proj, bA);
  hipLaunchKernelGGL(mgemm_kernel, dim3(4, Mtok/128), dim3(256), 0, stream, bA, WoTh, WoTl, bY, Mtok, 512, 512,
                     (const float*)nullptr, qc_ln, 1, 0);
  hipLaunchKernelGGL(ln_rows_kernel, dim3(Mtok), dim3(256), 0, stream, bY, bA, ffn_g, ffn_b, 0, scale);
  for (int p = 0; p < 8; p++){
    size_t mo = (size_t)p*4096;
    hipLaunchKernelGGL(mgemm_kernel, dim3(8, 4096/128), dim3(256), 0, stream, bA + mo*512, W1Th, W1Tl, bH, 4096, 1024, 512,
                       b1, (const float*)nullptr, 0, 1);
    hipLaunchKernelGGL(mgemm_kernel, dim3(4, 4096/128), dim3(256), 0, stream, bH, W2Th, W2Tl, bY + mo*512, 4096, 512, 1024,
                       b2, bY + mo*512, 2, 0);
  }

  // ---- phase 1: residual -> tanh LN -> Wd -> VQ -> Wu -> z_hat ----
  hipLaunchKernelGGL(resid_kernel, tgrid, tpb32, 0, stream, zt, bY, bA);
  hipLaunchKernelGGL(ln_rows_kernel, dim3(Mtok), dim3(256), 0, stream, bA, bA, tn_g, tn_b, 1, scale);
  hipLaunchKernelGGL(gemm_kernel, dim3(2, Mtok/64), dim3(256), 0, stream, bA, WdT, bX, Mtok, 96, 512,
                     bd, (const float*)nullptr, 0, 0);
  hipLaunchKernelGGL(tbt_kernel, dim3(NE/32, CD/32, NB), tpb32, 0, stream, books, booksTp);
  hipLaunchKernelGGL(vqg_kernel<128>, dim3(Mtok/128), dim3(256), 0, stream, bX, books, booksTp, hbuf);
  hipLaunchKernelGGL(mgemm_kernel, dim3(4, Mtok/128), dim3(256), 0, stream, bX, WuPh, WuPl, bA, Mtok, 512, 96,
                     bu, bY, 2, 0);
  hipLaunchKernelGGL(tout_kernel, tgrid, tpb32, 0, stream, bA, out);

  // ---- phase 2: token 0 of each chunk with true carries ----
  hipLaunchKernelGGL(q2_kernel, dim3(M2tok), dim3(256), 0, stream, out, p2q, lnq_g, lnq_b);
  hipLaunchKernelGGL(mgemm_kernel, dim3(4, M2tok/128), dim3(256), 0, stream, p2q, WqTh, WqTl, p2Qp, M2tok, 512, 512,
                     (const float*)nullptr, (const float*)nullptr, 0, 0);
  hipLaunchKernelGGL(attn2_kernel, dim3(M2tok), dim3(64), 0, stream, bK, bV, p2Qp, p2ctx);
  hipLaunchKernelGGL(mgemm_kernel, dim3(4, M2tok/128), dim3(256), 0, stream, p2ctx, WoTh, WoTl, p2y, M2tok, 512, 512,
                     (const float*)nullptr, p2q, 2, 0);
  hipLaunchKernelGGL(ln_rows_kernel, dim3(M2tok), dim3(256), 0, stream, p2y, p2lny, ffn_g, ffn_b, 0, scale);
  hipLaunchKernelGGL(mgemm_kernel, dim3(8, M2tok/128), dim3(256), 0, stream, p2lny, W1Th, W1Tl, p2h, M2tok, 1024, 512,
                     b1, (const float*)nullptr, 0, 1);
  hipLaunchKernelGGL(mgemm_kernel, dim3(4, M2tok/128), dim3(256), 0, stream, p2h, W2Th, W2Tl, p2y, M2tok, 512, 1024,
                     b2, p2y, 2, 0);
  hipLaunchKernelGGL(r2_kernel, dim3(M2tok), dim3(256), 0, stream, zt, p2y, p2r);
  hipLaunchKernelGGL(ln_rows_kernel, dim3(M2tok), dim3(256), 0, stream, p2r, p2r, tn_g, tn_b, 1, scale);
  hipLaunchKernelGGL(gemm_kernel, dim3(2, M2tok/64), dim3(256), 0, stream, p2r, WdT, p2x, M2tok, 96, 512,
                     bd, (const float*)nullptr, 0, 0);
  hipLaunchKernelGGL(vqg_kernel<64>, dim3(M2tok/64), dim3(256), 0, stream, p2x, books, booksTp, hbuf);
  hipLaunchKernelGGL(mgemm_kernel, dim3(4, M2tok/128), dim3(256), 0, stream, p2x, WuPh, WuPl, p2z, M2tok, 512, 96,
                     bu, p2y, 2, 0);
  hipLaunchKernelGGL(scatter2_kernel, dim3(M2tok), dim3(256), 0, stream, p2z, out);

  (void)in_sizes; (void)n_in; (void)out_size; (void)ws_size;
}

// Round 5
// 3335.455 us; speedup vs baseline: 2.2753x; 1.1193x over previous
//
#include <hip/hip_runtime.h>
#include <math.h>

#define Bsz 8
#define Cdim 512
#define Tdim 4096
#define NHq 8
#define CD 96
#define NB 8
#define NE 1024
#define NCHq 256
#define Mtok (Bsz*Tdim)     // 32768
#define M2tok (Bsz*NCHq)    // 2048

typedef __attribute__((ext_vector_type(8))) short bf16x8;
typedef __attribute__((ext_vector_type(4))) float f32x4;
typedef unsigned int uint;
typedef unsigned short ushort;

// ---------------- pe + constant query rows ----------------
__global__ __launch_bounds__(256) void pe_qc_kernel(float* pe_tab, float* qc_ln,
        const float* __restrict__ lnq_g, const float* __restrict__ lnq_b){
  int t = blockIdx.x;           // 0..15
  int tid = threadIdx.x;
  __shared__ float red[256];
  double f = -log(10000.0) / (double)Cdim;
  float v[2];
  #pragma unroll
  for (int u = 0; u < 2; ++u){
    int c = tid + u*256;
    int ce = c & ~1;
    double ang = (double)t * exp(f * (double)ce);
    v[u] = (float)((c & 1) ? cos(ang) : sin(ang));
    pe_tab[t*Cdim + c] = v[u];
  }
  red[tid] = v[0] + v[1]; __syncthreads();
  for (int s = 128; s > 0; s >>= 1){ if (tid < s) red[tid] += red[tid+s]; __syncthreads(); }
  float mean = red[0] * (1.f/512.f); __syncthreads();
  float d0 = v[0]-mean, d1 = v[1]-mean;
  red[tid] = d0*d0 + d1*d1; __syncthreads();
  for (int s = 128; s > 0; s >>= 1){ if (tid < s) red[tid] += red[tid+s]; __syncthreads(); }
  float rstd = 1.0f/sqrtf(red[0]*(1.f/512.f) + 1e-5f);
  qc_ln[t*Cdim + tid]       = d0*rstd*lnq_g[tid]     + lnq_b[tid];
  qc_ln[t*Cdim + tid + 256] = d1*rstd*lnq_g[tid+256] + lnq_b[tid+256];
}

// ---------------- generic row LayerNorm (rows of 512) ----------------
// mode 0: dst = norm*g+b ; mode 1: dst = tanh(norm*g+b)*clip(scale)
__global__ __launch_bounds__(256) void ln_rows_kernel(const float* __restrict__ src, float* __restrict__ dst,
        const float* __restrict__ g, const float* __restrict__ bia, int mode, const float* __restrict__ scale_ptr){
  int row = blockIdx.x; int tid = threadIdx.x;
  const float* sr = src + (size_t)row*Cdim;
  float v0 = sr[tid], v1 = sr[tid+256];
  __shared__ float red[256];
  red[tid] = v0+v1; __syncthreads();
  for (int s = 128; s > 0; s >>= 1){ if (tid < s) red[tid] += red[tid+s]; __syncthreads(); }
  float mean = red[0]*(1.f/512.f); __syncthreads();
  float d0 = v0-mean, d1 = v1-mean;
  red[tid] = d0*d0 + d1*d1; __syncthreads();
  for (int s = 128; s > 0; s >>= 1){ if (tid < s) red[tid] += red[tid+s]; __syncthreads(); }
  float rstd = 1.0f/sqrtf(red[0]*(1.f/512.f) + 1e-5f);
  float h0 = d0*rstd*g[tid]     + bia[tid];
  float h1 = d1*rstd*g[tid+256] + bia[tid+256];
  if (mode == 1){
    float sc = *scale_ptr; sc = fminf(fmaxf(sc, 0.005f), 0.5f);
    h0 = tanhf(h0)*sc; h1 = tanhf(h1)*sc;
  }
  float* dr = dst + (size_t)row*Cdim;
  dr[tid] = h0; dr[tid+256] = h1;
}

// ---------------- transposes [B,C,T] <-> token rows [B*T, C] ----------------
__global__ void tin_kernel(const float* __restrict__ qa, const float* __restrict__ pe_tab, float* __restrict__ rows){
  __shared__ float tile[32][33];
  int b = blockIdx.z, c0 = blockIdx.y*32, t0 = blockIdx.x*32;
  int tx = threadIdx.x, ty = threadIdx.y;
  int t = t0 + tx;
  #pragma unroll
  for (int j = 0; j < 4; j++){
    int c = c0 + ty + j*8;
    tile[ty+j*8][tx] = qa[((size_t)(b*Cdim + c))*Tdim + t] + pe_tab[(t & 15)*Cdim + c];
  }
  __syncthreads();
  #pragma unroll
  for (int j = 0; j < 4; j++){
    int tt = t0 + ty + j*8;
    rows[((size_t)(b*Tdim + tt))*Cdim + c0 + tx] = tile[tx][ty+j*8];
  }
}

__global__ void resid_kernel(const float* __restrict__ zt, const float* __restrict__ zp_rows, float* __restrict__ rows){
  __shared__ float tile[32][33];
  int b = blockIdx.z, c0 = blockIdx.y*32, t0 = blockIdx.x*32;
  int tx = threadIdx.x, ty = threadIdx.y;
  int t = t0 + tx;
  #pragma unroll
  for (int j = 0; j < 4; j++){
    int c = c0 + ty + j*8;
    tile[ty+j*8][tx] = zt[((size_t)(b*Cdim + c))*Tdim + t];
  }
  __syncthreads();
  #pragma unroll
  for (int j = 0; j < 4; j++){
    int tt = t0 + ty + j*8;
    size_t o = ((size_t)(b*Tdim + tt))*Cdim + c0 + tx;
    rows[o] = tile[tx][ty+j*8] - zp_rows[o];
  }
}

__global__ void tout_kernel(const float* __restrict__ rows, float* __restrict__ out){
  __shared__ float tile[32][33];
  int b = blockIdx.z, c0 = blockIdx.y*32, t0 = blockIdx.x*32;
  int tx = threadIdx.x, ty = threadIdx.y;
  #pragma unroll
  for (int j = 0; j < 4; j++){
    int tt = t0 + ty + j*8;
    tile[ty+j*8][tx] = rows[((size_t)(b*Tdim + tt))*Cdim + c0 + tx];
  }
  __syncthreads();
  #pragma unroll
  for (int j = 0; j < 4; j++){
    int c = c0 + ty + j*8;
    out[((size_t)(b*Cdim + c))*Tdim + t0 + tx] = tile[tx][ty+j*8];
  }
}

// ---------------- weight transposes ----------------
__global__ void twd_kernel(const float* __restrict__ Wd, float* __restrict__ WdT){ // Wd[96][512] -> WdT[512][96]
  int i = blockIdx.x*256 + threadIdx.x; if (i >= 96*512) return;
  int kq = i / 96, n = i % 96;
  WdT[i] = Wd[(size_t)n*512 + kq];
}

// ---------------- books[k][c][d] -> booksT[k][d][c] (tiled transpose) ----------------
__global__ void tbt_kernel(const float* __restrict__ books, float* __restrict__ booksT){
  __shared__ float tile[32][33];
  int k = blockIdx.z, d0 = blockIdx.y*32, c0 = blockIdx.x*32;
  int tx = threadIdx.x, ty = threadIdx.y;
  #pragma unroll
  for (int j = 0; j < 4; j++){
    int c = c0 + ty + j*8;
    tile[ty+j*8][tx] = books[((size_t)k*NE + c)*CD + d0 + tx];
  }
  __syncthreads();
  #pragma unroll
  for (int j = 0; j < 4; j++){
    int d = d0 + ty + j*8;
    booksT[(size_t)k*CD*NE + (size_t)d*NE + c0 + tx] = tile[tx][ty+j*8];
  }
}

// ---------------- 0.5*||e||^2 per codebook entry ----------------
__global__ void hb_kernel(const float* __restrict__ books, float* __restrict__ hb){
  int j = blockIdx.x*256 + threadIdx.x;
  if (j >= NB*NE) return;
  const float* e = books + (size_t)j*CD;
  float s = 0.f;
  #pragma unroll
  for (int d = 0; d < CD; d++) s = fmaf(e[d], e[d], s);
  hb[j] = 0.5f*s;
}

// ---------------- split-bf16 helpers (hi = truncate, lo = exact residual as bf16) ----------------
__device__ __forceinline__ uint pack_hi(float a, float b){
  uint ua = __float_as_uint(a), ub = __float_as_uint(b);
  return (ua >> 16) | (ub & 0xFFFF0000u);
}
__device__ __forceinline__ uint pack_lo(float a, float b){
  float ha = __uint_as_float(__float_as_uint(a) & 0xFFFF0000u);
  float hb = __uint_as_float(__float_as_uint(b) & 0xFFFF0000u);
  return pack_hi(a - ha, b - hb);
}

// ---------------- weight fp32 [K][N] -> transposed planar bf16 pair [N][K] ----------------
__global__ void cvtT_kernel(const float* __restrict__ W, ushort* __restrict__ hT, ushort* __restrict__ lT,
        int K, int N){
  __shared__ float tile[32][33];
  int k0 = blockIdx.y*32, n0 = blockIdx.x*32;
  int tx = threadIdx.x, ty = threadIdx.y;
  #pragma unroll
  for (int j = 0; j < 4; j++)
    tile[ty+j*8][tx] = W[(size_t)(k0+ty+j*8)*N + n0+tx];
  __syncthreads();
  #pragma unroll
  for (int j = 0; j < 4; j++){
    int n = n0 + ty + j*8;
    float f = tile[tx][ty+j*8];     // = W[k0+tx][n]
    uint u = __float_as_uint(f);
    float hf = __uint_as_float(u & 0xFFFF0000u);
    hT[(size_t)n*K + k0 + tx] = (ushort)(u >> 16);
    lT[(size_t)n*K + k0 + tx] = (ushort)(__float_as_uint(f - hf) >> 16);
  }
}

// ---------------- Wu fp32 [N=512][K=96] -> planar bf16 pair (already BT layout) ----------------
__global__ void cvtP_kernel(const float* __restrict__ X, ushort* __restrict__ h, ushort* __restrict__ lo, int n){
  int i = blockIdx.x*256 + threadIdx.x; if (i >= n) return;
  float f = X[i];
  uint u = __float_as_uint(f);
  float hf = __uint_as_float(u & 0xFFFF0000u);
  h[i]  = (ushort)(u >> 16);
  lo[i] = (ushort)(__float_as_uint(f - hf) >> 16);
}

// ---------------- generic tiled fp32 GEMM (64x64 tile): odd shapes only ----------------
// addmode: 0 none, 1 addbuf[(m&15)*N+n], 2 addbuf[m*N+n]
__global__ __launch_bounds__(256) void gemm_kernel(const float* __restrict__ A, const float* __restrict__ Bm,
        float* __restrict__ Cm, int M, int N, int K,
        const float* __restrict__ bias, const float* __restrict__ addbuf, int addmode, int act){
  __shared__ float As[16][65];
  __shared__ float Bs[16][64];
  int l = threadIdx.x;
  int tx = l & 15, ty = l >> 4;
  int m0 = blockIdx.y*64, n0 = blockIdx.x*64;
  int ai = l >> 2, ak = (l & 3)*4;
  int bk = l >> 4, bj = (l & 15)*4;
  float acc[4][4] = {{0.f}};
  bool nfull = (n0 + 64 <= N);
  for (int k0 = 0; k0 < K; k0 += 16){
    float4 av = make_float4(0.f, 0.f, 0.f, 0.f);
    if (m0 + ai < M) av = *(const float4*)(A + (size_t)(m0+ai)*K + k0 + ak);
    As[ak][ai] = av.x; As[ak+1][ai] = av.y; As[ak+2][ai] = av.z; As[ak+3][ai] = av.w;
    if (nfull){
      *(float4*)(&Bs[bk][bj]) = *(const float4*)(Bm + (size_t)(k0+bk)*N + n0 + bj);
    } else {
      #pragma unroll
      for (int u = 0; u < 4; u++){
        int n = n0 + bj + u;
        Bs[bk][bj+u] = (n < N) ? Bm[(size_t)(k0+bk)*N + n] : 0.f;
      }
    }
    __syncthreads();
    #pragma unroll
    for (int kk = 0; kk < 16; kk++){
      float a0 = As[kk][ty*4], a1 = As[kk][ty*4+1], a2 = As[kk][ty*4+2], a3 = As[kk][ty*4+3];
      float b0 = Bs[kk][tx*4], b1 = Bs[kk][tx*4+1], b2 = Bs[kk][tx*4+2], b3 = Bs[kk][tx*4+3];
      acc[0][0] = fmaf(a0,b0,acc[0][0]); acc[0][1] = fmaf(a0,b1,acc[0][1]);
      acc[0][2] = fmaf(a0,b2,acc[0][2]); acc[0][3] = fmaf(a0,b3,acc[0][3]);
      acc[1][0] = fmaf(a1,b0,acc[1][0]); acc[1][1] = fmaf(a1,b1,acc[1][1]);
      acc[1][2] = fmaf(a1,b2,acc[1][2]); acc[1][3] = fmaf(a1,b3,acc[1][3]);
      acc[2][0] = fmaf(a2,b0,acc[2][0]); acc[2][1] = fmaf(a2,b1,acc[2][1]);
      acc[2][2] = fmaf(a2,b2,acc[2][2]); acc[2][3] = fmaf(a2,b3,acc[2][3]);
      acc[3][0] = fmaf(a3,b0,acc[3][0]); acc[3][1] = fmaf(a3,b1,acc[3][1]);
      acc[3][2] = fmaf(a3,b2,acc[3][2]); acc[3][3] = fmaf(a3,b3,acc[3][3]);
    }
    __syncthreads();
  }
  #pragma unroll
  for (int r = 0; r < 4; r++){
    int m = m0 + ty*4 + r; if (m >= M) continue;
    #pragma unroll
    for (int c = 0; c < 4; c++){
      int n = n0 + tx*4 + c; if (n >= N) continue;
      float v = acc[r][c];
      if (bias) v += bias[n];
      if (act == 1) v = 0.5f*v*(1.0f + erff(v*0.7071067811865475f));
      if (addmode == 1) v += addbuf[(size_t)(m & 15)*N + n];
      else if (addmode == 2) v += addbuf[(size_t)m*N + n];
      Cm[(size_t)m*N + n] = v;
    }
  }
}

// ---------------- MFMA split-bf16 GEMM ----------------
__global__ __launch_bounds__(256, 1) void mgemm_kernel(const float* __restrict__ A,
        const ushort* __restrict__ BhT, const ushort* __restrict__ BlT,
        float* __restrict__ Cm, int M, int N, int K,
        const float* __restrict__ bias, const float* __restrict__ addbuf, int addmode, int act){
  __shared__ __align__(16) ushort Ah[128][32];
  __shared__ __align__(16) ushort Al[128][32];
  __shared__ __align__(16) ushort Bh[128][32];
  __shared__ __align__(16) ushort Bl[128][32];
  int l = threadIdx.x;
  int il = l & 63, wv = l >> 6;
  int wr = wv >> 1, wc = wv & 1;
  int fr = il & 15, fg = il >> 4;
  int m0 = blockIdx.y*128, n0 = blockIdx.x*128;
  int srow = l >> 1, shalf = (l & 1) * 16;       // stage: row srow, 16 elems at shalf
  const float*  Ap  = A   + (size_t)(m0 + srow)*K + shalf;
  const ushort* Bhp = BhT + (size_t)(n0 + srow)*K + shalf;
  const ushort* Blp = BlT + (size_t)(n0 + srow)*K + shalf;
  f32x4 acc[4][4];
  #pragma unroll
  for (int i = 0; i < 4; i++)
    #pragma unroll
    for (int j = 0; j < 4; j++)
      acc[i][j] = (f32x4){0.f, 0.f, 0.f, 0.f};
  for (int k0 = 0; k0 < K; k0 += 32){
    float4 a0 = *(const float4*)(Ap + k0);
    float4 a1 = *(const float4*)(Ap + k0 + 4);
    float4 a2 = *(const float4*)(Ap + k0 + 8);
    float4 a3 = *(const float4*)(Ap + k0 + 12);
    uint4 bh0 = *(const uint4*)(Bhp + k0);
    uint4 bh1 = *(const uint4*)(Bhp + k0 + 8);
    uint4 bl0 = *(const uint4*)(Blp + k0);
    uint4 bl1 = *(const uint4*)(Blp + k0 + 8);
    __syncthreads();                        // previous iteration's frag reads done
    uint4 h0, h1, l0v, l1v;
    h0.x = pack_hi(a0.x,a0.y); h0.y = pack_hi(a0.z,a0.w);
    h0.z = pack_hi(a1.x,a1.y); h0.w = pack_hi(a1.z,a1.w);
    h1.x = pack_hi(a2.x,a2.y); h1.y = pack_hi(a2.z,a2.w);
    h1.z = pack_hi(a3.x,a3.y); h1.w = pack_hi(a3.z,a3.w);
    l0v.x = pack_lo(a0.x,a0.y); l0v.y = pack_lo(a0.z,a0.w);
    l0v.z = pack_lo(a1.x,a1.y); l0v.w = pack_lo(a1.z,a1.w);
    l1v.x = pack_lo(a2.x,a2.y); l1v.y = pack_lo(a2.z,a2.w);
    l1v.z = pack_lo(a3.x,a3.y); l1v.w = pack_lo(a3.z,a3.w);
    *(uint4*)&Ah[srow][shalf]   = h0;  *(uint4*)&Ah[srow][shalf+8] = h1;
    *(uint4*)&Al[srow][shalf]   = l0v; *(uint4*)&Al[srow][shalf+8] = l1v;
    *(uint4*)&Bh[srow][shalf]   = bh0; *(uint4*)&Bh[srow][shalf+8] = bh1;
    *(uint4*)&Bl[srow][shalf]   = bl0; *(uint4*)&Bl[srow][shalf+8] = bl1;
    __syncthreads();
    bf16x8 afh[4], afl[4], bfh[4], bfl[4];
    #pragma unroll
    for (int q = 0; q < 4; q++){
      afh[q] = *(const bf16x8*)&Ah[wr*64 + q*16 + fr][fg*8];
      afl[q] = *(const bf16x8*)&Al[wr*64 + q*16 + fr][fg*8];
      bfh[q] = *(const bf16x8*)&Bh[wc*64 + q*16 + fr][fg*8];
      bfl[q] = *(const bf16x8*)&Bl[wc*64 + q*16 + fr][fg*8];
    }
    #pragma unroll
    for (int i = 0; i < 4; i++)
      #pragma unroll
      for (int j = 0; j < 4; j++)
        acc[i][j] = __builtin_amdgcn_mfma_f32_16x16x32_bf16(afh[i], bfh[j], acc[i][j], 0, 0, 0);
    #pragma unroll
    for (int i = 0; i < 4; i++)
      #pragma unroll
      for (int j = 0; j < 4; j++)
        acc[i][j] = __builtin_amdgcn_mfma_f32_16x16x32_bf16(afh[i], bfl[j], acc[i][j], 0, 0, 0);
    #pragma unroll
    for (int i = 0; i < 4; i++)
      #pragma unroll
      for (int j = 0; j < 4; j++)
        acc[i][j] = __builtin_amdgcn_mfma_f32_16x16x32_bf16(afl[i], bfh[j], acc[i][j], 0, 0, 0);
  }
  #pragma unroll
  for (int i = 0; i < 4; i++){
    #pragma unroll
    for (int j = 0; j < 4; j++){
      #pragma unroll
      for (int r = 0; r < 4; r++){
        int m = m0 + wr*64 + i*16 + fg*4 + r;
        int n = n0 + wc*64 + j*16 + fr;
        float v = acc[i][j][r];
        if (bias) v += bias[n];
        if (act == 1) v = 0.5f*v*(1.0f + erff(v*0.7071067811865475f));
        if (addmode == 1) v += addbuf[(size_t)(m & 15)*N + n];
        else if (addmode == 2) v += addbuf[(size_t)m*N + n];
        Cm[(size_t)m*N + n] = v;
      }
    }
  }
}

// ---------------- attention, phase 1 ----------------
__global__ __launch_bounds__(128) void attn1_kernel(const float* __restrict__ Kb, const float* __restrict__ Vb,
        const float* __restrict__ Qp, float* __restrict__ ctxb){
  int idx = blockIdx.x;                 // b*256 + ch
  int b = idx >> 8, ch = idx & 255;
  size_t m0 = (size_t)b*Tdim + ch*16;
  int t = threadIdx.x >> 3, h = threadIdx.x & 7;
  const float* q = Qp + t*Cdim + h*64;
  float qr[64];
  #pragma unroll
  for (int d = 0; d < 64; d += 4){ float4 f = *(const float4*)(q+d); qr[d]=f.x; qr[d+1]=f.y; qr[d+2]=f.z; qr[d+3]=f.w; }
  float s[16];
  #pragma unroll
  for (int k = 0; k < 16; k++){
    const float* kr = Kb + (m0+k)*Cdim + h*64;
    float acc = 0.f;
    #pragma unroll
    for (int d = 0; d < 64; d += 4){
      float4 f = *(const float4*)(kr+d);
      acc = fmaf(qr[d],f.x,acc); acc = fmaf(qr[d+1],f.y,acc);
      acc = fmaf(qr[d+2],f.z,acc); acc = fmaf(qr[d+3],f.w,acc);
    }
    s[k] = acc * 0.125f;
  }
  float mx = s[0];
  #pragma unroll
  for (int k = 1; k < 16; k++) mx = fmaxf(mx, s[k]);
  float sum = 0.f;
  #pragma unroll
  for (int k = 0; k < 16; k++){ s[k] = expf(s[k]-mx); sum += s[k]; }
  float inv = 1.0f/sum;
  float ctx[64];
  #pragma unroll
  for (int d = 0; d < 64; d++) ctx[d] = 0.f;
  #pragma unroll
  for (int k = 0; k < 16; k++){
    float p = s[k]*inv;
    const float* vr = Vb + (m0+k)*Cdim + h*64;
    #pragma unroll
    for (int d = 0; d < 64; d += 4){
      float4 f = *(const float4*)(vr+d);
      ctx[d]=fmaf(p,f.x,ctx[d]); ctx[d+1]=fmaf(p,f.y,ctx[d+1]);
      ctx[d+2]=fmaf(p,f.z,ctx[d+2]); ctx[d+3]=fmaf(p,f.w,ctx[d+3]);
    }
  }
  float* o = ctxb + (m0+t)*Cdim + h*64;
  #pragma unroll
  for (int d = 0; d < 64; d += 4){
    float4 f; f.x=ctx[d]; f.y=ctx[d+1]; f.z=ctx[d+2]; f.w=ctx[d+3];
    *(float4*)(o+d) = f;
  }
}

// ---------------- attention, phase 2 ----------------
__global__ __launch_bounds__(64) void attn2_kernel(const float* __restrict__ Kb, const float* __restrict__ Vb,
        const float* __restrict__ Qp, float* __restrict__ ctxb){
  int m2 = blockIdx.x;                 // b*256 + ch
  int b = m2 >> 8, ch = m2 & 255;
  size_t m0 = (size_t)b*Tdim + ch*16;
  int h = threadIdx.x;
  if (h >= 8) return;
  const float* q = Qp + (size_t)m2*Cdim + h*64;
  float qr[64];
  #pragma unroll
  for (int d = 0; d < 64; d += 4){ float4 f = *(const float4*)(q+d); qr[d]=f.x; qr[d+1]=f.y; qr[d+2]=f.z; qr[d+3]=f.w; }
  float s[16];
  #pragma unroll
  for (int k = 0; k < 16; k++){
    const float* kr = Kb + (m0+k)*Cdim + h*64;
    float acc = 0.f;
    #pragma unroll
    for (int d = 0; d < 64; d += 4){
      float4 f = *(const float4*)(kr+d);
      acc = fmaf(qr[d],f.x,acc); acc = fmaf(qr[d+1],f.y,acc);
      acc = fmaf(qr[d+2],f.z,acc); acc = fmaf(qr[d+3],f.w,acc);
    }
    s[k] = acc * 0.125f;
  }
  float mx = s[0];
  #pragma unroll
  for (int k = 1; k < 16; k++) mx = fmaxf(mx, s[k]);
  float sum = 0.f;
  #pragma unroll
  for (int k = 0; k < 16; k++){ s[k] = expf(s[k]-mx); sum += s[k]; }
  float inv = 1.0f/sum;
  float ctx[64];
  #pragma unroll
  for (int d = 0; d < 64; d++) ctx[d] = 0.f;
  #pragma unroll
  for (int k = 0; k < 16; k++){
    float p = s[k]*inv;
    const float* vr = Vb + (m0+k)*Cdim + h*64;
    #pragma unroll
    for (int d = 0; d < 64; d += 4){
      float4 f = *(const float4*)(vr+d);
      ctx[d]=fmaf(p,f.x,ctx[d]); ctx[d+1]=fmaf(p,f.y,ctx[d+1]);
      ctx[d+2]=fmaf(p,f.z,ctx[d+2]); ctx[d+3]=fmaf(p,f.w,ctx[d+3]);
    }
  }
  float* o = ctxb + (size_t)m2*Cdim + h*64;
  #pragma unroll
  for (int d = 0; d < 64; d += 4){
    float4 f; f.x=ctx[d]; f.y=ctx[d+1]; f.z=ctx[d+2]; f.w=ctx[d+3];
    *(float4*)(o+d) = f;
  }
}

// ---------------- phase 2: build token-0 query rows (carry + pe[:,0], LN) ----------------
__global__ __launch_bounds__(256) void q2_kernel(const float* __restrict__ dout, float* __restrict__ p2q,
        const float* __restrict__ g, const float* __restrict__ bia){
  int m2 = blockIdx.x; int tid = threadIdx.x;
  int b = m2 >> 8, ch = m2 & 255;
  int tprev = ch*16 - 1;
  float v0, v1;
  {
    int c = tid;
    float carry = (ch == 0) ? 0.f : dout[((size_t)(b*Cdim + c))*Tdim + tprev];
    v0 = carry + ((c & 1) ? 1.f : 0.f);     // pe[c,0] = c even ? sin(0)=0 : cos(0)=1
  }
  {
    int c = tid + 256;
    float carry = (ch == 0) ? 0.f : dout[((size_t)(b*Cdim + c))*Tdim + tprev];
    v1 = carry + ((c & 1) ? 1.f : 0.f);
  }
  __shared__ float red[256];
  red[tid] = v0+v1; __syncthreads();
  for (int s = 128; s > 0; s >>= 1){ if (tid < s) red[tid] += red[tid+s]; __syncthreads(); }
  float mean = red[0]*(1.f/512.f); __syncthreads();
  float d0 = v0-mean, d1 = v1-mean;
  red[tid] = d0*d0 + d1*d1; __syncthreads();
  for (int s = 128; s > 0; s >>= 1){ if (tid < s) red[tid] += red[tid+s]; __syncthreads(); }
  float rstd = 1.0f/sqrtf(red[0]*(1.f/512.f) + 1e-5f);
  p2q[(size_t)m2*Cdim + tid]       = d0*rstd*g[tid]     + bia[tid];
  p2q[(size_t)m2*Cdim + tid + 256] = d1*rstd*g[tid+256] + bia[tid+256];
}

// ---------------- phase 2: r = zt[:, :, t0] - z_pred0 ----------------
__global__ __launch_bounds__(256) void r2_kernel(const float* __restrict__ zt, const float* __restrict__ zp,
        float* __restrict__ out){
  int m2 = blockIdx.x; int tid = threadIdx.x;
  int b = m2 >> 8, ch = m2 & 255; int t0 = ch*16;
  #pragma unroll
  for (int u = 0; u < 2; u++){
    int c = tid + u*256;
    out[(size_t)m2*Cdim + c] = zt[((size_t)(b*Cdim + c))*Tdim + t0] - zp[(size_t)m2*Cdim + c];
  }
}

// ---------------- phase 2: scatter z_hat token-0 columns into d_out ----------------
__global__ __launch_bounds__(256) void scatter2_kernel(const float* __restrict__ z, float* __restrict__ dout){
  int m2 = blockIdx.x; int tid = threadIdx.x;
  int b = m2 >> 8, ch = m2 & 255; int t0 = ch*16;
  #pragma unroll
  for (int u = 0; u < 2; u++){
    int c = tid + u*256;
    dout[((size_t)(b*Cdim + c))*Tdim + t0] = z[(size_t)m2*Cdim + c];
  }
}

// ---------------- phase-1 residual VQ, monolithic (MT=128, 8x16 per-thread blocking) ----------------
// Per book: scores = res[128,96] @ E^T[96,1024] in 256-cand tiles. Per-thread acc[8][16]:
// per kk per wave = 6 ds_read_b128 for 128 FMA (288 vs 256 cyc -> near-balanced, was 1.5x LDS-bound).
// Cross-thread argmax via 16-lane shfl_xor butterfly (no LDS arrays): ascending per-thread cands +
// (s>, ==&&idx<) merge == exact jnp.argmax first-max. LDS 145.5KB (As 48K + Es 96K + hs/sel).
__global__ __launch_bounds__(256, 1) void vq1_kernel(float* __restrict__ x,
        const float* __restrict__ books, const float* __restrict__ booksT,
        const float* __restrict__ hb){
  int l = threadIdx.x;
  int tx = l & 15, ty = l >> 4;          // tx: 16 cand groups, ty: 16 row groups (8 rows each)
  int tok = l >> 1, part = l & 1;        // staging/update: 2 threads per token, 48 floats each
  size_t tok0 = (size_t)blockIdx.x * 128;
  __shared__ float As[96][128];          // res^T
  __shared__ float Es[96][256];          // E^T candidate tile (256 wide)
  __shared__ float hs[256];
  __shared__ int   sel[128];
  float* xp = x + (tok0 + tok)*CD;
  #pragma unroll
  for (int j = 0; j < 12; j++){
    int d4 = part*12 + j;
    float4 v = *(const float4*)(xp + d4*4);
    As[d4*4+0][tok]=v.x; As[d4*4+1][tok]=v.y; As[d4*4+2][tok]=v.z; As[d4*4+3][tok]=v.w;
  }
  for (int k = 0; k < NB; k++){
    const float* bT = booksT + (size_t)k*CD*NE;
    const float* hk = hb + k*NE;
    float best[8]; int bidx[8];
    #pragma unroll
    for (int i = 0; i < 8; i++){ best[i] = -3.0e38f; bidx[i] = 0; }
    for (int t = 0; t < 4; t++){
      int n0 = t*256;
      __syncthreads();                 // orders As writes (init/update) + prev Es reads
      #pragma unroll
      for (int j = 0; j < 24; j++){    // stage 96x256 E^T tile, coalesced
        int f4 = j*256 + l;
        int d = f4 >> 6, c4 = f4 & 63;
        float4 v = *(const float4*)(bT + (size_t)d*NE + n0 + c4*4);
        *(float4*)(&Es[d][c4*4]) = v;
      }
      if (l < 64){
        float4 hv = *(const float4*)(hk + n0 + l*4);
        *(float4*)(&hs[l*4]) = hv;
      }
      __syncthreads();
      float acc[8][16];
      #pragma unroll
      for (int i = 0; i < 8; i++)
        #pragma unroll
        for (int j = 0; j < 16; j++) acc[i][j] = 0.f;
      #pragma unroll 2
      for (int kk = 0; kk < 96; kk++){
        float av[8], bw[16];
        *(float4*)(av)   = *(const float4*)(&As[kk][ty*8]);
        *(float4*)(av+4) = *(const float4*)(&As[kk][ty*8+4]);
        #pragma unroll
        for (int p = 0; p < 4; p++)
          *(float4*)(bw + p*4) = *(const float4*)(&Es[kk][p*64 + tx*4]);
        #pragma unroll
        for (int i = 0; i < 8; i++)
          #pragma unroll
          for (int j = 0; j < 16; j++)
            acc[i][j] = fmaf(av[i], bw[j], acc[i][j]);
      }
      #pragma unroll
      for (int i = 0; i < 8; i++){
        #pragma unroll
        for (int j = 0; j < 16; j++){
          int cl = (j>>2)*64 + tx*4 + (j&3);     // ascending within thread (j = p*4+q)
          float s = acc[i][j] - hs[cl];
          if (s > best[i]){ best[i] = s; bidx[i] = n0 + cl; }
        }
      }
    }
    // cross-thread argmax: 16 tx-partials per row group live in 16 consecutive lanes
    #pragma unroll
    for (int i = 0; i < 8; i++){
      float s = best[i]; int idx = bidx[i];
      #pragma unroll
      for (int m = 1; m < 16; m <<= 1){
        float os = __shfl_xor(s, m);
        int   oi = __shfl_xor(idx, m);
        if (os > s || (os == s && oi < idx)){ s = os; idx = oi; }
      }
      if (tx == 0) sel[ty*8 + i] = idx;
    }
    __syncthreads();
    int s = sel[tok];
    const float* e = books + ((size_t)k*NE + s)*CD;
    #pragma unroll
    for (int j = 0; j < 12; j++){
      int d4 = part*12 + j;
      float4 v = *(const float4*)(e + d4*4);
      As[d4*4+0][tok] -= v.x; As[d4*4+1][tok] -= v.y;
      As[d4*4+2][tok] -= v.z; As[d4*4+3][tok] -= v.w;
    }
  }
  // q_sum = x - res_final (thread reads exactly the cells it wrote)
  #pragma unroll
  for (int j = 0; j < 12; j++){
    int d4 = part*12 + j;
    float4 xo = *(const float4*)(xp + d4*4);
    float4 q;
    q.x = xo.x - As[d4*4+0][tok];
    q.y = xo.y - As[d4*4+1][tok];
    q.z = xo.z - As[d4*4+2][tok];
    q.w = xo.w - As[d4*4+3][tok];
    *(float4*)(xp + d4*4) = q;
  }
}

// ---------------- phase-2 residual VQ, split per book (fixes 32-block starvation) ----------------
// vq2a: per (candblk of 128, tokblk of 64) block computes partial argmax -> (score, idx) to global.
// 256 blocks/book = full GPU (was 32). vq2b: merge 8 partials (ascending -> first-max), res update;
// k==0 reads x, k==NB-1 writes q = x - res directly.
__global__ __launch_bounds__(256, 2) void vq2a_kernel(const float* __restrict__ src,
        const float* __restrict__ booksT, const float* __restrict__ hb,
        float* __restrict__ ps, int* __restrict__ pi, int k){
  int l = threadIdx.x;
  int tx = l & 15, ty = l >> 4;
  int cb = blockIdx.x;                   // 0..7
  int tok0 = blockIdx.y * 64;
  int n0 = cb * 128;
  __shared__ float As[96][64];
  __shared__ float Es[96][128];
  __shared__ float hs[128];
  {
    int tok = l >> 2, part = l & 3;
    const float* sp = src + (size_t)(tok0 + tok)*CD;
    #pragma unroll
    for (int j = 0; j < 6; j++){
      int d4 = part*6 + j;
      float4 v = *(const float4*)(sp + d4*4);
      As[d4*4+0][tok]=v.x; As[d4*4+1][tok]=v.y; As[d4*4+2][tok]=v.z; As[d4*4+3][tok]=v.w;
    }
  }
  const float* bT = booksT + (size_t)k*CD*NE;
  #pragma unroll
  for (int j = 0; j < 12; j++){
    int f4 = j*256 + l;
    int d = f4 >> 5, c4 = f4 & 31;
    float4 v = *(const float4*)(bT + (size_t)d*NE + n0 + c4*4);
    *(float4*)(&Es[d][c4*4]) = v;
  }
  if (l < 32){
    float4 hv = *(const float4*)(hb + k*NE + n0 + l*4);
    *(float4*)(&hs[l*4]) = hv;
  }
  __syncthreads();
  float acc[4][8];
  #pragma unroll
  for (int i = 0; i < 4; i++)
    #pragma unroll
    for (int j = 0; j < 8; j++) acc[i][j] = 0.f;
  #pragma unroll 2
  for (int kk = 0; kk < 96; kk++){
    float av[4], bw[8];
    *(float4*)(av)   = *(const float4*)(&As[kk][ty*4]);
    *(float4*)(bw)   = *(const float4*)(&Es[kk][tx*4]);
    *(float4*)(bw+4) = *(const float4*)(&Es[kk][64 + tx*4]);
    #pragma unroll
    for (int i = 0; i < 4; i++)
      #pragma unroll
      for (int j = 0; j < 8; j++)
        acc[i][j] = fmaf(av[i], bw[j], acc[i][j]);
  }
  #pragma unroll
  for (int i = 0; i < 4; i++){
    float best = -3.0e38f; int bidx = 0;
    #pragma unroll
    for (int j = 0; j < 8; j++){
      int cl = (j>>2)*64 + tx*4 + (j&3);       // ascending within thread
      float s = acc[i][j] - hs[cl];
      if (s > best){ best = s; bidx = n0 + cl; }
    }
    #pragma unroll
    for (int m = 1; m < 16; m <<= 1){
      float os = __shfl_xor(best, m);
      int   oi = __shfl_xor(bidx, m);
      if (os > best || (os == best && oi < bidx)){ best = os; bidx = oi; }
    }
    if (tx == 0){
      int row = tok0 + ty*4 + i;
      ps[cb*M2tok + row] = best;
      pi[cb*M2tok + row] = bidx;
    }
  }
}

__global__ __launch_bounds__(256) void vq2b_kernel(float* __restrict__ x, float* __restrict__ res,
        const float* __restrict__ books, const float* __restrict__ ps, const int* __restrict__ pi, int k){
  int l = threadIdx.x;
  int tok = blockIdx.x*32 + (l >> 3);
  int part = l & 7;                      // 12 floats per thread
  float bb = ps[tok]; int bi = pi[tok];
  #pragma unroll
  for (int c = 1; c < 8; c++){
    float s2 = ps[c*M2tok + tok]; int i2 = pi[c*M2tok + tok];
    if (s2 > bb || (s2 == bb && i2 < bi)){ bb = s2; bi = i2; }
  }
  const float* e = books + ((size_t)k*NE + bi)*CD + part*12;
  const float* sp = ((k == 0) ? (const float*)x : (const float*)res) + (size_t)tok*CD + part*12;
  float r[12];
  #pragma unroll
  for (int j = 0; j < 12; j += 4){
    float4 sv = *(const float4*)(sp + j);
    float4 ev = *(const float4*)(e + j);
    r[j]=sv.x-ev.x; r[j+1]=sv.y-ev.y; r[j+2]=sv.z-ev.z; r[j+3]=sv.w-ev.w;
  }
  if (k < NB-1){
    float* rp = res + (size_t)tok*CD + part*12;
    #pragma unroll
    for (int j = 0; j < 12; j += 4){
      float4 v; v.x=r[j]; v.y=r[j+1]; v.z=r[j+2]; v.w=r[j+3];
      *(float4*)(rp + j) = v;
    }
  } else {
    float* xq = x + (size_t)tok*CD + part*12;
    #pragma unroll
    for (int j = 0; j < 12; j += 4){
      float4 xo = *(const float4*)(xq + j);
      float4 v; v.x=xo.x-r[j]; v.y=xo.y-r[j+1]; v.z=xo.z-r[j+2]; v.w=xo.w-r[j+3];
      *(float4*)(xq + j) = v;
    }
  }
}

// ---------------- host ----------------
extern "C" void kernel_launch(void* const* d_in, const int* in_sizes, int n_in,
                              void* d_out, int out_size, void* d_ws, size_t ws_size,
                              hipStream_t stream) {
  const float* qa    = (const float*)d_in[0];
  const float* zt    = (const float*)d_in[1];
  const float* lnq_g = (const float*)d_in[2];
  const float* lnq_b = (const float*)d_in[3];
  const float* lnkv_g= (const float*)d_in[4];
  const float* lnkv_b= (const float*)d_in[5];
  const float* Wq    = (const float*)d_in[6];
  const float* Wk    = (const float*)d_in[7];
  const float* Wv    = (const float*)d_in[8];
  const float* Wo    = (const float*)d_in[9];
  const float* ffn_g = (const float*)d_in[10];
  const float* ffn_b = (const float*)d_in[11];
  const float* W1    = (const float*)d_in[12];
  const float* b1    = (const float*)d_in[13];
  const float* W2    = (const float*)d_in[14];
  const float* b2    = (const float*)d_in[15];
  const float* tn_g  = (const float*)d_in[16];
  const float* tn_b  = (const float*)d_in[17];
  const float* scale = (const float*)d_in[18];
  const float* Wd    = (const float*)d_in[19];
  const float* bd    = (const float*)d_in[20];
  const float* Wu    = (const float*)d_in[21];
  const float* bu    = (const float*)d_in[22];
  const float* books = (const float*)d_in[23];
  float* out = (float*)d_out;

  // ---- workspace layout (~217 MiB) ----
  float* ws = (float*)d_ws;
  size_t off = 0;
  float* pe_tab  = ws + off; off += 16*512;
  float* qc_ln   = ws + off; off += 16*512;
  float* qc_proj = ws + off; off += 16*512;
  float* WdT     = ws + off; off += 512*96;
  float* hbuf    = ws + off; off += 8*1024;
  // split-bf16 transposed weight pairs (ushort), 16B-aligned (off stays multiple of 4)
  ushort* wub = (ushort*)(ws + off); off += 2146304;   // 4,292,608 ushorts
  ushort* WqTh = wub;            ushort* WqTl = WqTh + 262144;
  ushort* WkTh = WqTl + 262144;  ushort* WkTl = WkTh + 262144;
  ushort* WvTh = WkTl + 262144;  ushort* WvTl = WvTh + 262144;
  ushort* WoTh = WvTl + 262144;  ushort* WoTl = WoTh + 262144;
  ushort* W1Th = WoTl + 262144;  ushort* W1Tl = W1Th + 524288;
  ushort* W2Th = W1Tl + 524288;  ushort* W2Tl = W2Th + 524288;
  ushort* WuPh = W2Tl + 524288;  ushort* WuPl = WuPh + 49152;
  float* bA      = ws + off; off += (size_t)Mtok*512;   // kv rows -> ctx -> lny -> rn -> zhat rows -> phase2 scratch
  float* bK      = ws + off; off += (size_t)Mtok*512;
  float* bV      = ws + off; off += (size_t)Mtok*512;
  float* bH      = ws + off; off += (size_t)4096*1024;  // FFN hidden tile; also hosts bX + booksT
  float* bX      = bH;                                  // Mtok*96 = 12.6MB
  float* booksTp = bH + (size_t)Mtok*CD;                // 3MB in bH's spare tail
  float* bY      = out;                                 // y / z_pred rows live in d_out

  // phase-2 scratch carved inside bA (only used after tout consumes bA)
  float* p2q   = bA;
  float* p2Qp  = bA + 1048576;
  float* p2ctx = bA + 2*1048576;
  float* p2y   = bA + 3*1048576;
  float* p2lny = bA + 4*1048576;
  float* p2h   = bA + 5*1048576;          // 2048*1024
  float* p2r   = bA + 7*1048576;
  float* p2x   = bA + 8*1048576;          // 2048*96
  float* p2z   = bA + 8*1048576 + 196608;
  float* res2  = bA + 10*1048576;         // 2048*96 residual state for split VQ
  float* ps2   = bA + 10*1048576 + 196608;           // 8*2048 partial scores
  int*   pi2   = (int*)(bA + 10*1048576 + 196608 + 16384);  // 8*2048 partial idx

  dim3 tpb32(32, 8);
  dim3 tgrid(Tdim/32, Cdim/32, Bsz);

  // ---- prep ----
  hipLaunchKernelGGL(pe_qc_kernel, dim3(16), dim3(256), 0, stream, pe_tab, qc_ln, lnq_g, lnq_b);
  hipLaunchKernelGGL(twd_kernel, dim3((96*512+255)/256), dim3(256), 0, stream, Wd, WdT);
  hipLaunchKernelGGL(hb_kernel, dim3((NB*NE+255)/256), dim3(256), 0, stream, books, hbuf);
  hipLaunchKernelGGL(cvtT_kernel, dim3(16, 16), tpb32, 0, stream, Wq, WqTh, WqTl, 512, 512);
  hipLaunchKernelGGL(cvtT_kernel, dim3(16, 16), tpb32, 0, stream, Wk, WkTh, WkTl, 512, 512);
  hipLaunchKernelGGL(cvtT_kernel, dim3(16, 16), tpb32, 0, stream, Wv, WvTh, WvTl, 512, 512);
  hipLaunchKernelGGL(cvtT_kernel, dim3(16, 16), tpb32, 0, stream, Wo, WoTh, WoTl, 512, 512);
  hipLaunchKernelGGL(cvtT_kernel, dim3(32, 16), tpb32, 0, stream, W1, W1Th, W1Tl, 512, 1024);
  hipLaunchKernelGGL(cvtT_kernel, dim3(16, 32), tpb32, 0, stream, W2, W2Th, W2Tl, 1024, 512);
  hipLaunchKernelGGL(cvtP_kernel, dim3((512*96+255)/256), dim3(256), 0, stream, Wu, WuPh, WuPl, 512*96);

  // ---- phase 1: kv path ----
  hipLaunchKernelGGL(tin_kernel, tgrid, tpb32, 0, stream, qa, pe_tab, bA);
  hipLaunchKernelGGL(ln_rows_kernel, dim3(Mtok), dim3(256), 0, stream, bA, bA, lnkv_g, lnkv_b, 0, scale);
  hipLaunchKernelGGL(mgemm_kernel, dim3(4, Mtok/128), dim3(256), 0, stream, bA, WkTh, WkTl, bK, Mtok, 512, 512,
                     (const float*)nullptr, (const float*)nullptr, 0, 0);
  hipLaunchKernelGGL(mgemm_kernel, dim3(4, Mtok/128), dim3(256), 0, stream, bA, WvTh, WvTl, bV, Mtok, 512, 512,
                     (const float*)nullptr, (const float*)nullptr, 0, 0);
  hipLaunchKernelGGL(gemm_kernel, dim3(8, 1), dim3(256), 0, stream, qc_ln, Wq, qc_proj, 16, 512, 512,
                     (const float*)nullptr, (const float*)nullptr, 0, 0);

  // ---- phase 1: attention + Wo + FFN ----
  hipLaunchKernelGGL(attn1_kernel, dim3(M2tok), dim3(128), 0, stream, bK, bV, qc_proj, bA);
  hipLaunchKernelGGL(mgemm_kernel, dim3(4, Mtok/128), dim3(256), 0, stream, bA, WoTh, WoTl, bY, Mtok, 512, 512,
                     (const float*)nullptr, qc_ln, 1, 0);
  hipLaunchKernelGGL(ln_rows_kernel, dim3(Mtok), dim3(256), 0, stream, bY, bA, ffn_g, ffn_b, 0, scale);
  for (int p = 0; p < 8; p++){
    size_t mo = (size_t)p*4096;
    hipLaunchKernelGGL(mgemm_kernel, dim3(8, 4096/128), dim3(256), 0, stream, bA + mo*512, W1Th, W1Tl, bH, 4096, 1024, 512,
                       b1, (const float*)nullptr, 0, 1);
    hipLaunchKernelGGL(mgemm_kernel, dim3(4, 4096/128), dim3(256), 0, stream, bH, W2Th, W2Tl, bY + mo*512, 4096, 512, 1024,
                       b2, bY + mo*512, 2, 0);
  }

  // ---- phase 1: residual -> tanh LN -> Wd -> VQ -> Wu -> z_hat ----
  hipLaunchKernelGGL(resid_kernel, tgrid, tpb32, 0, stream, zt, bY, bA);
  hipLaunchKernelGGL(ln_rows_kernel, dim3(Mtok), dim3(256), 0, stream, bA, bA, tn_g, tn_b, 1, scale);
  hipLaunchKernelGGL(gemm_kernel, dim3(2, Mtok/64), dim3(256), 0, stream, bA, WdT, bX, Mtok, 96, 512,
                     bd, (const float*)nullptr, 0, 0);
  hipLaunchKernelGGL(tbt_kernel, dim3(NE/32, CD/32, NB), tpb32, 0, stream, books, booksTp);
  hipLaunchKernelGGL(vq1_kernel, dim3(Mtok/128), dim3(256), 0, stream, bX, books, booksTp, hbuf);
  hipLaunchKernelGGL(mgemm_kernel, dim3(4, Mtok/128), dim3(256), 0, stream, bX, WuPh, WuPl, bA, Mtok, 512, 96,
                     bu, bY, 2, 0);
  hipLaunchKernelGGL(tout_kernel, tgrid, tpb32, 0, stream, bA, out);

  // ---- phase 2: token 0 of each chunk with true carries ----
  hipLaunchKernelGGL(q2_kernel, dim3(M2tok), dim3(256), 0, stream, out, p2q, lnq_g, lnq_b);
  hipLaunchKernelGGL(mgemm_kernel, dim3(4, M2tok/128), dim3(256), 0, stream, p2q, WqTh, WqTl, p2Qp, M2tok, 512, 512,
                     (const float*)nullptr, (const float*)nullptr, 0, 0);
  hipLaunchKernelGGL(attn2_kernel, dim3(M2tok), dim3(64), 0, stream, bK, bV, p2Qp, p2ctx);
  hipLaunchKernelGGL(mgemm_kernel, dim3(4, M2tok/128), dim3(256), 0, stream, p2ctx, WoTh, WoTl, p2y, M2tok, 512, 512,
                     (const float*)nullptr, p2q, 2, 0);
  hipLaunchKernelGGL(ln_rows_kernel, dim3(M2tok), dim3(256), 0, stream, p2y, p2lny, ffn_g, ffn_b, 0, scale);
  hipLaunchKernelGGL(mgemm_kernel, dim3(8, M2tok/128), dim3(256), 0, stream, p2lny, W1Th, W1Tl, p2h, M2tok, 1024, 512,
                     b1, (const float*)nullptr, 0, 1);
  hipLaunchKernelGGL(mgemm_kernel, dim3(4, M2tok/128), dim3(256), 0, stream, p2h, W2Th, W2Tl, p2y, M2tok, 512, 1024,
                     b2, p2y, 2, 0);
  hipLaunchKernelGGL(r2_kernel, dim3(M2tok), dim3(256), 0, stream, zt, p2y, p2r);
  hipLaunchKernelGGL(ln_rows_kernel, dim3(M2tok), dim3(256), 0, stream, p2r, p2r, tn_g, tn_b, 1, scale);
  hipLaunchKernelGGL(gemm_kernel, dim3(2, M2tok/64), dim3(256), 0, stream, p2r, WdT, p2x, M2tok, 96, 512,
                     bd, (const float*)nullptr, 0, 0);
  for (int k = 0; k < NB; k++){
    hipLaunchKernelGGL(vq2a_kernel, dim3(8, M2tok/64), dim3(256), 0, stream,
                       (k == 0 ? p2x : res2), booksTp, hbuf, ps2, pi2, k);
    hipLaunchKernelGGL(vq2b_kernel, dim3(M2tok/32), dim3(256), 0, stream,
                       p2x, res2, books, ps2, pi2, k);
  }
  hipLaunchKernelGGL(mgemm_kernel, dim3(4, M2tok/128), dim3(256), 0, stream, p2x, WuPh, WuPl, p2z, M2tok, 512, 96,
                     bu, p2y, 2, 0);
  hipLaunchKernelGGL(scatter2_kernel, dim3(M2tok), dim3(256), 0, stream, p2z, out);

  (void)in_sizes; (void)n_in; (void)out_size; (void)ws_size;
}

// Round 7
// 3311.577 us; speedup vs baseline: 2.2917x; 1.0072x over previous
//
#include <hip/hip_runtime.h>
#include <math.h>

#define Bsz 8
#define Cdim 512
#define Tdim 4096
#define NHq 8
#define CD 96
#define NB 8
#define NE 1024
#define NCHq 256
#define Mtok (Bsz*Tdim)     // 32768
#define M2tok (Bsz*NCHq)    // 2048

typedef __attribute__((ext_vector_type(8))) short bf16x8;
typedef __attribute__((ext_vector_type(4))) float f32x4;
typedef unsigned int uint;
typedef unsigned short ushort;

// ---------------- pe + constant query rows ----------------
__global__ __launch_bounds__(256) void pe_qc_kernel(float* pe_tab, float* qc_ln,
        const float* __restrict__ lnq_g, const float* __restrict__ lnq_b){
  int t = blockIdx.x;           // 0..15
  int tid = threadIdx.x;
  __shared__ float red[256];
  double f = -log(10000.0) / (double)Cdim;
  float v[2];
  #pragma unroll
  for (int u = 0; u < 2; ++u){
    int c = tid + u*256;
    int ce = c & ~1;
    double ang = (double)t * exp(f * (double)ce);
    v[u] = (float)((c & 1) ? cos(ang) : sin(ang));
    pe_tab[t*Cdim + c] = v[u];
  }
  red[tid] = v[0] + v[1]; __syncthreads();
  for (int s = 128; s > 0; s >>= 1){ if (tid < s) red[tid] += red[tid+s]; __syncthreads(); }
  float mean = red[0] * (1.f/512.f); __syncthreads();
  float d0 = v[0]-mean, d1 = v[1]-mean;
  red[tid] = d0*d0 + d1*d1; __syncthreads();
  for (int s = 128; s > 0; s >>= 1){ if (tid < s) red[tid] += red[tid+s]; __syncthreads(); }
  float rstd = 1.0f/sqrtf(red[0]*(1.f/512.f) + 1e-5f);
  qc_ln[t*Cdim + tid]       = d0*rstd*lnq_g[tid]     + lnq_b[tid];
  qc_ln[t*Cdim + tid + 256] = d1*rstd*lnq_g[tid+256] + lnq_b[tid+256];
}

// ---------------- generic row LayerNorm (rows of 512) ----------------
// mode 0: dst = norm*g+b ; mode 1: dst = tanh(norm*g+b)*clip(scale)
__global__ __launch_bounds__(256) void ln_rows_kernel(const float* __restrict__ src, float* __restrict__ dst,
        const float* __restrict__ g, const float* __restrict__ bia, int mode, const float* __restrict__ scale_ptr){
  int row = blockIdx.x; int tid = threadIdx.x;
  const float* sr = src + (size_t)row*Cdim;
  float v0 = sr[tid], v1 = sr[tid+256];
  __shared__ float red[256];
  red[tid] = v0+v1; __syncthreads();
  for (int s = 128; s > 0; s >>= 1){ if (tid < s) red[tid] += red[tid+s]; __syncthreads(); }
  float mean = red[0]*(1.f/512.f); __syncthreads();
  float d0 = v0-mean, d1 = v1-mean;
  red[tid] = d0*d0 + d1*d1; __syncthreads();
  for (int s = 128; s > 0; s >>= 1){ if (tid < s) red[tid] += red[tid+s]; __syncthreads(); }
  float rstd = 1.0f/sqrtf(red[0]*(1.f/512.f) + 1e-5f);
  float h0 = d0*rstd*g[tid]     + bia[tid];
  float h1 = d1*rstd*g[tid+256] + bia[tid+256];
  if (mode == 1){
    float sc = *scale_ptr; sc = fminf(fmaxf(sc, 0.005f), 0.5f);
    h0 = tanhf(h0)*sc; h1 = tanhf(h1)*sc;
  }
  float* dr = dst + (size_t)row*Cdim;
  dr[tid] = h0; dr[tid+256] = h1;
}

// ---------------- transposes [B,C,T] <-> token rows [B*T, C] ----------------
__global__ void tin_kernel(const float* __restrict__ qa, const float* __restrict__ pe_tab, float* __restrict__ rows){
  __shared__ float tile[32][33];
  int b = blockIdx.z, c0 = blockIdx.y*32, t0 = blockIdx.x*32;
  int tx = threadIdx.x, ty = threadIdx.y;
  int t = t0 + tx;
  #pragma unroll
  for (int j = 0; j < 4; j++){
    int c = c0 + ty + j*8;
    tile[ty+j*8][tx] = qa[((size_t)(b*Cdim + c))*Tdim + t] + pe_tab[(t & 15)*Cdim + c];
  }
  __syncthreads();
  #pragma unroll
  for (int j = 0; j < 4; j++){
    int tt = t0 + ty + j*8;
    rows[((size_t)(b*Tdim + tt))*Cdim + c0 + tx] = tile[tx][ty+j*8];
  }
}

__global__ void resid_kernel(const float* __restrict__ zt, const float* __restrict__ zp_rows, float* __restrict__ rows){
  __shared__ float tile[32][33];
  int b = blockIdx.z, c0 = blockIdx.y*32, t0 = blockIdx.x*32;
  int tx = threadIdx.x, ty = threadIdx.y;
  int t = t0 + tx;
  #pragma unroll
  for (int j = 0; j < 4; j++){
    int c = c0 + ty + j*8;
    tile[ty+j*8][tx] = zt[((size_t)(b*Cdim + c))*Tdim + t];
  }
  __syncthreads();
  #pragma unroll
  for (int j = 0; j < 4; j++){
    int tt = t0 + ty + j*8;
    size_t o = ((size_t)(b*Tdim + tt))*Cdim + c0 + tx;
    rows[o] = tile[tx][ty+j*8] - zp_rows[o];
  }
}

__global__ void tout_kernel(const float* __restrict__ rows, float* __restrict__ out){
  __shared__ float tile[32][33];
  int b = blockIdx.z, c0 = blockIdx.y*32, t0 = blockIdx.x*32;
  int tx = threadIdx.x, ty = threadIdx.y;
  #pragma unroll
  for (int j = 0; j < 4; j++){
    int tt = t0 + ty + j*8;
    tile[ty+j*8][tx] = rows[((size_t)(b*Tdim + tt))*Cdim + c0 + tx];
  }
  __syncthreads();
  #pragma unroll
  for (int j = 0; j < 4; j++){
    int c = c0 + ty + j*8;
    out[((size_t)(b*Cdim + c))*Tdim + t0 + tx] = tile[tx][ty+j*8];
  }
}

// ---------------- weight transposes ----------------
__global__ void twd_kernel(const float* __restrict__ Wd, float* __restrict__ WdT){ // Wd[96][512] -> WdT[512][96]
  int i = blockIdx.x*256 + threadIdx.x; if (i >= 96*512) return;
  int kq = i / 96, n = i % 96;
  WdT[i] = Wd[(size_t)n*512 + kq];
}

// ---------------- books[k][c][d] -> booksT[k][d][c] (tiled transpose) ----------------
__global__ void tbt_kernel(const float* __restrict__ books, float* __restrict__ booksT){
  __shared__ float tile[32][33];
  int k = blockIdx.z, d0 = blockIdx.y*32, c0 = blockIdx.x*32;
  int tx = threadIdx.x, ty = threadIdx.y;
  #pragma unroll
  for (int j = 0; j < 4; j++){
    int c = c0 + ty + j*8;
    tile[ty+j*8][tx] = books[((size_t)k*NE + c)*CD + d0 + tx];
  }
  __syncthreads();
  #pragma unroll
  for (int j = 0; j < 4; j++){
    int d = d0 + ty + j*8;
    booksT[(size_t)k*CD*NE + (size_t)d*NE + c0 + tx] = tile[tx][ty+j*8];
  }
}

// ---------------- 0.5*||e||^2 per codebook entry ----------------
__global__ void hb_kernel(const float* __restrict__ books, float* __restrict__ hb){
  int j = blockIdx.x*256 + threadIdx.x;
  if (j >= NB*NE) return;
  const float* e = books + (size_t)j*CD;
  float s = 0.f;
  #pragma unroll
  for (int d = 0; d < CD; d++) s = fmaf(e[d], e[d], s);
  hb[j] = 0.5f*s;
}

// ---------------- split-bf16 helpers (hi = truncate, lo = exact residual as bf16) ----------------
__device__ __forceinline__ uint pack_hi(float a, float b){
  uint ua = __float_as_uint(a), ub = __float_as_uint(b);
  return (ua >> 16) | (ub & 0xFFFF0000u);
}
__device__ __forceinline__ uint pack_lo(float a, float b){
  float ha = __uint_as_float(__float_as_uint(a) & 0xFFFF0000u);
  float hb = __uint_as_float(__float_as_uint(b) & 0xFFFF0000u);
  return pack_hi(a - ha, b - hb);
}

// ---------------- weight fp32 [K][N] -> transposed planar bf16 pair [N][K] ----------------
__global__ void cvtT_kernel(const float* __restrict__ W, ushort* __restrict__ hT, ushort* __restrict__ lT,
        int K, int N){
  __shared__ float tile[32][33];
  int k0 = blockIdx.y*32, n0 = blockIdx.x*32;
  int tx = threadIdx.x, ty = threadIdx.y;
  #pragma unroll
  for (int j = 0; j < 4; j++)
    tile[ty+j*8][tx] = W[(size_t)(k0+ty+j*8)*N + n0+tx];
  __syncthreads();
  #pragma unroll
  for (int j = 0; j < 4; j++){
    int n = n0 + ty + j*8;
    float f = tile[tx][ty+j*8];     // = W[k0+tx][n]
    uint u = __float_as_uint(f);
    float hf = __uint_as_float(u & 0xFFFF0000u);
    hT[(size_t)n*K + k0 + tx] = (ushort)(u >> 16);
    lT[(size_t)n*K + k0 + tx] = (ushort)(__float_as_uint(f - hf) >> 16);
  }
}

// ---------------- Wu fp32 [N=512][K=96] -> planar bf16 pair (already BT layout) ----------------
__global__ void cvtP_kernel(const float* __restrict__ X, ushort* __restrict__ h, ushort* __restrict__ lo, int n){
  int i = blockIdx.x*256 + threadIdx.x; if (i >= n) return;
  float f = X[i];
  uint u = __float_as_uint(f);
  float hf = __uint_as_float(u & 0xFFFF0000u);
  h[i]  = (ushort)(u >> 16);
  lo[i] = (ushort)(__float_as_uint(f - hf) >> 16);
}

// ---------------- generic tiled fp32 GEMM (64x64 tile): qc + Wd ----------------
// Wd MUST stay exact fp32: its output feeds the VQ argmax (discontinuous) — split-bf16
// score error ~3e-6 vs top-2 gaps ~4e-4 flipped ~1% of 262K selections (round-6 fail, 0.148).
__global__ __launch_bounds__(256) void gemm_kernel(const float* __restrict__ A, const float* __restrict__ Bm,
        float* __restrict__ Cm, int M, int N, int K,
        const float* __restrict__ bias, const float* __restrict__ addbuf, int addmode, int act){
  __shared__ float As[16][65];
  __shared__ float Bs[16][64];
  int l = threadIdx.x;
  int tx = l & 15, ty = l >> 4;
  int m0 = blockIdx.y*64, n0 = blockIdx.x*64;
  int ai = l >> 2, ak = (l & 3)*4;
  int bk = l >> 4, bj = (l & 15)*4;
  float acc[4][4] = {{0.f}};
  bool nfull = (n0 + 64 <= N);
  for (int k0 = 0; k0 < K; k0 += 16){
    float4 av = make_float4(0.f, 0.f, 0.f, 0.f);
    if (m0 + ai < M) av = *(const float4*)(A + (size_t)(m0+ai)*K + k0 + ak);
    As[ak][ai] = av.x; As[ak+1][ai] = av.y; As[ak+2][ai] = av.z; As[ak+3][ai] = av.w;
    if (nfull){
      *(float4*)(&Bs[bk][bj]) = *(const float4*)(Bm + (size_t)(k0+bk)*N + n0 + bj);
    } else {
      #pragma unroll
      for (int u = 0; u < 4; u++){
        int n = n0 + bj + u;
        Bs[bk][bj+u] = (n < N) ? Bm[(size_t)(k0+bk)*N + n] : 0.f;
      }
    }
    __syncthreads();
    #pragma unroll
    for (int kk = 0; kk < 16; kk++){
      float a0 = As[kk][ty*4], a1 = As[kk][ty*4+1], a2 = As[kk][ty*4+2], a3 = As[kk][ty*4+3];
      float b0 = Bs[kk][tx*4], b1 = Bs[kk][tx*4+1], b2 = Bs[kk][tx*4+2], b3 = Bs[kk][tx*4+3];
      acc[0][0] = fmaf(a0,b0,acc[0][0]); acc[0][1] = fmaf(a0,b1,acc[0][1]);
      acc[0][2] = fmaf(a0,b2,acc[0][2]); acc[0][3] = fmaf(a0,b3,acc[0][3]);
      acc[1][0] = fmaf(a1,b0,acc[1][0]); acc[1][1] = fmaf(a1,b1,acc[1][1]);
      acc[1][2] = fmaf(a1,b2,acc[1][2]); acc[1][3] = fmaf(a1,b3,acc[1][3]);
      acc[2][0] = fmaf(a2,b0,acc[2][0]); acc[2][1] = fmaf(a2,b1,acc[2][1]);
      acc[2][2] = fmaf(a2,b2,acc[2][2]); acc[2][3] = fmaf(a2,b3,acc[2][3]);
      acc[3][0] = fmaf(a3,b0,acc[3][0]); acc[3][1] = fmaf(a3,b1,acc[3][1]);
      acc[3][2] = fmaf(a3,b2,acc[3][2]); acc[3][3] = fmaf(a3,b3,acc[3][3]);
    }
    __syncthreads();
  }
  #pragma unroll
  for (int r = 0; r < 4; r++){
    int m = m0 + ty*4 + r; if (m >= M) continue;
    #pragma unroll
    for (int c = 0; c < 4; c++){
      int n = n0 + tx*4 + c; if (n >= N) continue;
      float v = acc[r][c];
      if (bias) v += bias[n];
      if (act == 1) v = 0.5f*v*(1.0f + erff(v*0.7071067811865475f));
      if (addmode == 1) v += addbuf[(size_t)(m & 15)*N + n];
      else if (addmode == 2) v += addbuf[(size_t)m*N + n];
      Cm[(size_t)m*N + n] = v;
    }
  }
}

// ---------------- MFMA split-bf16 GEMM (lda = A row stride) ----------------
__global__ __launch_bounds__(256, 1) void mgemm_kernel(const float* __restrict__ A,
        const ushort* __restrict__ BhT, const ushort* __restrict__ BlT,
        float* __restrict__ Cm, int M, int N, int K, int lda,
        const float* __restrict__ bias, const float* __restrict__ addbuf, int addmode, int act){
  __shared__ __align__(16) ushort Ah[128][32];
  __shared__ __align__(16) ushort Al[128][32];
  __shared__ __align__(16) ushort Bh[128][32];
  __shared__ __align__(16) ushort Bl[128][32];
  int l = threadIdx.x;
  int il = l & 63, wv = l >> 6;
  int wr = wv >> 1, wc = wv & 1;
  int fr = il & 15, fg = il >> 4;
  int m0 = blockIdx.y*128, n0 = blockIdx.x*128;
  int srow = l >> 1, shalf = (l & 1) * 16;       // stage: row srow, 16 elems at shalf
  const float*  Ap  = A   + (size_t)(m0 + srow)*lda + shalf;
  const ushort* Bhp = BhT + (size_t)(n0 + srow)*K + shalf;
  const ushort* Blp = BlT + (size_t)(n0 + srow)*K + shalf;
  f32x4 acc[4][4];
  #pragma unroll
  for (int i = 0; i < 4; i++)
    #pragma unroll
    for (int j = 0; j < 4; j++)
      acc[i][j] = (f32x4){0.f, 0.f, 0.f, 0.f};
  for (int k0 = 0; k0 < K; k0 += 32){
    float4 a0 = *(const float4*)(Ap + k0);
    float4 a1 = *(const float4*)(Ap + k0 + 4);
    float4 a2 = *(const float4*)(Ap + k0 + 8);
    float4 a3 = *(const float4*)(Ap + k0 + 12);
    uint4 bh0 = *(const uint4*)(Bhp + k0);
    uint4 bh1 = *(const uint4*)(Bhp + k0 + 8);
    uint4 bl0 = *(const uint4*)(Blp + k0);
    uint4 bl1 = *(const uint4*)(Blp + k0 + 8);
    __syncthreads();                        // previous iteration's frag reads done
    uint4 h0, h1, l0v, l1v;
    h0.x = pack_hi(a0.x,a0.y); h0.y = pack_hi(a0.z,a0.w);
    h0.z = pack_hi(a1.x,a1.y); h0.w = pack_hi(a1.z,a1.w);
    h1.x = pack_hi(a2.x,a2.y); h1.y = pack_hi(a2.z,a2.w);
    h1.z = pack_hi(a3.x,a3.y); h1.w = pack_hi(a3.z,a3.w);
    l0v.x = pack_lo(a0.x,a0.y); l0v.y = pack_lo(a0.z,a0.w);
    l0v.z = pack_lo(a1.x,a1.y); l0v.w = pack_lo(a1.z,a1.w);
    l1v.x = pack_lo(a2.x,a2.y); l1v.y = pack_lo(a2.z,a2.w);
    l1v.z = pack_lo(a3.x,a3.y); l1v.w = pack_lo(a3.z,a3.w);
    *(uint4*)&Ah[srow][shalf]   = h0;  *(uint4*)&Ah[srow][shalf+8] = h1;
    *(uint4*)&Al[srow][shalf]   = l0v; *(uint4*)&Al[srow][shalf+8] = l1v;
    *(uint4*)&Bh[srow][shalf]   = bh0; *(uint4*)&Bh[srow][shalf+8] = bh1;
    *(uint4*)&Bl[srow][shalf]   = bl0; *(uint4*)&Bl[srow][shalf+8] = bl1;
    __syncthreads();
    bf16x8 afh[4], afl[4], bfh[4], bfl[4];
    #pragma unroll
    for (int q = 0; q < 4; q++){
      afh[q] = *(const bf16x8*)&Ah[wr*64 + q*16 + fr][fg*8];
      afl[q] = *(const bf16x8*)&Al[wr*64 + q*16 + fr][fg*8];
      bfh[q] = *(const bf16x8*)&Bh[wc*64 + q*16 + fr][fg*8];
      bfl[q] = *(const bf16x8*)&Bl[wc*64 + q*16 + fr][fg*8];
    }
    #pragma unroll
    for (int i = 0; i < 4; i++)
      #pragma unroll
      for (int j = 0; j < 4; j++)
        acc[i][j] = __builtin_amdgcn_mfma_f32_16x16x32_bf16(afh[i], bfh[j], acc[i][j], 0, 0, 0);
    #pragma unroll
    for (int i = 0; i < 4; i++)
      #pragma unroll
      for (int j = 0; j < 4; j++)
        acc[i][j] = __builtin_amdgcn_mfma_f32_16x16x32_bf16(afh[i], bfl[j], acc[i][j], 0, 0, 0);
    #pragma unroll
    for (int i = 0; i < 4; i++)
      #pragma unroll
      for (int j = 0; j < 4; j++)
        acc[i][j] = __builtin_amdgcn_mfma_f32_16x16x32_bf16(afl[i], bfh[j], acc[i][j], 0, 0, 0);
  }
  #pragma unroll
  for (int i = 0; i < 4; i++){
    #pragma unroll
    for (int j = 0; j < 4; j++){
      #pragma unroll
      for (int r = 0; r < 4; r++){
        int m = m0 + wr*64 + i*16 + fg*4 + r;
        int n = n0 + wc*64 + j*16 + fr;
        float v = acc[i][j][r];
        if (bias) v += bias[n];
        if (act == 1) v = 0.5f*v*(1.0f + erff(v*0.7071067811865475f));
        if (addmode == 1) v += addbuf[(size_t)(m & 15)*N + n];
        else if (addmode == 2) v += addbuf[(size_t)m*N + n];
        Cm[(size_t)m*N + n] = v;
      }
    }
  }
}

// ---------------- attention, phase 1 ----------------
__global__ __launch_bounds__(128) void attn1_kernel(const float* __restrict__ Kb, const float* __restrict__ Vb,
        const float* __restrict__ Qp, float* __restrict__ ctxb){
  int idx = blockIdx.x;                 // b*256 + ch
  int b = idx >> 8, ch = idx & 255;
  size_t m0 = (size_t)b*Tdim + ch*16;
  int t = threadIdx.x >> 3, h = threadIdx.x & 7;
  const float* q = Qp + t*Cdim + h*64;
  float qr[64];
  #pragma unroll
  for (int d = 0; d < 64; d += 4){ float4 f = *(const float4*)(q+d); qr[d]=f.x; qr[d+1]=f.y; qr[d+2]=f.z; qr[d+3]=f.w; }
  float s[16];
  #pragma unroll
  for (int k = 0; k < 16; k++){
    const float* kr = Kb + (m0+k)*Cdim + h*64;
    float acc = 0.f;
    #pragma unroll
    for (int d = 0; d < 64; d += 4){
      float4 f = *(const float4*)(kr+d);
      acc = fmaf(qr[d],f.x,acc); acc = fmaf(qr[d+1],f.y,acc);
      acc = fmaf(qr[d+2],f.z,acc); acc = fmaf(qr[d+3],f.w,acc);
    }
    s[k] = acc * 0.125f;
  }
  float mx = s[0];
  #pragma unroll
  for (int k = 1; k < 16; k++) mx = fmaxf(mx, s[k]);
  float sum = 0.f;
  #pragma unroll
  for (int k = 0; k < 16; k++){ s[k] = expf(s[k]-mx); sum += s[k]; }
  float inv = 1.0f/sum;
  float ctx[64];
  #pragma unroll
  for (int d = 0; d < 64; d++) ctx[d] = 0.f;
  #pragma unroll
  for (int k = 0; k < 16; k++){
    float p = s[k]*inv;
    const float* vr = Vb + (m0+k)*Cdim + h*64;
    #pragma unroll
    for (int d = 0; d < 64; d += 4){
      float4 f = *(const float4*)(vr+d);
      ctx[d]=fmaf(p,f.x,ctx[d]); ctx[d+1]=fmaf(p,f.y,ctx[d+1]);
      ctx[d+2]=fmaf(p,f.z,ctx[d+2]); ctx[d+3]=fmaf(p,f.w,ctx[d+3]);
    }
  }
  float* o = ctxb + (m0+t)*Cdim + h*64;
  #pragma unroll
  for (int d = 0; d < 64; d += 4){
    float4 f; f.x=ctx[d]; f.y=ctx[d+1]; f.z=ctx[d+2]; f.w=ctx[d+3];
    *(float4*)(o+d) = f;
  }
}

// ---------------- attention, phase 2 ----------------
__global__ __launch_bounds__(64) void attn2_kernel(const float* __restrict__ Kb, const float* __restrict__ Vb,
        const float* __restrict__ Qp, float* __restrict__ ctxb){
  int m2 = blockIdx.x;                 // b*256 + ch
  int b = m2 >> 8, ch = m2 & 255;
  size_t m0 = (size_t)b*Tdim + ch*16;
  int h = threadIdx.x;
  if (h >= 8) return;
  const float* q = Qp + (size_t)m2*Cdim + h*64;
  float qr[64];
  #pragma unroll
  for (int d = 0; d < 64; d += 4){ float4 f = *(const float4*)(q+d); qr[d]=f.x; qr[d+1]=f.y; qr[d+2]=f.z; qr[d+3]=f.w; }
  float s[16];
  #pragma unroll
  for (int k = 0; k < 16; k++){
    const float* kr = Kb + (m0+k)*Cdim + h*64;
    float acc = 0.f;
    #pragma unroll
    for (int d = 0; d < 64; d += 4){
      float4 f = *(const float4*)(kr+d);
      acc = fmaf(qr[d],f.x,acc); acc = fmaf(qr[d+1],f.y,acc);
      acc = fmaf(qr[d+2],f.z,acc); acc = fmaf(qr[d+3],f.w,acc);
    }
    s[k] = acc * 0.125f;
  }
  float mx = s[0];
  #pragma unroll
  for (int k = 1; k < 16; k++) mx = fmaxf(mx, s[k]);
  float sum = 0.f;
  #pragma unroll
  for (int k = 0; k < 16; k++){ s[k] = expf(s[k]-mx); sum += s[k]; }
  float inv = 1.0f/sum;
  float ctx[64];
  #pragma unroll
  for (int d = 0; d < 64; d++) ctx[d] = 0.f;
  #pragma unroll
  for (int k = 0; k < 16; k++){
    float p = s[k]*inv;
    const float* vr = Vb + (m0+k)*Cdim + h*64;
    #pragma unroll
    for (int d = 0; d < 64; d += 4){
      float4 f = *(const float4*)(vr+d);
      ctx[d]=fmaf(p,f.x,ctx[d]); ctx[d+1]=fmaf(p,f.y,ctx[d+1]);
      ctx[d+2]=fmaf(p,f.z,ctx[d+2]); ctx[d+3]=fmaf(p,f.w,ctx[d+3]);
    }
  }
  float* o = ctxb + (size_t)m2*Cdim + h*64;
  #pragma unroll
  for (int d = 0; d < 64; d += 4){
    float4 f; f.x=ctx[d]; f.y=ctx[d+1]; f.z=ctx[d+2]; f.w=ctx[d+3];
    *(float4*)(o+d) = f;
  }
}

// ---------------- phase 2: build token-0 query rows (carry + pe[:,0], LN) ----------------
__global__ __launch_bounds__(256) void q2_kernel(const float* __restrict__ dout, float* __restrict__ p2q,
        const float* __restrict__ g, const float* __restrict__ bia){
  int m2 = blockIdx.x; int tid = threadIdx.x;
  int b = m2 >> 8, ch = m2 & 255;
  int tprev = ch*16 - 1;
  float v0, v1;
  {
    int c = tid;
    float carry = (ch == 0) ? 0.f : dout[((size_t)(b*Cdim + c))*Tdim + tprev];
    v0 = carry + ((c & 1) ? 1.f : 0.f);     // pe[c,0] = c even ? sin(0)=0 : cos(0)=1
  }
  {
    int c = tid + 256;
    float carry = (ch == 0) ? 0.f : dout[((size_t)(b*Cdim + c))*Tdim + tprev];
    v1 = carry + ((c & 1) ? 1.f : 0.f);
  }
  __shared__ float red[256];
  red[tid] = v0+v1; __syncthreads();
  for (int s = 128; s > 0; s >>= 1){ if (tid < s) red[tid] += red[tid+s]; __syncthreads(); }
  float mean = red[0]*(1.f/512.f); __syncthreads();
  float d0 = v0-mean, d1 = v1-mean;
  red[tid] = d0*d0 + d1*d1; __syncthreads();
  for (int s = 128; s > 0; s >>= 1){ if (tid < s) red[tid] += red[tid+s]; __syncthreads(); }
  float rstd = 1.0f/sqrtf(red[0]*(1.f/512.f) + 1e-5f);
  p2q[(size_t)m2*Cdim + tid]       = d0*rstd*g[tid]     + bia[tid];
  p2q[(size_t)m2*Cdim + tid + 256] = d1*rstd*g[tid+256] + bia[tid+256];
}

// ---------------- phase 2: r = zt[:, :, t0] - z_pred0 ----------------
__global__ __launch_bounds__(256) void r2_kernel(const float* __restrict__ zt, const float* __restrict__ zp,
        float* __restrict__ out){
  int m2 = blockIdx.x; int tid = threadIdx.x;
  int b = m2 >> 8, ch = m2 & 255; int t0 = ch*16;
  #pragma unroll
  for (int u = 0; u < 2; u++){
    int c = tid + u*256;
    out[(size_t)m2*Cdim + c] = zt[((size_t)(b*Cdim + c))*Tdim + t0] - zp[(size_t)m2*Cdim + c];
  }
}

// ---------------- phase 2: scatter z_hat token-0 columns into d_out ----------------
__global__ __launch_bounds__(256) void scatter2_kernel(const float* __restrict__ z, float* __restrict__ dout){
  int m2 = blockIdx.x; int tid = threadIdx.x;
  int b = m2 >> 8, ch = m2 & 255; int t0 = ch*16;
  #pragma unroll
  for (int u = 0; u < 2; u++){
    int c = tid + u*256;
    dout[((size_t)(b*Cdim + c))*Tdim + t0] = z[(size_t)m2*Cdim + c];
  }
}

// ---------------- phase-1 residual VQ (MT=128, 8x16 blocking, reg double-buffer) ----------------
// Round-5 counters: VALU 433us + LDS 369us ran SERIALIZED (832us): at 1 wave/SIMD the reused
// av/bw regs create WAR hazards -> lgkmcnt drain every kk. Fix: two named buffer sets, load
// kk+1 while FMA kk. As/Es padded +1 row so the final prefetch over-read is benign (never used).
__global__ __launch_bounds__(256, 1) void vq1_kernel(float* __restrict__ x,
        const float* __restrict__ books, const float* __restrict__ booksT,
        const float* __restrict__ hb, int xs){
  int l = threadIdx.x;
  int tx = l & 15, ty = l >> 4;          // tx: 16 cand groups, ty: 16 row groups (8 rows each)
  int tok = l >> 1, part = l & 1;        // staging/update: 2 threads per token, 48 floats each
  size_t tok0 = (size_t)blockIdx.x * 128;
  __shared__ float As[97][128];          // res^T (+1 pad row)
  __shared__ float Es[97][256];          // E^T candidate tile (+1 pad row)
  __shared__ float hs[256];
  __shared__ int   sel[128];
  float* xp = x + (tok0 + tok)*xs;
  #pragma unroll
  for (int j = 0; j < 12; j++){
    int d4 = part*12 + j;
    float4 v = *(const float4*)(xp + d4*4);
    As[d4*4+0][tok]=v.x; As[d4*4+1][tok]=v.y; As[d4*4+2][tok]=v.z; As[d4*4+3][tok]=v.w;
  }
  for (int k = 0; k < NB; k++){
    const float* bT = booksT + (size_t)k*CD*NE;
    const float* hk = hb + k*NE;
    float best[8]; int bidx[8];
    #pragma unroll
    for (int i = 0; i < 8; i++){ best[i] = -3.0e38f; bidx[i] = 0; }
    for (int t = 0; t < 4; t++){
      int n0 = t*256;
      __syncthreads();                 // orders As writes (init/update) + prev Es reads
      #pragma unroll
      for (int j = 0; j < 24; j++){    // stage 96x256 E^T tile, coalesced
        int f4 = j*256 + l;
        int d = f4 >> 6, c4 = f4 & 63;
        float4 v = *(const float4*)(bT + (size_t)d*NE + n0 + c4*4);
        *(float4*)(&Es[d][c4*4]) = v;
      }
      if (l < 64){
        float4 hv = *(const float4*)(hk + n0 + l*4);
        *(float4*)(&hs[l*4]) = hv;
      }
      __syncthreads();
      float acc[8][16];
      #pragma unroll
      for (int i = 0; i < 8; i++)
        #pragma unroll
        for (int j = 0; j < 16; j++) acc[i][j] = 0.f;
      float av0[8], bw0[16], av1[8], bw1[16];
      *(float4*)(av0)   = *(const float4*)(&As[0][ty*8]);
      *(float4*)(av0+4) = *(const float4*)(&As[0][ty*8+4]);
      #pragma unroll
      for (int p = 0; p < 4; p++)
        *(float4*)(bw0 + p*4) = *(const float4*)(&Es[0][p*64 + tx*4]);
      for (int kk = 0; kk < 96; kk += 2){
        *(float4*)(av1)   = *(const float4*)(&As[kk+1][ty*8]);
        *(float4*)(av1+4) = *(const float4*)(&As[kk+1][ty*8+4]);
        #pragma unroll
        for (int p = 0; p < 4; p++)
          *(float4*)(bw1 + p*4) = *(const float4*)(&Es[kk+1][p*64 + tx*4]);
        #pragma unroll
        for (int i = 0; i < 8; i++)
          #pragma unroll
          for (int j = 0; j < 16; j++)
            acc[i][j] = fmaf(av0[i], bw0[j], acc[i][j]);
        *(float4*)(av0)   = *(const float4*)(&As[kk+2][ty*8]);      // kk+2==96 hits pad row (unused)
        *(float4*)(av0+4) = *(const float4*)(&As[kk+2][ty*8+4]);
        #pragma unroll
        for (int p = 0; p < 4; p++)
          *(float4*)(bw0 + p*4) = *(const float4*)(&Es[kk+2][p*64 + tx*4]);
        #pragma unroll
        for (int i = 0; i < 8; i++)
          #pragma unroll
          for (int j = 0; j < 16; j++)
            acc[i][j] = fmaf(av1[i], bw1[j], acc[i][j]);
      }
      #pragma unroll
      for (int i = 0; i < 8; i++){
        #pragma unroll
        for (int j = 0; j < 16; j++){
          int cl = (j>>2)*64 + tx*4 + (j&3);     // ascending within thread (j = p*4+q)
          float s = acc[i][j] - hs[cl];
          if (s > best[i]){ best[i] = s; bidx[i] = n0 + cl; }
        }
      }
    }
    // cross-thread argmax: 16 tx-partials per row group live in 16 consecutive lanes
    #pragma unroll
    for (int i = 0; i < 8; i++){
      float s = best[i]; int idx = bidx[i];
      #pragma unroll
      for (int m = 1; m < 16; m <<= 1){
        float os = __shfl_xor(s, m);
        int   oi = __shfl_xor(idx, m);
        if (os > s || (os == s && oi < idx)){ s = os; idx = oi; }
      }
      if (tx == 0) sel[ty*8 + i] = idx;
    }
    __syncthreads();
    int s = sel[tok];
    const float* e = books + ((size_t)k*NE + s)*CD;
    #pragma unroll
    for (int j = 0; j < 12; j++){
      int d4 = part*12 + j;
      float4 v = *(const float4*)(e + d4*4);
      As[d4*4+0][tok] -= v.x; As[d4*4+1][tok] -= v.y;
      As[d4*4+2][tok] -= v.z; As[d4*4+3][tok] -= v.w;
    }
  }
  // q_sum = x - res_final (thread reads exactly the cells it wrote)
  #pragma unroll
  for (int j = 0; j < 12; j++){
    int d4 = part*12 + j;
    float4 xo = *(const float4*)(xp + d4*4);
    float4 q;
    q.x = xo.x - As[d4*4+0][tok];
    q.y = xo.y - As[d4*4+1][tok];
    q.z = xo.z - As[d4*4+2][tok];
    q.w = xo.w - As[d4*4+3][tok];
    *(float4*)(xp + d4*4) = q;
  }
}

// ---------------- phase-2 residual VQ, split per book ----------------
__global__ __launch_bounds__(256, 2) void vq2a_kernel(const float* __restrict__ src, int ss,
        const float* __restrict__ booksT, const float* __restrict__ hb,
        float* __restrict__ ps, int* __restrict__ pi, int k){
  int l = threadIdx.x;
  int tx = l & 15, ty = l >> 4;
  int cb = blockIdx.x;                   // 0..7
  int tok0 = blockIdx.y * 64;
  int n0 = cb * 128;
  __shared__ float As[97][64];
  __shared__ float Es[97][128];
  __shared__ float hs[128];
  {
    int tok = l >> 2, part = l & 3;
    const float* sp = src + (size_t)(tok0 + tok)*ss;
    #pragma unroll
    for (int j = 0; j < 6; j++){
      int d4 = part*6 + j;
      float4 v = *(const float4*)(sp + d4*4);
      As[d4*4+0][tok]=v.x; As[d4*4+1][tok]=v.y; As[d4*4+2][tok]=v.z; As[d4*4+3][tok]=v.w;
    }
  }
  const float* bT = booksT + (size_t)k*CD*NE;
  #pragma unroll
  for (int j = 0; j < 12; j++){
    int f4 = j*256 + l;
    int d = f4 >> 5, c4 = f4 & 31;
    float4 v = *(const float4*)(bT + (size_t)d*NE + n0 + c4*4);
    *(float4*)(&Es[d][c4*4]) = v;
  }
  if (l < 32){
    float4 hv = *(const float4*)(hb + k*NE + n0 + l*4);
    *(float4*)(&hs[l*4]) = hv;
  }
  __syncthreads();
  float acc[4][8];
  #pragma unroll
  for (int i = 0; i < 4; i++)
    #pragma unroll
    for (int j = 0; j < 8; j++) acc[i][j] = 0.f;
  float av0[4], bw0[8], av1[4], bw1[8];
  *(float4*)(av0) = *(const float4*)(&As[0][ty*4]);
  *(float4*)(bw0)   = *(const float4*)(&Es[0][tx*4]);
  *(float4*)(bw0+4) = *(const float4*)(&Es[0][64 + tx*4]);
  for (int kk = 0; kk < 96; kk += 2){
    *(float4*)(av1) = *(const float4*)(&As[kk+1][ty*4]);
    *(float4*)(bw1)   = *(const float4*)(&Es[kk+1][tx*4]);
    *(float4*)(bw1+4) = *(const float4*)(&Es[kk+1][64 + tx*4]);
    #pragma unroll
    for (int i = 0; i < 4; i++)
      #pragma unroll
      for (int j = 0; j < 8; j++)
        acc[i][j] = fmaf(av0[i], bw0[j], acc[i][j]);
    *(float4*)(av0) = *(const float4*)(&As[kk+2][ty*4]);           // pad row at 96 (unused)
    *(float4*)(bw0)   = *(const float4*)(&Es[kk+2][tx*4]);
    *(float4*)(bw0+4) = *(const float4*)(&Es[kk+2][64 + tx*4]);
    #pragma unroll
    for (int i = 0; i < 4; i++)
      #pragma unroll
      for (int j = 0; j < 8; j++)
        acc[i][j] = fmaf(av1[i], bw1[j], acc[i][j]);
  }
  #pragma unroll
  for (int i = 0; i < 4; i++){
    float best = -3.0e38f; int bidx = 0;
    #pragma unroll
    for (int j = 0; j < 8; j++){
      int cl = (j>>2)*64 + tx*4 + (j&3);       // ascending within thread
      float s = acc[i][j] - hs[cl];
      if (s > best){ best = s; bidx = n0 + cl; }
    }
    #pragma unroll
    for (int m = 1; m < 16; m <<= 1){
      float os = __shfl_xor(best, m);
      int   oi = __shfl_xor(bidx, m);
      if (os > best || (os == best && oi < bidx)){ best = os; bidx = oi; }
    }
    if (tx == 0){
      int row = tok0 + ty*4 + i;
      ps[cb*M2tok + row] = best;
      pi[cb*M2tok + row] = bidx;
    }
  }
}

__global__ __launch_bounds__(256) void vq2b_kernel(float* __restrict__ x, int xs, float* __restrict__ res,
        const float* __restrict__ books, const float* __restrict__ ps, const int* __restrict__ pi, int k){
  int l = threadIdx.x;
  int tok = blockIdx.x*32 + (l >> 3);
  int part = l & 7;                      // 12 floats per thread
  float bb = ps[tok]; int bi = pi[tok];
  #pragma unroll
  for (int c = 1; c < 8; c++){
    float s2 = ps[c*M2tok + tok]; int i2 = pi[c*M2tok + tok];
    if (s2 > bb || (s2 == bb && i2 < bi)){ bb = s2; bi = i2; }
  }
  const float* e = books + ((size_t)k*NE + bi)*CD + part*12;
  const float* sp = ((k == 0) ? (const float*)(x + (size_t)tok*xs) : (const float*)(res + (size_t)tok*CD)) + part*12;
  float r[12];
  #pragma unroll
  for (int j = 0; j < 12; j += 4){
    float4 sv = *(const float4*)(sp + j);
    float4 ev = *(const float4*)(e + j);
    r[j]=sv.x-ev.x; r[j+1]=sv.y-ev.y; r[j+2]=sv.z-ev.z; r[j+3]=sv.w-ev.w;
  }
  if (k < NB-1){
    float* rp = res + (size_t)tok*CD + part*12;
    #pragma unroll
    for (int j = 0; j < 12; j += 4){
      float4 v; v.x=r[j]; v.y=r[j+1]; v.z=r[j+2]; v.w=r[j+3];
      *(float4*)(rp + j) = v;
    }
  } else {
    float* xq = x + (size_t)tok*xs + part*12;
    #pragma unroll
    for (int j = 0; j < 12; j += 4){
      float4 xo = *(const float4*)(xq + j);
      float4 v; v.x=xo.x-r[j]; v.y=xo.y-r[j+1]; v.z=xo.z-r[j+2]; v.w=xo.w-r[j+3];
      *(float4*)(xq + j) = v;
    }
  }
}

// ---------------- host ----------------
extern "C" void kernel_launch(void* const* d_in, const int* in_sizes, int n_in,
                              void* d_out, int out_size, void* d_ws, size_t ws_size,
                              hipStream_t stream) {
  const float* qa    = (const float*)d_in[0];
  const float* zt    = (const float*)d_in[1];
  const float* lnq_g = (const float*)d_in[2];
  const float* lnq_b = (const float*)d_in[3];
  const float* lnkv_g= (const float*)d_in[4];
  const float* lnkv_b= (const float*)d_in[5];
  const float* Wq    = (const float*)d_in[6];
  const float* Wk    = (const float*)d_in[7];
  const float* Wv    = (const float*)d_in[8];
  const float* Wo    = (const float*)d_in[9];
  const float* ffn_g = (const float*)d_in[10];
  const float* ffn_b = (const float*)d_in[11];
  const float* W1    = (const float*)d_in[12];
  const float* b1    = (const float*)d_in[13];
  const float* W2    = (const float*)d_in[14];
  const float* b2    = (const float*)d_in[15];
  const float* tn_g  = (const float*)d_in[16];
  const float* tn_b  = (const float*)d_in[17];
  const float* scale = (const float*)d_in[18];
  const float* Wd    = (const float*)d_in[19];
  const float* bd    = (const float*)d_in[20];
  const float* Wu    = (const float*)d_in[21];
  const float* bu    = (const float*)d_in[22];
  const float* books = (const float*)d_in[23];
  float* out = (float*)d_out;

  // ---- workspace layout (~227 MiB, round-5-proven) ----
  float* ws = (float*)d_ws;
  size_t off = 0;
  float* pe_tab  = ws + off; off += 16*512;
  float* qc_ln   = ws + off; off += 16*512;
  float* qc_proj = ws + off; off += 16*512;
  float* WdT     = ws + off; off += 512*96;
  float* hbuf    = ws + off; off += 8*1024;
  // split-bf16 weight pairs (ushort)
  ushort* wub = (ushort*)(ws + off); off += 2146304;   // 4,292,608 ushorts
  ushort* WqTh = wub;            ushort* WqTl = WqTh + 262144;
  ushort* WkTh = WqTl + 262144;  ushort* WkTl = WkTh + 262144;
  ushort* WvTh = WkTl + 262144;  ushort* WvTl = WvTh + 262144;
  ushort* WoTh = WvTl + 262144;  ushort* WoTl = WoTh + 262144;
  ushort* W1Th = WoTl + 262144;  ushort* W1Tl = W1Th + 524288;
  ushort* W2Th = W1Tl + 524288;  ushort* W2Tl = W2Th + 524288;
  ushort* WuPh = W2Tl + 524288;  ushort* WuPl = WuPh + 49152;
  float* bA      = ws + off; off += (size_t)Mtok*512;   // kv rows -> ctx -> lny -> rn -> zhat rows -> phase2 scratch
  float* bK      = ws + off; off += (size_t)Mtok*512;
  float* bV      = ws + off; off += (size_t)Mtok*512;
  float* bH      = ws + off; off += (size_t)4096*1024;  // FFN hidden tile; also hosts bX + booksT
  float* bX      = bH;                                  // Mtok*96 = 12.6MB
  float* booksTp = bH + (size_t)Mtok*CD;                // 3MB in bH's spare tail
  float* bY      = out;                                 // y / z_pred rows live in d_out

  // phase-2 scratch carved inside bA (only used after tout consumes bA)
  float* p2q   = bA;
  float* p2Qp  = bA + 1048576;
  float* p2ctx = bA + 2*1048576;
  float* p2y   = bA + 3*1048576;
  float* p2lny = bA + 4*1048576;
  float* p2h   = bA + 5*1048576;          // 2048*1024
  float* p2r   = bA + 7*1048576;
  float* p2x   = bA + 8*1048576;          // 2048*96
  float* p2z   = bA + 8*1048576 + 196608;
  float* res2  = bA + 10*1048576;         // 2048*96 residual state for split VQ
  float* ps2   = bA + 10*1048576 + 196608;           // 8*2048 partial scores
  int*   pi2   = (int*)(bA + 10*1048576 + 196608 + 16384);  // 8*2048 partial idx

  dim3 tpb32(32, 8);
  dim3 tgrid(Tdim/32, Cdim/32, Bsz);

  // ---- prep ----
  hipLaunchKernelGGL(pe_qc_kernel, dim3(16), dim3(256), 0, stream, pe_tab, qc_ln, lnq_g, lnq_b);
  hipLaunchKernelGGL(twd_kernel, dim3((96*512+255)/256), dim3(256), 0, stream, Wd, WdT);
  hipLaunchKernelGGL(hb_kernel, dim3((NB*NE+255)/256), dim3(256), 0, stream, books, hbuf);
  hipLaunchKernelGGL(cvtT_kernel, dim3(16, 16), tpb32, 0, stream, Wq, WqTh, WqTl, 512, 512);
  hipLaunchKernelGGL(cvtT_kernel, dim3(16, 16), tpb32, 0, stream, Wk, WkTh, WkTl, 512, 512);
  hipLaunchKernelGGL(cvtT_kernel, dim3(16, 16), tpb32, 0, stream, Wv, WvTh, WvTl, 512, 512);
  hipLaunchKernelGGL(cvtT_kernel, dim3(16, 16), tpb32, 0, stream, Wo, WoTh, WoTl, 512, 512);
  hipLaunchKernelGGL(cvtT_kernel, dim3(32, 16), tpb32, 0, stream, W1, W1Th, W1Tl, 512, 1024);
  hipLaunchKernelGGL(cvtT_kernel, dim3(16, 32), tpb32, 0, stream, W2, W2Th, W2Tl, 1024, 512);
  hipLaunchKernelGGL(cvtP_kernel, dim3((512*96+255)/256), dim3(256), 0, stream, Wu, WuPh, WuPl, 512*96);

  // ---- phase 1: kv path ----
  hipLaunchKernelGGL(tin_kernel, tgrid, tpb32, 0, stream, qa, pe_tab, bA);
  hipLaunchKernelGGL(ln_rows_kernel, dim3(Mtok), dim3(256), 0, stream, bA, bA, lnkv_g, lnkv_b, 0, scale);
  hipLaunchKernelGGL(mgemm_kernel, dim3(4, Mtok/128), dim3(256), 0, stream, bA, WkTh, WkTl, bK, Mtok, 512, 512, 512,
                     (const float*)nullptr, (const float*)nullptr, 0, 0);
  hipLaunchKernelGGL(mgemm_kernel, dim3(4, Mtok/128), dim3(256), 0, stream, bA, WvTh, WvTl, bV, Mtok, 512, 512, 512,
                     (const float*)nullptr, (const float*)nullptr, 0, 0);
  hipLaunchKernelGGL(gemm_kernel, dim3(8, 1), dim3(256), 0, stream, qc_ln, Wq, qc_proj, 16, 512, 512,
                     (const float*)nullptr, (const float*)nullptr, 0, 0);

  // ---- phase 1: attention + Wo + FFN ----
  hipLaunchKernelGGL(attn1_kernel, dim3(M2tok), dim3(128), 0, stream, bK, bV, qc_proj, bA);
  hipLaunchKernelGGL(mgemm_kernel, dim3(4, Mtok/128), dim3(256), 0, stream, bA, WoTh, WoTl, bY, Mtok, 512, 512, 512,
                     (const float*)nullptr, qc_ln, 1, 0);
  hipLaunchKernelGGL(ln_rows_kernel, dim3(Mtok), dim3(256), 0, stream, bY, bA, ffn_g, ffn_b, 0, scale);
  for (int p = 0; p < 8; p++){
    size_t mo = (size_t)p*4096;
    hipLaunchKernelGGL(mgemm_kernel, dim3(8, 4096/128), dim3(256), 0, stream, bA + mo*512, W1Th, W1Tl, bH, 4096, 1024, 512, 512,
                       b1, (const float*)nullptr, 0, 1);
    hipLaunchKernelGGL(mgemm_kernel, dim3(4, 4096/128), dim3(256), 0, stream, bH, W2Th, W2Tl, bY + mo*512, 4096, 512, 1024, 1024,
                       b2, bY + mo*512, 2, 0);
  }

  // ---- phase 1: residual -> tanh LN -> Wd (fp32 exact: feeds argmax) -> VQ -> Wu -> z_hat ----
  hipLaunchKernelGGL(resid_kernel, tgrid, tpb32, 0, stream, zt, bY, bA);
  hipLaunchKernelGGL(ln_rows_kernel, dim3(Mtok), dim3(256), 0, stream, bA, bA, tn_g, tn_b, 1, scale);
  hipLaunchKernelGGL(gemm_kernel, dim3(2, Mtok/64), dim3(256), 0, stream, bA, WdT, bX, Mtok, 96, 512,
                     bd, (const float*)nullptr, 0, 0);
  hipLaunchKernelGGL(tbt_kernel, dim3(NE/32, CD/32, NB), tpb32, 0, stream, books, booksTp);
  hipLaunchKernelGGL(vq1_kernel, dim3(Mtok/128), dim3(256), 0, stream, bX, books, booksTp, hbuf, 96);
  hipLaunchKernelGGL(mgemm_kernel, dim3(4, Mtok/128), dim3(256), 0, stream, bX, WuPh, WuPl, bA, Mtok, 512, 96, 96,
                     bu, bY, 2, 0);
  hipLaunchKernelGGL(tout_kernel, tgrid, tpb32, 0, stream, bA, out);

  // ---- phase 2: token 0 of each chunk with true carries ----
  hipLaunchKernelGGL(q2_kernel, dim3(M2tok), dim3(256), 0, stream, out, p2q, lnq_g, lnq_b);
  hipLaunchKernelGGL(mgemm_kernel, dim3(4, M2tok/128), dim3(256), 0, stream, p2q, WqTh, WqTl, p2Qp, M2tok, 512, 512, 512,
                     (const float*)nullptr, (const float*)nullptr, 0, 0);
  hipLaunchKernelGGL(attn2_kernel, dim3(M2tok), dim3(64), 0, stream, bK, bV, p2Qp, p2ctx);
  hipLaunchKernelGGL(mgemm_kernel, dim3(4, M2tok/128), dim3(256), 0, stream, p2ctx, WoTh, WoTl, p2y, M2tok, 512, 512, 512,
                     (const float*)nullptr, p2q, 2, 0);
  hipLaunchKernelGGL(ln_rows_kernel, dim3(M2tok), dim3(256), 0, stream, p2y, p2lny, ffn_g, ffn_b, 0, scale);
  hipLaunchKernelGGL(mgemm_kernel, dim3(8, M2tok/128), dim3(256), 0, stream, p2lny, W1Th, W1Tl, p2h, M2tok, 1024, 512, 512,
                     b1, (const float*)nullptr, 0, 1);
  hipLaunchKernelGGL(mgemm_kernel, dim3(4, M2tok/128), dim3(256), 0, stream, p2h, W2Th, W2Tl, p2y, M2tok, 512, 1024, 1024,
                     b2, p2y, 2, 0);
  hipLaunchKernelGGL(r2_kernel, dim3(M2tok), dim3(256), 0, stream, zt, p2y, p2r);
  hipLaunchKernelGGL(ln_rows_kernel, dim3(M2tok), dim3(256), 0, stream, p2r, p2r, tn_g, tn_b, 1, scale);
  hipLaunchKernelGGL(gemm_kernel, dim3(2, M2tok/64), dim3(256), 0, stream, p2r, WdT, p2x, M2tok, 96, 512,
                     bd, (const float*)nullptr, 0, 0);
  for (int k = 0; k < NB; k++){
    hipLaunchKernelGGL(vq2a_kernel, dim3(8, M2tok/64), dim3(256), 0, stream,
                       (k == 0 ? p2x : res2), 96, booksTp, hbuf, ps2, pi2, k);
    hipLaunchKernelGGL(vq2b_kernel, dim3(M2tok/32), dim3(256), 0, stream,
                       p2x, 96, res2, books, ps2, pi2, k);
  }
  hipLaunchKernelGGL(mgemm_kernel, dim3(4, M2tok/128), dim3(256), 0, stream, p2x, WuPh, WuPl, p2z, M2tok, 512, 96, 96,
                     bu, p2y, 2, 0);
  hipLaunchKernelGGL(scatter2_kernel, dim3(M2tok), dim3(256), 0, stream, p2z, out);

  (void)in_sizes; (void)n_in; (void)out_size; (void)ws_size;
}

// Round 8
// 3261.192 us; speedup vs baseline: 2.3271x; 1.0154x over previous
//
#include <hip/hip_runtime.h>
#include <math.h>

#define Bsz 8
#define Cdim 512
#define Tdim 4096
#define NHq 8
#define CD 96
#define NB 8
#define NE 1024
#define NCHq 256
#define Mtok (Bsz*Tdim)     // 32768
#define M2tok (Bsz*NCHq)    // 2048

typedef __attribute__((ext_vector_type(8))) short bf16x8;
typedef __attribute__((ext_vector_type(4))) float f32x4;
typedef unsigned int uint;
typedef unsigned short ushort;

// ---------------- pe + constant query rows ----------------
__global__ __launch_bounds__(256) void pe_qc_kernel(float* pe_tab, float* qc_ln,
        const float* __restrict__ lnq_g, const float* __restrict__ lnq_b){
  int t = blockIdx.x;           // 0..15
  int tid = threadIdx.x;
  __shared__ float red[256];
  double f = -log(10000.0) / (double)Cdim;
  float v[2];
  #pragma unroll
  for (int u = 0; u < 2; ++u){
    int c = tid + u*256;
    int ce = c & ~1;
    double ang = (double)t * exp(f * (double)ce);
    v[u] = (float)((c & 1) ? cos(ang) : sin(ang));
    pe_tab[t*Cdim + c] = v[u];
  }
  red[tid] = v[0] + v[1]; __syncthreads();
  for (int s = 128; s > 0; s >>= 1){ if (tid < s) red[tid] += red[tid+s]; __syncthreads(); }
  float mean = red[0] * (1.f/512.f); __syncthreads();
  float d0 = v[0]-mean, d1 = v[1]-mean;
  red[tid] = d0*d0 + d1*d1; __syncthreads();
  for (int s = 128; s > 0; s >>= 1){ if (tid < s) red[tid] += red[tid+s]; __syncthreads(); }
  float rstd = 1.0f/sqrtf(red[0]*(1.f/512.f) + 1e-5f);
  qc_ln[t*Cdim + tid]       = d0*rstd*lnq_g[tid]     + lnq_b[tid];
  qc_ln[t*Cdim + tid + 256] = d1*rstd*lnq_g[tid+256] + lnq_b[tid+256];
}

// ---------------- generic row LayerNorm (rows of 512) ----------------
// mode 0: dst = norm*g+b ; mode 1: dst = tanh(norm*g+b)*clip(scale)
__global__ __launch_bounds__(256) void ln_rows_kernel(const float* __restrict__ src, float* __restrict__ dst,
        const float* __restrict__ g, const float* __restrict__ bia, int mode, const float* __restrict__ scale_ptr){
  int row = blockIdx.x; int tid = threadIdx.x;
  const float* sr = src + (size_t)row*Cdim;
  float v0 = sr[tid], v1 = sr[tid+256];
  __shared__ float red[256];
  red[tid] = v0+v1; __syncthreads();
  for (int s = 128; s > 0; s >>= 1){ if (tid < s) red[tid] += red[tid+s]; __syncthreads(); }
  float mean = red[0]*(1.f/512.f); __syncthreads();
  float d0 = v0-mean, d1 = v1-mean;
  red[tid] = d0*d0 + d1*d1; __syncthreads();
  for (int s = 128; s > 0; s >>= 1){ if (tid < s) red[tid] += red[tid+s]; __syncthreads(); }
  float rstd = 1.0f/sqrtf(red[0]*(1.f/512.f) + 1e-5f);
  float h0 = d0*rstd*g[tid]     + bia[tid];
  float h1 = d1*rstd*g[tid+256] + bia[tid+256];
  if (mode == 1){
    float sc = *scale_ptr; sc = fminf(fmaxf(sc, 0.005f), 0.5f);
    h0 = tanhf(h0)*sc; h1 = tanhf(h1)*sc;
  }
  float* dr = dst + (size_t)row*Cdim;
  dr[tid] = h0; dr[tid+256] = h1;
}

// ---------------- transposes [B,C,T] <-> token rows [B*T, C] ----------------
__global__ void tin_kernel(const float* __restrict__ qa, const float* __restrict__ pe_tab, float* __restrict__ rows){
  __shared__ float tile[32][33];
  int b = blockIdx.z, c0 = blockIdx.y*32, t0 = blockIdx.x*32;
  int tx = threadIdx.x, ty = threadIdx.y;
  int t = t0 + tx;
  #pragma unroll
  for (int j = 0; j < 4; j++){
    int c = c0 + ty + j*8;
    tile[ty+j*8][tx] = qa[((size_t)(b*Cdim + c))*Tdim + t] + pe_tab[(t & 15)*Cdim + c];
  }
  __syncthreads();
  #pragma unroll
  for (int j = 0; j < 4; j++){
    int tt = t0 + ty + j*8;
    rows[((size_t)(b*Tdim + tt))*Cdim + c0 + tx] = tile[tx][ty+j*8];
  }
}

__global__ void resid_kernel(const float* __restrict__ zt, const float* __restrict__ zp_rows, float* __restrict__ rows){
  __shared__ float tile[32][33];
  int b = blockIdx.z, c0 = blockIdx.y*32, t0 = blockIdx.x*32;
  int tx = threadIdx.x, ty = threadIdx.y;
  int t = t0 + tx;
  #pragma unroll
  for (int j = 0; j < 4; j++){
    int c = c0 + ty + j*8;
    tile[ty+j*8][tx] = zt[((size_t)(b*Cdim + c))*Tdim + t];
  }
  __syncthreads();
  #pragma unroll
  for (int j = 0; j < 4; j++){
    int tt = t0 + ty + j*8;
    size_t o = ((size_t)(b*Tdim + tt))*Cdim + c0 + tx;
    rows[o] = tile[tx][ty+j*8] - zp_rows[o];
  }
}

__global__ void tout_kernel(const float* __restrict__ rows, float* __restrict__ out){
  __shared__ float tile[32][33];
  int b = blockIdx.z, c0 = blockIdx.y*32, t0 = blockIdx.x*32;
  int tx = threadIdx.x, ty = threadIdx.y;
  #pragma unroll
  for (int j = 0; j < 4; j++){
    int tt = t0 + ty + j*8;
    tile[ty+j*8][tx] = rows[((size_t)(b*Tdim + tt))*Cdim + c0 + tx];
  }
  __syncthreads();
  #pragma unroll
  for (int j = 0; j < 4; j++){
    int c = c0 + ty + j*8;
    out[((size_t)(b*Cdim + c))*Tdim + t0 + tx] = tile[tx][ty+j*8];
  }
}

// ---------------- weight transposes ----------------
__global__ void twd_kernel(const float* __restrict__ Wd, float* __restrict__ WdT){ // Wd[96][512] -> WdT[512][96]
  int i = blockIdx.x*256 + threadIdx.x; if (i >= 96*512) return;
  int kq = i / 96, n = i % 96;
  WdT[i] = Wd[(size_t)n*512 + kq];
}

// ---------------- books[k][c][d] -> booksT[k][d][c] (tiled transpose) ----------------
__global__ void tbt_kernel(const float* __restrict__ books, float* __restrict__ booksT){
  __shared__ float tile[32][33];
  int k = blockIdx.z, d0 = blockIdx.y*32, c0 = blockIdx.x*32;
  int tx = threadIdx.x, ty = threadIdx.y;
  #pragma unroll
  for (int j = 0; j < 4; j++){
    int c = c0 + ty + j*8;
    tile[ty+j*8][tx] = books[((size_t)k*NE + c)*CD + d0 + tx];
  }
  __syncthreads();
  #pragma unroll
  for (int j = 0; j < 4; j++){
    int d = d0 + ty + j*8;
    booksT[(size_t)k*CD*NE + (size_t)d*NE + c0 + tx] = tile[tx][ty+j*8];
  }
}

// ---------------- 0.5*||e||^2 per codebook entry ----------------
__global__ void hb_kernel(const float* __restrict__ books, float* __restrict__ hb){
  int j = blockIdx.x*256 + threadIdx.x;
  if (j >= NB*NE) return;
  const float* e = books + (size_t)j*CD;
  float s = 0.f;
  #pragma unroll
  for (int d = 0; d < CD; d++) s = fmaf(e[d], e[d], s);
  hb[j] = 0.5f*s;
}

// ---------------- split-bf16 helpers (hi = truncate, lo = exact residual as bf16) ----------------
__device__ __forceinline__ uint pack_hi(float a, float b){
  uint ua = __float_as_uint(a), ub = __float_as_uint(b);
  return (ua >> 16) | (ub & 0xFFFF0000u);
}
__device__ __forceinline__ uint pack_lo(float a, float b){
  float ha = __uint_as_float(__float_as_uint(a) & 0xFFFF0000u);
  float hb = __uint_as_float(__float_as_uint(b) & 0xFFFF0000u);
  return pack_hi(a - ha, b - hb);
}

// ---------------- weight fp32 [K][N] -> transposed planar bf16 pair [N][K] ----------------
__global__ void cvtT_kernel(const float* __restrict__ W, ushort* __restrict__ hT, ushort* __restrict__ lT,
        int K, int N){
  __shared__ float tile[32][33];
  int k0 = blockIdx.y*32, n0 = blockIdx.x*32;
  int tx = threadIdx.x, ty = threadIdx.y;
  #pragma unroll
  for (int j = 0; j < 4; j++)
    tile[ty+j*8][tx] = W[(size_t)(k0+ty+j*8)*N + n0+tx];
  __syncthreads();
  #pragma unroll
  for (int j = 0; j < 4; j++){
    int n = n0 + ty + j*8;
    float f = tile[tx][ty+j*8];     // = W[k0+tx][n]
    uint u = __float_as_uint(f);
    float hf = __uint_as_float(u & 0xFFFF0000u);
    hT[(size_t)n*K + k0 + tx] = (ushort)(u >> 16);
    lT[(size_t)n*K + k0 + tx] = (ushort)(__float_as_uint(f - hf) >> 16);
  }
}

// ---------------- Wu fp32 [N=512][K=96] -> planar bf16 pair (already BT layout) ----------------
__global__ void cvtP_kernel(const float* __restrict__ X, ushort* __restrict__ h, ushort* __restrict__ lo, int n){
  int i = blockIdx.x*256 + threadIdx.x; if (i >= n) return;
  float f = X[i];
  uint u = __float_as_uint(f);
  float hf = __uint_as_float(u & 0xFFFF0000u);
  h[i]  = (ushort)(u >> 16);
  lo[i] = (ushort)(__float_as_uint(f - hf) >> 16);
}

// ---------------- generic tiled fp32 GEMM (64x64 tile): qc + Wd ----------------
// Wd MUST stay exact fp32: its output feeds the VQ argmax (discontinuous) — split-bf16
// score error ~3e-6 vs top-2 gaps ~4e-4 flipped ~1% of 262K selections (round-6 fail, 0.148).
__global__ __launch_bounds__(256) void gemm_kernel(const float* __restrict__ A, const float* __restrict__ Bm,
        float* __restrict__ Cm, int M, int N, int K,
        const float* __restrict__ bias, const float* __restrict__ addbuf, int addmode, int act){
  __shared__ float As[16][65];
  __shared__ float Bs[16][64];
  int l = threadIdx.x;
  int tx = l & 15, ty = l >> 4;
  int m0 = blockIdx.y*64, n0 = blockIdx.x*64;
  int ai = l >> 2, ak = (l & 3)*4;
  int bk = l >> 4, bj = (l & 15)*4;
  float acc[4][4] = {{0.f}};
  bool nfull = (n0 + 64 <= N);
  for (int k0 = 0; k0 < K; k0 += 16){
    float4 av = make_float4(0.f, 0.f, 0.f, 0.f);
    if (m0 + ai < M) av = *(const float4*)(A + (size_t)(m0+ai)*K + k0 + ak);
    As[ak][ai] = av.x; As[ak+1][ai] = av.y; As[ak+2][ai] = av.z; As[ak+3][ai] = av.w;
    if (nfull){
      *(float4*)(&Bs[bk][bj]) = *(const float4*)(Bm + (size_t)(k0+bk)*N + n0 + bj);
    } else {
      #pragma unroll
      for (int u = 0; u < 4; u++){
        int n = n0 + bj + u;
        Bs[bk][bj+u] = (n < N) ? Bm[(size_t)(k0+bk)*N + n] : 0.f;
      }
    }
    __syncthreads();
    #pragma unroll
    for (int kk = 0; kk < 16; kk++){
      float a0 = As[kk][ty*4], a1 = As[kk][ty*4+1], a2 = As[kk][ty*4+2], a3 = As[kk][ty*4+3];
      float b0 = Bs[kk][tx*4], b1 = Bs[kk][tx*4+1], b2 = Bs[kk][tx*4+2], b3 = Bs[kk][tx*4+3];
      acc[0][0] = fmaf(a0,b0,acc[0][0]); acc[0][1] = fmaf(a0,b1,acc[0][1]);
      acc[0][2] = fmaf(a0,b2,acc[0][2]); acc[0][3] = fmaf(a0,b3,acc[0][3]);
      acc[1][0] = fmaf(a1,b0,acc[1][0]); acc[1][1] = fmaf(a1,b1,acc[1][1]);
      acc[1][2] = fmaf(a1,b2,acc[1][2]); acc[1][3] = fmaf(a1,b3,acc[1][3]);
      acc[2][0] = fmaf(a2,b0,acc[2][0]); acc[2][1] = fmaf(a2,b1,acc[2][1]);
      acc[2][2] = fmaf(a2,b2,acc[2][2]); acc[2][3] = fmaf(a2,b3,acc[2][3]);
      acc[3][0] = fmaf(a3,b0,acc[3][0]); acc[3][1] = fmaf(a3,b1,acc[3][1]);
      acc[3][2] = fmaf(a3,b2,acc[3][2]); acc[3][3] = fmaf(a3,b3,acc[3][3]);
    }
    __syncthreads();
  }
  #pragma unroll
  for (int r = 0; r < 4; r++){
    int m = m0 + ty*4 + r; if (m >= M) continue;
    #pragma unroll
    for (int c = 0; c < 4; c++){
      int n = n0 + tx*4 + c; if (n >= N) continue;
      float v = acc[r][c];
      if (bias) v += bias[n];
      if (act == 1) v = 0.5f*v*(1.0f + erff(v*0.7071067811865475f));
      if (addmode == 1) v += addbuf[(size_t)(m & 15)*N + n];
      else if (addmode == 2) v += addbuf[(size_t)m*N + n];
      Cm[(size_t)m*N + n] = v;
    }
  }
}

// ---------------- MFMA split-bf16 GEMM (lda = A row stride) ----------------
__global__ __launch_bounds__(256, 1) void mgemm_kernel(const float* __restrict__ A,
        const ushort* __restrict__ BhT, const ushort* __restrict__ BlT,
        float* __restrict__ Cm, int M, int N, int K, int lda,
        const float* __restrict__ bias, const float* __restrict__ addbuf, int addmode, int act){
  __shared__ __align__(16) ushort Ah[128][32];
  __shared__ __align__(16) ushort Al[128][32];
  __shared__ __align__(16) ushort Bh[128][32];
  __shared__ __align__(16) ushort Bl[128][32];
  int l = threadIdx.x;
  int il = l & 63, wv = l >> 6;
  int wr = wv >> 1, wc = wv & 1;
  int fr = il & 15, fg = il >> 4;
  int m0 = blockIdx.y*128, n0 = blockIdx.x*128;
  int srow = l >> 1, shalf = (l & 1) * 16;       // stage: row srow, 16 elems at shalf
  const float*  Ap  = A   + (size_t)(m0 + srow)*lda + shalf;
  const ushort* Bhp = BhT + (size_t)(n0 + srow)*K + shalf;
  const ushort* Blp = BlT + (size_t)(n0 + srow)*K + shalf;
  f32x4 acc[4][4];
  #pragma unroll
  for (int i = 0; i < 4; i++)
    #pragma unroll
    for (int j = 0; j < 4; j++)
      acc[i][j] = (f32x4){0.f, 0.f, 0.f, 0.f};
  for (int k0 = 0; k0 < K; k0 += 32){
    float4 a0 = *(const float4*)(Ap + k0);
    float4 a1 = *(const float4*)(Ap + k0 + 4);
    float4 a2 = *(const float4*)(Ap + k0 + 8);
    float4 a3 = *(const float4*)(Ap + k0 + 12);
    uint4 bh0 = *(const uint4*)(Bhp + k0);
    uint4 bh1 = *(const uint4*)(Bhp + k0 + 8);
    uint4 bl0 = *(const uint4*)(Blp + k0);
    uint4 bl1 = *(const uint4*)(Blp + k0 + 8);
    __syncthreads();                        // previous iteration's frag reads done
    uint4 h0, h1, l0v, l1v;
    h0.x = pack_hi(a0.x,a0.y); h0.y = pack_hi(a0.z,a0.w);
    h0.z = pack_hi(a1.x,a1.y); h0.w = pack_hi(a1.z,a1.w);
    h1.x = pack_hi(a2.x,a2.y); h1.y = pack_hi(a2.z,a2.w);
    h1.z = pack_hi(a3.x,a3.y); h1.w = pack_hi(a3.z,a3.w);
    l0v.x = pack_lo(a0.x,a0.y); l0v.y = pack_lo(a0.z,a0.w);
    l0v.z = pack_lo(a1.x,a1.y); l0v.w = pack_lo(a1.z,a1.w);
    l1v.x = pack_lo(a2.x,a2.y); l1v.y = pack_lo(a2.z,a2.w);
    l1v.z = pack_lo(a3.x,a3.y); l1v.w = pack_lo(a3.z,a3.w);
    *(uint4*)&Ah[srow][shalf]   = h0;  *(uint4*)&Ah[srow][shalf+8] = h1;
    *(uint4*)&Al[srow][shalf]   = l0v; *(uint4*)&Al[srow][shalf+8] = l1v;
    *(uint4*)&Bh[srow][shalf]   = bh0; *(uint4*)&Bh[srow][shalf+8] = bh1;
    *(uint4*)&Bl[srow][shalf]   = bl0; *(uint4*)&Bl[srow][shalf+8] = bl1;
    __syncthreads();
    bf16x8 afh[4], afl[4], bfh[4], bfl[4];
    #pragma unroll
    for (int q = 0; q < 4; q++){
      afh[q] = *(const bf16x8*)&Ah[wr*64 + q*16 + fr][fg*8];
      afl[q] = *(const bf16x8*)&Al[wr*64 + q*16 + fr][fg*8];
      bfh[q] = *(const bf16x8*)&Bh[wc*64 + q*16 + fr][fg*8];
      bfl[q] = *(const bf16x8*)&Bl[wc*64 + q*16 + fr][fg*8];
    }
    #pragma unroll
    for (int i = 0; i < 4; i++)
      #pragma unroll
      for (int j = 0; j < 4; j++)
        acc[i][j] = __builtin_amdgcn_mfma_f32_16x16x32_bf16(afh[i], bfh[j], acc[i][j], 0, 0, 0);
    #pragma unroll
    for (int i = 0; i < 4; i++)
      #pragma unroll
      for (int j = 0; j < 4; j++)
        acc[i][j] = __builtin_amdgcn_mfma_f32_16x16x32_bf16(afh[i], bfl[j], acc[i][j], 0, 0, 0);
    #pragma unroll
    for (int i = 0; i < 4; i++)
      #pragma unroll
      for (int j = 0; j < 4; j++)
        acc[i][j] = __builtin_amdgcn_mfma_f32_16x16x32_bf16(afl[i], bfh[j], acc[i][j], 0, 0, 0);
  }
  #pragma unroll
  for (int i = 0; i < 4; i++){
    #pragma unroll
    for (int j = 0; j < 4; j++){
      #pragma unroll
      for (int r = 0; r < 4; r++){
        int m = m0 + wr*64 + i*16 + fg*4 + r;
        int n = n0 + wc*64 + j*16 + fr;
        float v = acc[i][j][r];
        if (bias) v += bias[n];
        if (act == 1) v = 0.5f*v*(1.0f + erff(v*0.7071067811865475f));
        if (addmode == 1) v += addbuf[(size_t)(m & 15)*N + n];
        else if (addmode == 2) v += addbuf[(size_t)m*N + n];
        Cm[(size_t)m*N + n] = v;
      }
    }
  }
}

// ---------------- attention, phase 1 ----------------
__global__ __launch_bounds__(128) void attn1_kernel(const float* __restrict__ Kb, const float* __restrict__ Vb,
        const float* __restrict__ Qp, float* __restrict__ ctxb){
  int idx = blockIdx.x;                 // b*256 + ch
  int b = idx >> 8, ch = idx & 255;
  size_t m0 = (size_t)b*Tdim + ch*16;
  int t = threadIdx.x >> 3, h = threadIdx.x & 7;
  const float* q = Qp + t*Cdim + h*64;
  float qr[64];
  #pragma unroll
  for (int d = 0; d < 64; d += 4){ float4 f = *(const float4*)(q+d); qr[d]=f.x; qr[d+1]=f.y; qr[d+2]=f.z; qr[d+3]=f.w; }
  float s[16];
  #pragma unroll
  for (int k = 0; k < 16; k++){
    const float* kr = Kb + (m0+k)*Cdim + h*64;
    float acc = 0.f;
    #pragma unroll
    for (int d = 0; d < 64; d += 4){
      float4 f = *(const float4*)(kr+d);
      acc = fmaf(qr[d],f.x,acc); acc = fmaf(qr[d+1],f.y,acc);
      acc = fmaf(qr[d+2],f.z,acc); acc = fmaf(qr[d+3],f.w,acc);
    }
    s[k] = acc * 0.125f;
  }
  float mx = s[0];
  #pragma unroll
  for (int k = 1; k < 16; k++) mx = fmaxf(mx, s[k]);
  float sum = 0.f;
  #pragma unroll
  for (int k = 0; k < 16; k++){ s[k] = expf(s[k]-mx); sum += s[k]; }
  float inv = 1.0f/sum;
  float ctx[64];
  #pragma unroll
  for (int d = 0; d < 64; d++) ctx[d] = 0.f;
  #pragma unroll
  for (int k = 0; k < 16; k++){
    float p = s[k]*inv;
    const float* vr = Vb + (m0+k)*Cdim + h*64;
    #pragma unroll
    for (int d = 0; d < 64; d += 4){
      float4 f = *(const float4*)(vr+d);
      ctx[d]=fmaf(p,f.x,ctx[d]); ctx[d+1]=fmaf(p,f.y,ctx[d+1]);
      ctx[d+2]=fmaf(p,f.z,ctx[d+2]); ctx[d+3]=fmaf(p,f.w,ctx[d+3]);
    }
  }
  float* o = ctxb + (m0+t)*Cdim + h*64;
  #pragma unroll
  for (int d = 0; d < 64; d += 4){
    float4 f; f.x=ctx[d]; f.y=ctx[d+1]; f.z=ctx[d+2]; f.w=ctx[d+3];
    *(float4*)(o+d) = f;
  }
}

// ---------------- attention, phase 2 ----------------
__global__ __launch_bounds__(64) void attn2_kernel(const float* __restrict__ Kb, const float* __restrict__ Vb,
        const float* __restrict__ Qp, float* __restrict__ ctxb){
  int m2 = blockIdx.x;                 // b*256 + ch
  int b = m2 >> 8, ch = m2 & 255;
  size_t m0 = (size_t)b*Tdim + ch*16;
  int h = threadIdx.x;
  if (h >= 8) return;
  const float* q = Qp + (size_t)m2*Cdim + h*64;
  float qr[64];
  #pragma unroll
  for (int d = 0; d < 64; d += 4){ float4 f = *(const float4*)(q+d); qr[d]=f.x; qr[d+1]=f.y; qr[d+2]=f.z; qr[d+3]=f.w; }
  float s[16];
  #pragma unroll
  for (int k = 0; k < 16; k++){
    const float* kr = Kb + (m0+k)*Cdim + h*64;
    float acc = 0.f;
    #pragma unroll
    for (int d = 0; d < 64; d += 4){
      float4 f = *(const float4*)(kr+d);
      acc = fmaf(qr[d],f.x,acc); acc = fmaf(qr[d+1],f.y,acc);
      acc = fmaf(qr[d+2],f.z,acc); acc = fmaf(qr[d+3],f.w,acc);
    }
    s[k] = acc * 0.125f;
  }
  float mx = s[0];
  #pragma unroll
  for (int k = 1; k < 16; k++) mx = fmaxf(mx, s[k]);
  float sum = 0.f;
  #pragma unroll
  for (int k = 0; k < 16; k++){ s[k] = expf(s[k]-mx); sum += s[k]; }
  float inv = 1.0f/sum;
  float ctx[64];
  #pragma unroll
  for (int d = 0; d < 64; d++) ctx[d] = 0.f;
  #pragma unroll
  for (int k = 0; k < 16; k++){
    float p = s[k]*inv;
    const float* vr = Vb + (m0+k)*Cdim + h*64;
    #pragma unroll
    for (int d = 0; d < 64; d += 4){
      float4 f = *(const float4*)(vr+d);
      ctx[d]=fmaf(p,f.x,ctx[d]); ctx[d+1]=fmaf(p,f.y,ctx[d+1]);
      ctx[d+2]=fmaf(p,f.z,ctx[d+2]); ctx[d+3]=fmaf(p,f.w,ctx[d+3]);
    }
  }
  float* o = ctxb + (size_t)m2*Cdim + h*64;
  #pragma unroll
  for (int d = 0; d < 64; d += 4){
    float4 f; f.x=ctx[d]; f.y=ctx[d+1]; f.z=ctx[d+2]; f.w=ctx[d+3];
    *(float4*)(o+d) = f;
  }
}

// ---------------- phase 2: build token-0 query rows (carry + pe[:,0], LN) ----------------
__global__ __launch_bounds__(256) void q2_kernel(const float* __restrict__ dout, float* __restrict__ p2q,
        const float* __restrict__ g, const float* __restrict__ bia){
  int m2 = blockIdx.x; int tid = threadIdx.x;
  int b = m2 >> 8, ch = m2 & 255;
  int tprev = ch*16 - 1;
  float v0, v1;
  {
    int c = tid;
    float carry = (ch == 0) ? 0.f : dout[((size_t)(b*Cdim + c))*Tdim + tprev];
    v0 = carry + ((c & 1) ? 1.f : 0.f);     // pe[c,0] = c even ? sin(0)=0 : cos(0)=1
  }
  {
    int c = tid + 256;
    float carry = (ch == 0) ? 0.f : dout[((size_t)(b*Cdim + c))*Tdim + tprev];
    v1 = carry + ((c & 1) ? 1.f : 0.f);
  }
  __shared__ float red[256];
  red[tid] = v0+v1; __syncthreads();
  for (int s = 128; s > 0; s >>= 1){ if (tid < s) red[tid] += red[tid+s]; __syncthreads(); }
  float mean = red[0]*(1.f/512.f); __syncthreads();
  float d0 = v0-mean, d1 = v1-mean;
  red[tid] = d0*d0 + d1*d1; __syncthreads();
  for (int s = 128; s > 0; s >>= 1){ if (tid < s) red[tid] += red[tid+s]; __syncthreads(); }
  float rstd = 1.0f/sqrtf(red[0]*(1.f/512.f) + 1e-5f);
  p2q[(size_t)m2*Cdim + tid]       = d0*rstd*g[tid]     + bia[tid];
  p2q[(size_t)m2*Cdim + tid + 256] = d1*rstd*g[tid+256] + bia[tid+256];
}

// ---------------- phase 2: r = zt[:, :, t0] - z_pred0 ----------------
__global__ __launch_bounds__(256) void r2_kernel(const float* __restrict__ zt, const float* __restrict__ zp,
        float* __restrict__ out){
  int m2 = blockIdx.x; int tid = threadIdx.x;
  int b = m2 >> 8, ch = m2 & 255; int t0 = ch*16;
  #pragma unroll
  for (int u = 0; u < 2; u++){
    int c = tid + u*256;
    out[(size_t)m2*Cdim + c] = zt[((size_t)(b*Cdim + c))*Tdim + t0] - zp[(size_t)m2*Cdim + c];
  }
}

// ---------------- phase 2: scatter z_hat token-0 columns into d_out ----------------
__global__ __launch_bounds__(256) void scatter2_kernel(const float* __restrict__ z, float* __restrict__ dout){
  int m2 = blockIdx.x; int tid = threadIdx.x;
  int b = m2 >> 8, ch = m2 & 255; int t0 = ch*16;
  #pragma unroll
  for (int u = 0; u < 2; u++){
    int c = tid + u*256;
    dout[((size_t)(b*Cdim + c))*Tdim + t0] = z[(size_t)m2*Cdim + c];
  }
}

// ---------------- phase-1 residual VQ (MT=128, 512 threads = 2 waves/SIMD) ----------------
// Round-7: dbuf alone gave 832->795 (1 wave/SIMD = no latency hiding partner). Same LDS
// geometry (As[97][128], Es[97][256], 147KB, 1 blk/CU) but 8 waves: per-thread acc 8x8,
// per-wave/kk = 4 ds_read_b128 / 64 FMA (same aggregate LDS:FMA ratio), partner wave on
// each SIMD hides LDS latency + barrier skew. 32-lane shfl_xor argmax butterfly (lanes of
// a row group are contiguous-32 within a wave; masks 1..16 stay inside).
__global__ __launch_bounds__(512, 2) void vq1_kernel(float* __restrict__ x,
        const float* __restrict__ books, const float* __restrict__ booksT,
        const float* __restrict__ hb, int xs){
  int l = threadIdx.x;
  int tx = l & 31, ty = l >> 5;          // tx: 32 cand groups (8 cands), ty: 16 row groups (8 rows)
  int tok = l >> 2, part = l & 3;        // staging/update: 4 threads per token, 24 floats each
  size_t tok0 = (size_t)blockIdx.x * 128;
  __shared__ float As[97][128];          // res^T (+1 pad row)
  __shared__ float Es[97][256];          // E^T candidate tile (+1 pad row)
  __shared__ float hs[256];
  __shared__ int   sel[128];
  float* xp = x + (tok0 + tok)*xs;
  #pragma unroll
  for (int j = 0; j < 6; j++){
    int d4 = part*6 + j;
    float4 v = *(const float4*)(xp + d4*4);
    As[d4*4+0][tok]=v.x; As[d4*4+1][tok]=v.y; As[d4*4+2][tok]=v.z; As[d4*4+3][tok]=v.w;
  }
  for (int k = 0; k < NB; k++){
    const float* bT = booksT + (size_t)k*CD*NE;
    const float* hk = hb + k*NE;
    float best[8]; int bidx[8];
    #pragma unroll
    for (int i = 0; i < 8; i++){ best[i] = -3.0e38f; bidx[i] = 0; }
    for (int t = 0; t < 4; t++){
      int n0 = t*256;
      __syncthreads();                 // orders As writes (init/update) + prev Es reads
      #pragma unroll
      for (int j = 0; j < 12; j++){    // stage 96x256 E^T tile, coalesced
        int f4 = j*512 + l;
        int d = f4 >> 6, c4 = f4 & 63;
        float4 v = *(const float4*)(bT + (size_t)d*NE + n0 + c4*4);
        *(float4*)(&Es[d][c4*4]) = v;
      }
      if (l < 64){
        float4 hv = *(const float4*)(hk + n0 + l*4);
        *(float4*)(&hs[l*4]) = hv;
      }
      __syncthreads();
      float acc[8][8];
      #pragma unroll
      for (int i = 0; i < 8; i++)
        #pragma unroll
        for (int j = 0; j < 8; j++) acc[i][j] = 0.f;
      float av0[8], bw0[8], av1[8], bw1[8];
      *(float4*)(av0)   = *(const float4*)(&As[0][ty*8]);
      *(float4*)(av0+4) = *(const float4*)(&As[0][ty*8+4]);
      *(float4*)(bw0)   = *(const float4*)(&Es[0][tx*4]);
      *(float4*)(bw0+4) = *(const float4*)(&Es[0][128 + tx*4]);
      for (int kk = 0; kk < 96; kk += 2){
        *(float4*)(av1)   = *(const float4*)(&As[kk+1][ty*8]);
        *(float4*)(av1+4) = *(const float4*)(&As[kk+1][ty*8+4]);
        *(float4*)(bw1)   = *(const float4*)(&Es[kk+1][tx*4]);
        *(float4*)(bw1+4) = *(const float4*)(&Es[kk+1][128 + tx*4]);
        #pragma unroll
        for (int i = 0; i < 8; i++)
          #pragma unroll
          for (int j = 0; j < 8; j++)
            acc[i][j] = fmaf(av0[i], bw0[j], acc[i][j]);
        *(float4*)(av0)   = *(const float4*)(&As[kk+2][ty*8]);      // kk+2==96 hits pad row (unused)
        *(float4*)(av0+4) = *(const float4*)(&As[kk+2][ty*8+4]);
        *(float4*)(bw0)   = *(const float4*)(&Es[kk+2][tx*4]);
        *(float4*)(bw0+4) = *(const float4*)(&Es[kk+2][128 + tx*4]);
        #pragma unroll
        for (int i = 0; i < 8; i++)
          #pragma unroll
          for (int j = 0; j < 8; j++)
            acc[i][j] = fmaf(av1[i], bw1[j], acc[i][j]);
      }
      #pragma unroll
      for (int i = 0; i < 8; i++){
        #pragma unroll
        for (int j = 0; j < 8; j++){
          int cl = (j>>2)*128 + tx*4 + (j&3);    // ascending within thread
          float s = acc[i][j] - hs[cl];
          if (s > best[i]){ best[i] = s; bidx[i] = n0 + cl; }
        }
      }
    }
    // cross-thread argmax: 32 tx-partials per row group in contiguous 32 lanes of a wave
    #pragma unroll
    for (int i = 0; i < 8; i++){
      float s = best[i]; int idx = bidx[i];
      #pragma unroll
      for (int m = 1; m < 32; m <<= 1){
        float os = __shfl_xor(s, m);
        int   oi = __shfl_xor(idx, m);
        if (os > s || (os == s && oi < idx)){ s = os; idx = oi; }
      }
      if (tx == 0) sel[ty*8 + i] = idx;
    }
    __syncthreads();
    int s = sel[tok];
    const float* e = books + ((size_t)k*NE + s)*CD;
    #pragma unroll
    for (int j = 0; j < 6; j++){
      int d4 = part*6 + j;
      float4 v = *(const float4*)(e + d4*4);
      As[d4*4+0][tok] -= v.x; As[d4*4+1][tok] -= v.y;
      As[d4*4+2][tok] -= v.z; As[d4*4+3][tok] -= v.w;
    }
  }
  // q_sum = x - res_final (thread reads exactly the cells it wrote)
  #pragma unroll
  for (int j = 0; j < 6; j++){
    int d4 = part*6 + j;
    float4 xo = *(const float4*)(xp + d4*4);
    float4 q;
    q.x = xo.x - As[d4*4+0][tok];
    q.y = xo.y - As[d4*4+1][tok];
    q.z = xo.z - As[d4*4+2][tok];
    q.w = xo.w - As[d4*4+3][tok];
    *(float4*)(xp + d4*4) = q;
  }
}

// ---------------- phase-2 residual VQ, split per book ----------------
__global__ __launch_bounds__(256, 2) void vq2a_kernel(const float* __restrict__ src, int ss,
        const float* __restrict__ booksT, const float* __restrict__ hb,
        float* __restrict__ ps, int* __restrict__ pi, int k){
  int l = threadIdx.x;
  int tx = l & 15, ty = l >> 4;
  int cb = blockIdx.x;                   // 0..7
  int tok0 = blockIdx.y * 64;
  int n0 = cb * 128;
  __shared__ float As[97][64];
  __shared__ float Es[97][128];
  __shared__ float hs[128];
  {
    int tok = l >> 2, part = l & 3;
    const float* sp = src + (size_t)(tok0 + tok)*ss;
    #pragma unroll
    for (int j = 0; j < 6; j++){
      int d4 = part*6 + j;
      float4 v = *(const float4*)(sp + d4*4);
      As[d4*4+0][tok]=v.x; As[d4*4+1][tok]=v.y; As[d4*4+2][tok]=v.z; As[d4*4+3][tok]=v.w;
    }
  }
  const float* bT = booksT + (size_t)k*CD*NE;
  #pragma unroll
  for (int j = 0; j < 12; j++){
    int f4 = j*256 + l;
    int d = f4 >> 5, c4 = f4 & 31;
    float4 v = *(const float4*)(bT + (size_t)d*NE + n0 + c4*4);
    *(float4*)(&Es[d][c4*4]) = v;
  }
  if (l < 32){
    float4 hv = *(const float4*)(hb + k*NE + n0 + l*4);
    *(float4*)(&hs[l*4]) = hv;
  }
  __syncthreads();
  float acc[4][8];
  #pragma unroll
  for (int i = 0; i < 4; i++)
    #pragma unroll
    for (int j = 0; j < 8; j++) acc[i][j] = 0.f;
  float av0[4], bw0[8], av1[4], bw1[8];
  *(float4*)(av0) = *(const float4*)(&As[0][ty*4]);
  *(float4*)(bw0)   = *(const float4*)(&Es[0][tx*4]);
  *(float4*)(bw0+4) = *(const float4*)(&Es[0][64 + tx*4]);
  for (int kk = 0; kk < 96; kk += 2){
    *(float4*)(av1) = *(const float4*)(&As[kk+1][ty*4]);
    *(float4*)(bw1)   = *(const float4*)(&Es[kk+1][tx*4]);
    *(float4*)(bw1+4) = *(const float4*)(&Es[kk+1][64 + tx*4]);
    #pragma unroll
    for (int i = 0; i < 4; i++)
      #pragma unroll
      for (int j = 0; j < 8; j++)
        acc[i][j] = fmaf(av0[i], bw0[j], acc[i][j]);
    *(float4*)(av0) = *(const float4*)(&As[kk+2][ty*4]);           // pad row at 96 (unused)
    *(float4*)(bw0)   = *(const float4*)(&Es[kk+2][tx*4]);
    *(float4*)(bw0+4) = *(const float4*)(&Es[kk+2][64 + tx*4]);
    #pragma unroll
    for (int i = 0; i < 4; i++)
      #pragma unroll
      for (int j = 0; j < 8; j++)
        acc[i][j] = fmaf(av1[i], bw1[j], acc[i][j]);
  }
  #pragma unroll
  for (int i = 0; i < 4; i++){
    float best = -3.0e38f; int bidx = 0;
    #pragma unroll
    for (int j = 0; j < 8; j++){
      int cl = (j>>2)*64 + tx*4 + (j&3);       // ascending within thread
      float s = acc[i][j] - hs[cl];
      if (s > best){ best = s; bidx = n0 + cl; }
    }
    #pragma unroll
    for (int m = 1; m < 16; m <<= 1){
      float os = __shfl_xor(best, m);
      int   oi = __shfl_xor(bidx, m);
      if (os > best || (os == best && oi < bidx)){ best = os; bidx = oi; }
    }
    if (tx == 0){
      int row = tok0 + ty*4 + i;
      ps[cb*M2tok + row] = best;
      pi[cb*M2tok + row] = bidx;
    }
  }
}

__global__ __launch_bounds__(256) void vq2b_kernel(float* __restrict__ x, int xs, float* __restrict__ res,
        const float* __restrict__ books, const float* __restrict__ ps, const int* __restrict__ pi, int k){
  int l = threadIdx.x;
  int tok = blockIdx.x*32 + (l >> 3);
  int part = l & 7;                      // 12 floats per thread
  float bb = ps[tok]; int bi = pi[tok];
  #pragma unroll
  for (int c = 1; c < 8; c++){
    float s2 = ps[c*M2tok + tok]; int i2 = pi[c*M2tok + tok];
    if (s2 > bb || (s2 == bb && i2 < bi)){ bb = s2; bi = i2; }
  }
  const float* e = books + ((size_t)k*NE + bi)*CD + part*12;
  const float* sp = ((k == 0) ? (const float*)(x + (size_t)tok*xs) : (const float*)(res + (size_t)tok*CD)) + part*12;
  float r[12];
  #pragma unroll
  for (int j = 0; j < 12; j += 4){
    float4 sv = *(const float4*)(sp + j);
    float4 ev = *(const float4*)(e + j);
    r[j]=sv.x-ev.x; r[j+1]=sv.y-ev.y; r[j+2]=sv.z-ev.z; r[j+3]=sv.w-ev.w;
  }
  if (k < NB-1){
    float* rp = res + (size_t)tok*CD + part*12;
    #pragma unroll
    for (int j = 0; j < 12; j += 4){
      float4 v; v.x=r[j]; v.y=r[j+1]; v.z=r[j+2]; v.w=r[j+3];
      *(float4*)(rp + j) = v;
    }
  } else {
    float* xq = x + (size_t)tok*xs + part*12;
    #pragma unroll
    for (int j = 0; j < 12; j += 4){
      float4 xo = *(const float4*)(xq + j);
      float4 v; v.x=xo.x-r[j]; v.y=xo.y-r[j+1]; v.z=xo.z-r[j+2]; v.w=xo.w-r[j+3];
      *(float4*)(xq + j) = v;
    }
  }
}

// ---------------- host ----------------
extern "C" void kernel_launch(void* const* d_in, const int* in_sizes, int n_in,
                              void* d_out, int out_size, void* d_ws, size_t ws_size,
                              hipStream_t stream) {
  const float* qa    = (const float*)d_in[0];
  const float* zt    = (const float*)d_in[1];
  const float* lnq_g = (const float*)d_in[2];
  const float* lnq_b = (const float*)d_in[3];
  const float* lnkv_g= (const float*)d_in[4];
  const float* lnkv_b= (const float*)d_in[5];
  const float* Wq    = (const float*)d_in[6];
  const float* Wk    = (const float*)d_in[7];
  const float* Wv    = (const float*)d_in[8];
  const float* Wo    = (const float*)d_in[9];
  const float* ffn_g = (const float*)d_in[10];
  const float* ffn_b = (const float*)d_in[11];
  const float* W1    = (const float*)d_in[12];
  const float* b1    = (const float*)d_in[13];
  const float* W2    = (const float*)d_in[14];
  const float* b2    = (const float*)d_in[15];
  const float* tn_g  = (const float*)d_in[16];
  const float* tn_b  = (const float*)d_in[17];
  const float* scale = (const float*)d_in[18];
  const float* Wd    = (const float*)d_in[19];
  const float* bd    = (const float*)d_in[20];
  const float* Wu    = (const float*)d_in[21];
  const float* bu    = (const float*)d_in[22];
  const float* books = (const float*)d_in[23];
  float* out = (float*)d_out;

  // ---- workspace layout (~227 MiB, round-7-proven) ----
  float* ws = (float*)d_ws;
  size_t off = 0;
  float* pe_tab  = ws + off; off += 16*512;
  float* qc_ln   = ws + off; off += 16*512;
  float* qc_proj = ws + off; off += 16*512;
  float* WdT     = ws + off; off += 512*96;
  float* hbuf    = ws + off; off += 8*1024;
  // split-bf16 weight pairs (ushort)
  ushort* wub = (ushort*)(ws + off); off += 2146304;   // 4,292,608 ushorts
  ushort* WqTh = wub;            ushort* WqTl = WqTh + 262144;
  ushort* WkTh = WqTl + 262144;  ushort* WkTl = WkTh + 262144;
  ushort* WvTh = WkTl + 262144;  ushort* WvTl = WvTh + 262144;
  ushort* WoTh = WvTl + 262144;  ushort* WoTl = WoTh + 262144;
  ushort* W1Th = WoTl + 262144;  ushort* W1Tl = W1Th + 524288;
  ushort* W2Th = W1Tl + 524288;  ushort* W2Tl = W2Th + 524288;
  ushort* WuPh = W2Tl + 524288;  ushort* WuPl = WuPh + 49152;
  float* bA      = ws + off; off += (size_t)Mtok*512;   // kv rows -> ctx -> lny -> rn -> zhat rows -> phase2 scratch
  float* bK      = ws + off; off += (size_t)Mtok*512;
  float* bV      = ws + off; off += (size_t)Mtok*512;
  float* bH      = ws + off; off += (size_t)4096*1024;  // FFN hidden tile; also hosts bX + booksT
  float* bX      = bH;                                  // Mtok*96 = 12.6MB
  float* booksTp = bH + (size_t)Mtok*CD;                // 3MB in bH's spare tail
  float* bY      = out;                                 // y / z_pred rows live in d_out

  // phase-2 scratch carved inside bA (only used after tout consumes bA)
  float* p2q   = bA;
  float* p2Qp  = bA + 1048576;
  float* p2ctx = bA + 2*1048576;
  float* p2y   = bA + 3*1048576;
  float* p2lny = bA + 4*1048576;
  float* p2h   = bA + 5*1048576;          // 2048*1024
  float* p2r   = bA + 7*1048576;
  float* p2x   = bA + 8*1048576;          // 2048*96
  float* p2z   = bA + 8*1048576 + 196608;
  float* res2  = bA + 10*1048576;         // 2048*96 residual state for split VQ
  float* ps2   = bA + 10*1048576 + 196608;           // 8*2048 partial scores
  int*   pi2   = (int*)(bA + 10*1048576 + 196608 + 16384);  // 8*2048 partial idx

  dim3 tpb32(32, 8);
  dim3 tgrid(Tdim/32, Cdim/32, Bsz);

  // ---- prep ----
  hipLaunchKernelGGL(pe_qc_kernel, dim3(16), dim3(256), 0, stream, pe_tab, qc_ln, lnq_g, lnq_b);
  hipLaunchKernelGGL(twd_kernel, dim3((96*512+255)/256), dim3(256), 0, stream, Wd, WdT);
  hipLaunchKernelGGL(hb_kernel, dim3((NB*NE+255)/256), dim3(256), 0, stream, books, hbuf);
  hipLaunchKernelGGL(cvtT_kernel, dim3(16, 16), tpb32, 0, stream, Wq, WqTh, WqTl, 512, 512);
  hipLaunchKernelGGL(cvtT_kernel, dim3(16, 16), tpb32, 0, stream, Wk, WkTh, WkTl, 512, 512);
  hipLaunchKernelGGL(cvtT_kernel, dim3(16, 16), tpb32, 0, stream, Wv, WvTh, WvTl, 512, 512);
  hipLaunchKernelGGL(cvtT_kernel, dim3(16, 16), tpb32, 0, stream, Wo, WoTh, WoTl, 512, 512);
  hipLaunchKernelGGL(cvtT_kernel, dim3(32, 16), tpb32, 0, stream, W1, W1Th, W1Tl, 512, 1024);
  hipLaunchKernelGGL(cvtT_kernel, dim3(16, 32), tpb32, 0, stream, W2, W2Th, W2Tl, 1024, 512);
  hipLaunchKernelGGL(cvtP_kernel, dim3((512*96+255)/256), dim3(256), 0, stream, Wu, WuPh, WuPl, 512*96);

  // ---- phase 1: kv path ----
  hipLaunchKernelGGL(tin_kernel, tgrid, tpb32, 0, stream, qa, pe_tab, bA);
  hipLaunchKernelGGL(ln_rows_kernel, dim3(Mtok), dim3(256), 0, stream, bA, bA, lnkv_g, lnkv_b, 0, scale);
  hipLaunchKernelGGL(mgemm_kernel, dim3(4, Mtok/128), dim3(256), 0, stream, bA, WkTh, WkTl, bK, Mtok, 512, 512, 512,
                     (const float*)nullptr, (const float*)nullptr, 0, 0);
  hipLaunchKernelGGL(mgemm_kernel, dim3(4, Mtok/128), dim3(256), 0, stream, bA, WvTh, WvTl, bV, Mtok, 512, 512, 512,
                     (const float*)nullptr, (const float*)nullptr, 0, 0);
  hipLaunchKernelGGL(gemm_kernel, dim3(8, 1), dim3(256), 0, stream, qc_ln, Wq, qc_proj, 16, 512, 512,
                     (const float*)nullptr, (const float*)nullptr, 0, 0);

  // ---- phase 1: attention + Wo + FFN ----
  hipLaunchKernelGGL(attn1_kernel, dim3(M2tok), dim3(128), 0, stream, bK, bV, qc_proj, bA);
  hipLaunchKernelGGL(mgemm_kernel, dim3(4, Mtok/128), dim3(256), 0, stream, bA, WoTh, WoTl, bY, Mtok, 512, 512, 512,
                     (const float*)nullptr, qc_ln, 1, 0);
  hipLaunchKernelGGL(ln_rows_kernel, dim3(Mtok), dim3(256), 0, stream, bY, bA, ffn_g, ffn_b, 0, scale);
  for (int p = 0; p < 8; p++){
    size_t mo = (size_t)p*4096;
    hipLaunchKernelGGL(mgemm_kernel, dim3(8, 4096/128), dim3(256), 0, stream, bA + mo*512, W1Th, W1Tl, bH, 4096, 1024, 512, 512,
                       b1, (const float*)nullptr, 0, 1);
    hipLaunchKernelGGL(mgemm_kernel, dim3(4, 4096/128), dim3(256), 0, stream, bH, W2Th, W2Tl, bY + mo*512, 4096, 512, 1024, 1024,
                       b2, bY + mo*512, 2, 0);
  }

  // ---- phase 1: residual -> tanh LN -> Wd (fp32 exact: feeds argmax) -> VQ -> Wu -> z_hat ----
  hipLaunchKernelGGL(resid_kernel, tgrid, tpb32, 0, stream, zt, bY, bA);
  hipLaunchKernelGGL(ln_rows_kernel, dim3(Mtok), dim3(256), 0, stream, bA, bA, tn_g, tn_b, 1, scale);
  hipLaunchKernelGGL(gemm_kernel, dim3(2, Mtok/64), dim3(256), 0, stream, bA, WdT, bX, Mtok, 96, 512,
                     bd, (const float*)nullptr, 0, 0);
  hipLaunchKernelGGL(tbt_kernel, dim3(NE/32, CD/32, NB), tpb32, 0, stream, books, booksTp);
  hipLaunchKernelGGL(vq1_kernel, dim3(Mtok/128), dim3(512), 0, stream, bX, books, booksTp, hbuf, 96);
  hipLaunchKernelGGL(mgemm_kernel, dim3(4, Mtok/128), dim3(256), 0, stream, bX, WuPh, WuPl, bA, Mtok, 512, 96, 96,
                     bu, bY, 2, 0);
  hipLaunchKernelGGL(tout_kernel, tgrid, tpb32, 0, stream, bA, out);

  // ---- phase 2: token 0 of each chunk with true carries ----
  hipLaunchKernelGGL(q2_kernel, dim3(M2tok), dim3(256), 0, stream, out, p2q, lnq_g, lnq_b);
  hipLaunchKernelGGL(mgemm_kernel, dim3(4, M2tok/128), dim3(256), 0, stream, p2q, WqTh, WqTl, p2Qp, M2tok, 512, 512, 512,
                     (const float*)nullptr, (const float*)nullptr, 0, 0);
  hipLaunchKernelGGL(attn2_kernel, dim3(M2tok), dim3(64), 0, stream, bK, bV, p2Qp, p2ctx);
  hipLaunchKernelGGL(mgemm_kernel, dim3(4, M2tok/128), dim3(256), 0, stream, p2ctx, WoTh, WoTl, p2y, M2tok, 512, 512, 512,
                     (const float*)nullptr, p2q, 2, 0);
  hipLaunchKernelGGL(ln_rows_kernel, dim3(M2tok), dim3(256), 0, stream, p2y, p2lny, ffn_g, ffn_b, 0, scale);
  hipLaunchKernelGGL(mgemm_kernel, dim3(8, M2tok/128), dim3(256), 0, stream, p2lny, W1Th, W1Tl, p2h, M2tok, 1024, 512, 512,
                     b1, (const float*)nullptr, 0, 1);
  hipLaunchKernelGGL(mgemm_kernel, dim3(4, M2tok/128), dim3(256), 0, stream, p2h, W2Th, W2Tl, p2y, M2tok, 512, 1024, 1024,
                     b2, p2y, 2, 0);
  hipLaunchKernelGGL(r2_kernel, dim3(M2tok), dim3(256), 0, stream, zt, p2y, p2r);
  hipLaunchKernelGGL(ln_rows_kernel, dim3(M2tok), dim3(256), 0, stream, p2r, p2r, tn_g, tn_b, 1, scale);
  hipLaunchKernelGGL(gemm_kernel, dim3(2, M2tok/64), dim3(256), 0, stream, p2r, WdT, p2x, M2tok, 96, 512,
                     bd, (const float*)nullptr, 0, 0);
  for (int k = 0; k < NB; k++){
    hipLaunchKernelGGL(vq2a_kernel, dim3(8, M2tok/64), dim3(256), 0, stream,
                       (k == 0 ? p2x : res2), 96, booksTp, hbuf, ps2, pi2, k);
    hipLaunchKernelGGL(vq2b_kernel, dim3(M2tok/32), dim3(256), 0, stream,
                       p2x, 96, res2, books, ps2, pi2, k);
  }
  hipLaunchKernelGGL(mgemm_kernel, dim3(4, M2tok/128), dim3(256), 0, stream, p2x, WuPh, WuPl, p2z, M2tok, 512, 96, 96,
                     bu, p2y, 2, 0);
  hipLaunchKernelGGL(scatter2_kernel, dim3(M2tok), dim3(256), 0, stream, p2z, out);

  (void)in_sizes; (void)n_in; (void)out_size; (void)ws_size;
}